// Round 2
// baseline (3324.814 us; speedup 1.0000x reference)
//
#include <hip/hip_runtime.h>
#include <hip/hip_bf16.h>

// ---------------------------------------------------------------------------
// SSGraphDTI forward, fp32, half-batch pipelined to keep d_ws under 24 MB.
// B=64 (2 halves of 32), ND=NPR=32, LD=100, LP=1000, DIM=64, CONV=40
// ---------------------------------------------------------------------------

#define BH_ 32   // batches per half

// ---------------- workspace layout (float offsets) ----------------
// R region: per-half GNN buffers, later aliased by per-half protein conv.
static constexpr size_t PX0H   = 0;         // 1024*1000
static constexpr size_t PX1H   = 1024000;   // 1024*1000
static constexpr size_t AGGPP  = 2048000;   // 1024*1000
static constexpr size_t DX0H   = 3072000;   // 1024*100
static constexpr size_t DX1H   = 3174400;   // 1024*100
static constexpr size_t AGGDD  = 3276800;   // 1024*100
static constexpr size_t ZPD    = 3379200;   // 1024*100
static constexpr size_t AGGZPD = 3481600;   // 1024*100
static constexpr size_t AGGDP  = 3584000;   // 1024*100
static constexpr size_t A2DD   = 3686400;   // 32*100
static constexpr size_t A2DP   = 3689600;   // 32*100
static constexpr size_t A2PD   = 3692800;   // 32*1000
static constexpr size_t A2PP   = 3724800;   // 32*1000
static constexpr size_t CD2H   = 3756800;   // 32*100   (zeroed per half)
static constexpr size_t CP2H   = 3760000;   // 32*1000  -> 3792000
// conv aliases of R: y1p_h @0 (32*40*997=1276160), y2p_h @1276160 (32*80*990=2534400) -> 3810560
static constexpr size_t Y1PH   = 0;
static constexpr size_t Y2PH   = 1276160;
// persistent region:
static constexpr size_t Y1D    = 3810560;   // 64*40*97 = 248320
static constexpr size_t Y2D    = 4058880;   // 64*80*92 = 471040
static constexpr size_t WSUMP  = 4529920;   // 1000*1000
static constexpr size_t WSUMD  = 5529920;   // 100*100
static constexpr size_t BD     = 5539920;   // 100 (pad)
static constexpr size_t BP     = 5540020;   // 1000
static constexpr size_t PAIR   = 5541020;   // 64*1420 = 90880  (zeroed once)
static constexpr size_t CF1    = 5631900;   // 64*1024          (zeroed once)
static constexpr size_t CF2    = 5697436;   // 64*1024
static constexpr size_t CF3    = 5762972;   // 64*512 -> 5795740
static constexpr size_t H1     = 5795740;   // 64*1024
static constexpr size_t H2     = 5861276;   // 64*1024
static constexpr size_t H3     = 5926812;   // 64*512 -> 5959580
static constexpr size_t NEED_FLOATS = 5959580;        // ~23.8 MB
static constexpr size_t ZERO1_BEG = PAIR;             // pair..CF3 contiguous
static constexpr size_t ZERO1_CNT = 254720;
static constexpr size_t ZERO2_BEG = CD2H;             // CD2H..CP2H contiguous
static constexpr size_t ZERO2_CNT = 35200;

// ---------------------------------------------------------------------------
__global__ void zero_k(float* __restrict__ p, int n) {
    int i = blockIdx.x * 256 + threadIdx.x;
    if (i < n) p[i] = 0.f;
}

// out[i] = s * (a[i] + b[i])
__global__ void addsc_k(float* __restrict__ o, const float* __restrict__ a,
                        const float* __restrict__ b, float s, int n) {
    int i = blockIdx.x * 256 + threadIdx.x;
    if (i < n) o[i] = s * (a[i] + b[i]);
}

// out[i] += s * x[i]
__global__ void axpy_k(float* __restrict__ o, const float* __restrict__ x, float s, int n) {
    int i = blockIdx.x * 256 + threadIdx.x;
    if (i < n) o[i] += s * x[i];
}

// bag-of-tokens node features (histogram @ table / L). Half-batch: rows lb*32+n.
__global__ __launch_bounds__(256) void node_feat_k(const int* __restrict__ toks,
                                                   const float* __restrict__ table,
                                                   float* __restrict__ out,
                                                   int V, int Lw, int b0) {
    const int lb = blockIdx.y, n = blockIdx.x, tid = threadIdx.x;
    __shared__ int cnt[71];
    for (int v = tid; v < V; v += 256) cnt[v] = 0;
    __syncthreads();
    const int* t = toks + ((size_t)(b0 + lb) * 32 + n) * Lw;
    for (int i = tid; i < Lw; i += 256) atomicAdd(&cnt[t[i]], 1);
    __syncthreads();
    float inv = 1.f / (float)Lw;
    float* o = out + ((size_t)lb * 32 + n) * Lw;
    for (int d = tid; d < Lw; d += 256) {
        float a = 0.f;
        for (int v = 0; v < V; ++v) {
            int c = cnt[v];
            if (c) a += (float)c * table[(size_t)v * Lw + d];
        }
        o[d] = a * inv;
    }
}

// segment-mean gather: out[lb,n,:] = mean over edges e with dst==n of x[lb,src,:]
// edges layout per batch: eb = edges + (b0+lb)*E2; src at eb[srcrel+e], dst at eb[dstrel+e]
__global__ __launch_bounds__(256) void segmean_k(const float* __restrict__ x,
                                                 const int* __restrict__ edges,
                                                 float* __restrict__ out,
                                                 int b0, int E2, int srcrel, int dstrel,
                                                 int E, int D, int nout) {
    const int n = blockIdx.x, lb = blockIdx.y, tid = threadIdx.x;
    const int* eb = edges + (size_t)(b0 + lb) * E2;
    const float* xb = x + (size_t)lb * 32 * D;
    const int d0 = tid, d1 = tid + 256, d2 = tid + 512, d3 = tid + 768;
    float s0 = 0.f, s1 = 0.f, s2 = 0.f, s3 = 0.f;
    int cnt = 0;
    for (int e = 0; e < E; ++e) {
        if (eb[dstrel + e] == n) {
            ++cnt;
            const float* xr = xb + (size_t)eb[srcrel + e] * D;
            if (d0 < D) s0 += xr[d0];
            if (d1 < D) s1 += xr[d1];
            if (d2 < D) s2 += xr[d2];
            if (d3 < D) s3 += xr[d3];
        }
    }
    float inv = 1.f / (float)max(cnt, 1);
    float* o = out + ((size_t)lb * nout + n) * D;
    if (d0 < D) o[d0] = s0 * inv;
    if (d1 < D) o[d1] = s1 * inv;
    if (d2 < D) o[d2] = s2 * inv;
    if (d3 < D) o[d3] = s3 * inv;
}

// NT-SGEMM: acc = A(M,K,lda) @ B(N,K)^T, 64x64x16 tiles, 4x4 reg tile.
// mode 0 WRITE: C[m*rs+coloff+n] = act(scale*acc + bias[n])
// mode 1 ACC:   C[m*rs+coloff+n] += scale*acc
// mode 2 ATOMIC: atomicAdd(&C[m*N+n], scale*acc)   (split-K)
__global__ __launch_bounds__(256) void gemm_nt(const float* __restrict__ A, int lda,
                                               const float* __restrict__ Bm,
                                               float* __restrict__ Cout,
                                               const float* __restrict__ bias,
                                               int M, int N, int K, int KC, int mode,
                                               float scale, int act, int rs, int coloff) {
    const int m0 = blockIdx.x * 64, n0 = blockIdx.y * 64, s = blockIdx.z;
    const int tid = threadIdx.x, ty = tid >> 4, tx = tid & 15;
    __shared__ __align__(16) float As[16][68];
    __shared__ __align__(16) float Bs[16][68];
    float acc[4][4] = {};
    const int kbeg = s * KC, kend = min(K, kbeg + KC);
    for (int k0 = kbeg; k0 < kend; k0 += 16) {
        int colk = k0 + tx;
        bool kok = colk < kend;
        #pragma unroll
        for (int q = 0; q < 4; ++q) {
            int mi = ty + q * 16;
            As[tx][mi] = (kok && (m0 + mi) < M) ? A[(size_t)(m0 + mi) * lda + colk] : 0.f;
            Bs[tx][mi] = (kok && (n0 + mi) < N) ? Bm[(size_t)(n0 + mi) * K + colk] : 0.f;
        }
        __syncthreads();
        #pragma unroll
        for (int kk = 0; kk < 16; ++kk) {
            float4 a4 = *(const float4*)&As[kk][ty * 4];
            float4 b4 = *(const float4*)&Bs[kk][tx * 4];
            float av[4] = {a4.x, a4.y, a4.z, a4.w};
            float bv[4] = {b4.x, b4.y, b4.z, b4.w};
            #pragma unroll
            for (int i = 0; i < 4; ++i)
                #pragma unroll
                for (int j = 0; j < 4; ++j)
                    acc[i][j] = fmaf(av[i], bv[j], acc[i][j]);
        }
        __syncthreads();
    }
    #pragma unroll
    for (int i = 0; i < 4; ++i) {
        int m = m0 + ty * 4 + i;
        if (m >= M) continue;
        #pragma unroll
        for (int j = 0; j < 4; ++j) {
            int n = n0 + tx * 4 + j;
            if (n >= N) continue;
            if (mode == 2) {
                atomicAdd(&Cout[(size_t)m * N + n], scale * acc[i][j]);
            } else {
                size_t o = (size_t)m * rs + coloff + n;
                float v = scale * acc[i][j];
                if (mode == 0) { v += bias ? bias[n] : 0.f; if (act == 2) v = v >= 0.f ? v : 0.01f * v; }
                else v += Cout[o];
                Cout[o] = v;
            }
        }
    }
}

// epilogue: out[m*rs+coloff+n] = act(scale*C[m*N+n] + bias[n])
__global__ void epilogue_k(const float* __restrict__ C, const float* __restrict__ bias,
                           float* __restrict__ out, int M, int N, float scale, int act,
                           int rs, int coloff) {
    int idx = blockIdx.x * 256 + threadIdx.x;
    if (idx >= M * N) return;
    int m = idx / N, n = idx % N;
    float v = scale * C[idx] + (bias ? bias[n] : 0.f);
    if (act == 2) v = v >= 0.f ? v : 0.01f * v;
    out[(size_t)m * rs + coloff + n] = v;
}

// conv1 fused with embedding lookup: table (V,64) staged transposed in LDS.
// Y[(lb*Co+co)*Lout+t] = relu(sum_{ci,k} W[co,ci,k]*emb[tok[b,t+k],ci] + b[co])
template <int K>
__global__ __launch_bounds__(256) void conv1e_k(const int* __restrict__ toks, int b0, int L,
                                                const float* __restrict__ table, int V,
                                                const float* __restrict__ W,
                                                const float* __restrict__ bias,
                                                float* __restrict__ Y, int Co, int Lout) {
    const int lb = blockIdx.z, co0 = blockIdx.y * 64, t0 = blockIdx.x * 64;
    const int tid = threadIdx.x, ty = tid >> 4, tx = tid & 15;
    constexpr int WX = 64 + K - 1;
    __shared__ float tabT[64 * 71];
    __shared__ int tok_s[WX];
    __shared__ __align__(16) float xs[4][80];
    __shared__ __align__(16) float ws[4 * K][68];
    for (int idx = tid; idx < 64 * V; idx += 256) {
        int v = idx >> 6, c = idx & 63;
        tabT[c * V + v] = table[idx];
    }
    for (int t = tid; t < WX; t += 256) {
        int gt = t0 + t;
        tok_s[t] = (gt < L) ? toks[(size_t)(b0 + lb) * L + gt] : 0;  // row 0 is zeros
    }
    __syncthreads();
    float acc[4][4] = {};
    for (int ci0 = 0; ci0 < 64; ci0 += 4) {
        for (int idx = tid; idx < 4 * WX; idx += 256) {
            int ci = idx / WX, t = idx % WX;
            xs[ci][t] = tabT[(ci0 + ci) * V + tok_s[t]];
        }
        for (int idx = tid; idx < 64 * 4 * K; idx += 256) {
            int co = idx / (4 * K), j = idx % (4 * K);
            ws[j][co] = (co0 + co < Co) ? W[(size_t)(co0 + co) * 64 * K + (size_t)ci0 * K + j] : 0.f;
        }
        __syncthreads();
        #pragma unroll
        for (int ci = 0; ci < 4; ++ci) {
            float xr[16];
            #pragma unroll
            for (int q = 0; q < (K + 6) / 4; ++q)
                *(float4*)&xr[q * 4] = *(const float4*)&xs[ci][tx * 4 + q * 4];
            #pragma unroll
            for (int k = 0; k < K; ++k) {
                float4 a4 = *(const float4*)&ws[ci * K + k][ty * 4];
                float av[4] = {a4.x, a4.y, a4.z, a4.w};
                #pragma unroll
                for (int j = 0; j < 4; ++j) {
                    float bx = xr[j + k];
                    #pragma unroll
                    for (int i = 0; i < 4; ++i)
                        acc[i][j] = fmaf(av[i], bx, acc[i][j]);
                }
            }
        }
        __syncthreads();
    }
    #pragma unroll
    for (int i = 0; i < 4; ++i) {
        int co = co0 + ty * 4 + i;
        if (co >= Co) continue;
        float bv = bias[co];
        #pragma unroll
        for (int j = 0; j < 4; ++j) {
            int t = t0 + tx * 4 + j;
            if (t < Lout)
                Y[((size_t)lb * Co + co) * Lout + t] = fmaxf(acc[i][j] + bv, 0.f);
        }
    }
}

// direct conv1d VALID + relu; final_pool: length-max via int atomicMax into Y[lb*rs+coloff+co]
template <int K>
__global__ __launch_bounds__(256) void conv_k(const float* __restrict__ X,
                                              const float* __restrict__ W,
                                              const float* __restrict__ bias,
                                              float* __restrict__ Y,
                                              int Ci, int Co, int L, int Lout,
                                              int final_pool, int rs, int coloff) {
    const int lb = blockIdx.z, co0 = blockIdx.y * 64, t0 = blockIdx.x * 64;
    const int tid = threadIdx.x, ty = tid >> 4, tx = tid & 15;
    constexpr int WX = 64 + K - 1;
    __shared__ __align__(16) float xs[4][80];
    __shared__ __align__(16) float ws[4 * K][68];
    float acc[4][4] = {};
    for (int ci0 = 0; ci0 < Ci; ci0 += 4) {
        for (int idx = tid; idx < 4 * WX; idx += 256) {
            int ci = idx / WX, t = idx % WX;
            int gt = t0 + t;
            xs[ci][t] = (gt < L) ? X[((size_t)lb * Ci + ci0 + ci) * L + gt] : 0.f;
        }
        for (int idx = tid; idx < 64 * 4 * K; idx += 256) {
            int co = idx / (4 * K), j = idx % (4 * K);
            ws[j][co] = (co0 + co < Co) ? W[(size_t)(co0 + co) * Ci * K + (size_t)ci0 * K + j] : 0.f;
        }
        __syncthreads();
        #pragma unroll
        for (int ci = 0; ci < 4; ++ci) {
            float xr[16];
            #pragma unroll
            for (int q = 0; q < (K + 6) / 4; ++q)
                *(float4*)&xr[q * 4] = *(const float4*)&xs[ci][tx * 4 + q * 4];
            #pragma unroll
            for (int k = 0; k < K; ++k) {
                float4 a4 = *(const float4*)&ws[ci * K + k][ty * 4];
                float av[4] = {a4.x, a4.y, a4.z, a4.w};
                #pragma unroll
                for (int j = 0; j < 4; ++j) {
                    float bx = xr[j + k];
                    #pragma unroll
                    for (int i = 0; i < 4; ++i)
                        acc[i][j] = fmaf(av[i], bx, acc[i][j]);
                }
            }
        }
        __syncthreads();
    }
    #pragma unroll
    for (int i = 0; i < 4; ++i) {
        int co = co0 + ty * 4 + i;
        if (co >= Co) continue;
        float bv = bias[co];
        if (!final_pool) {
            #pragma unroll
            for (int j = 0; j < 4; ++j) {
                int t = t0 + tx * 4 + j;
                if (t < Lout)
                    Y[((size_t)lb * Co + co) * Lout + t] = fmaxf(acc[i][j] + bv, 0.f);
            }
        } else {
            float m = 0.f;
            #pragma unroll
            for (int j = 0; j < 4; ++j) {
                int t = t0 + tx * 4 + j;
                if (t < Lout) m = fmaxf(m, fmaxf(acc[i][j] + bv, 0.f));
            }
            atomicMax((int*)&Y[(size_t)lb * rs + coloff + co], __float_as_int(m));
        }
    }
}

// final 512 -> 2 projection
__global__ void out_k(const float* __restrict__ h3, const float* __restrict__ W,
                      const float* __restrict__ bias, float* __restrict__ out) {
    int tid = threadIdx.x;
    if (tid >= 128) return;
    int b = tid >> 1, n = tid & 1;
    const float* hr = h3 + (size_t)b * 512;
    const float* wr = W + (size_t)n * 512;
    float a = 0.f;
    for (int k = 0; k < 512; ++k) a = fmaf(hr[k], wr[k], a);
    out[b * 2 + n] = a + bias[n];
}

// ---------------------------------------------------------------------------
static inline int kc_of(int K, int S) { return ((K + S * 16 - 1) / (S * 16)) * 16; }
static inline dim3 g1d(int n) { return dim3((n + 255) / 256); }

extern "C" void kernel_launch(void* const* d_in, const int* in_sizes, int n_in,
                              void* d_out, int out_size, void* d_ws, size_t ws_size,
                              hipStream_t stream) {
    const int* drug_tokens       = (const int*)d_in[0];
    const int* protein_tokens    = (const int*)d_in[1];
    const int* drug_node_tokens  = (const int*)d_in[2];
    const int* protein_node_toks = (const int*)d_in[3];
    const int* ddi_edges         = (const int*)d_in[4];
    const int* ppi_edges         = (const int*)d_in[5];
    const int* dpi_edges         = (const int*)d_in[6];
    const float* drug_embed      = (const float*)d_in[7];
    const float* protein_embed   = (const float*)d_in[8];
    const float* dW1 = (const float*)d_in[9];  const float* db1 = (const float*)d_in[10];
    const float* dW2 = (const float*)d_in[11]; const float* db2 = (const float*)d_in[12];
    const float* dW3 = (const float*)d_in[13]; const float* db3 = (const float*)d_in[14];
    const float* pW1 = (const float*)d_in[15]; const float* pb1 = (const float*)d_in[16];
    const float* pW2 = (const float*)d_in[17]; const float* pb2 = (const float*)d_in[18];
    const float* pW3 = (const float*)d_in[19]; const float* pb3 = (const float*)d_in[20];
    const float* drug_node_table = (const float*)d_in[21];
    const float* prot_node_table = (const float*)d_in[22];
    const float* ddi_Wl = (const float*)d_in[23]; const float* ddi_bl = (const float*)d_in[24];
    const float* ddi_Wr = (const float*)d_in[25];
    const float* ppi_Wl = (const float*)d_in[26]; const float* ppi_bl = (const float*)d_in[27];
    const float* ppi_Wr = (const float*)d_in[28];
    const float* dpi_Wl = (const float*)d_in[29]; const float* dpi_bl = (const float*)d_in[30];
    const float* dpi_Wr = (const float*)d_in[31];
    const float* pdi_Wl = (const float*)d_in[32]; const float* pdi_bl = (const float*)d_in[33];
    const float* pdi_Wr = (const float*)d_in[34];
    const float* fc1_W = (const float*)d_in[35]; const float* fc1_b = (const float*)d_in[36];
    const float* fc2_W = (const float*)d_in[37]; const float* fc2_b = (const float*)d_in[38];
    const float* fc3_W = (const float*)d_in[39]; const float* fc3_b = (const float*)d_in[40];
    const float* out_W = (const float*)d_in[41]; const float* out_b = (const float*)d_in[42];

    float* outp = (float*)d_out;
    // ws-size guard: if scratch is too small, emit zeros (clean absmax failure,
    // distinguishable from a crash) instead of corrupting memory.
    if (ws_size < NEED_FLOATS * sizeof(float)) {
        zero_k<<<g1d(out_size), 256, 0, stream>>>(outp, out_size);
        return;
    }

    float* ws = (float*)d_ws;
    float* px0h = ws + PX0H; float* px1h = ws + PX1H; float* aggpp = ws + AGGPP;
    float* dx0h = ws + DX0H; float* dx1h = ws + DX1H; float* aggdd = ws + AGGDD;
    float* zpd = ws + ZPD;   float* aggzpd = ws + AGGZPD; float* aggdp = ws + AGGDP;
    float* a2dd = ws + A2DD; float* a2dp = ws + A2DP; float* a2pd = ws + A2PD;
    float* a2pp = ws + A2PP; float* cd2h = ws + CD2H; float* cp2h = ws + CP2H;
    float* y1ph = ws + Y1PH; float* y2ph = ws + Y2PH;
    float* y1d = ws + Y1D;   float* y2d = ws + Y2D;
    float* wsump = ws + WSUMP; float* wsumd = ws + WSUMD;
    float* bd = ws + BD;     float* bp = ws + BP;
    float* pair = ws + PAIR;
    float* cf1 = ws + CF1;   float* cf2 = ws + CF2;   float* cf3 = ws + CF3;
    float* h1 = ws + H1;     float* h2 = ws + H2;     float* h3 = ws + H3;

    // 0) zero accumulation region (pair + FC split-K bufs), build combined weights
    zero_k<<<g1d((int)ZERO1_CNT), 256, 0, stream>>>(ws + ZERO1_BEG, (int)ZERO1_CNT);
    addsc_k<<<g1d(10000), 256, 0, stream>>>(wsumd, ddi_Wr, pdi_Wr, 1.f, 10000);
    addsc_k<<<g1d(1000000), 256, 0, stream>>>(wsump, ppi_Wr, dpi_Wr, 1.f, 1000000);
    addsc_k<<<g1d(100), 256, 0, stream>>>(bd, ddi_bl, pdi_bl, 0.5f, 100);
    addsc_k<<<g1d(1000), 256, 0, stream>>>(bp, ppi_bl, dpi_bl, 0.5f, 1000);

    for (int h = 0; h < 2; ++h) {
        const int b0 = h * BH_;
        // --- node features ---
        node_feat_k<<<dim3(32, BH_), 256, 0, stream>>>(drug_node_tokens, drug_node_table, dx0h, 71, 100, b0);
        node_feat_k<<<dim3(32, BH_), 256, 0, stream>>>(protein_node_toks, prot_node_table, px0h, 26, 1000, b0);
        // --- layer-1 aggregations ---
        segmean_k<<<dim3(32, BH_), 256, 0, stream>>>(dx0h, ddi_edges, aggdd, b0, 256, 0, 128, 128, 100, 32);
        segmean_k<<<dim3(32, BH_), 256, 0, stream>>>(dx0h, dpi_edges, aggdp, b0, 128, 0, 64, 64, 100, 32);
        segmean_k<<<dim3(32, BH_), 256, 0, stream>>>(px0h, ppi_edges, aggpp, b0, 256, 0, 128, 128, 1000, 32);
        // pdi: transform (1000->100) then aggregate (exact: segmean is linear)
        gemm_nt<<<dim3(16, 2, 1), 256, 0, stream>>>(px0h, 1000, pdi_Wl, zpd, nullptr,
                                                    1024, 100, 1000, kc_of(1000, 1), 0, 1.f, 0, 100, 0);
        segmean_k<<<dim3(32, BH_), 256, 0, stream>>>(zpd, dpi_edges, aggzpd, b0, 128, 64, 0, 64, 100, 32);
        // --- layer-1 drug update: dx1 = .5*(aggdd@Wl^T + dx0@Wsum^T + aggzpd) + bd ---
        gemm_nt<<<dim3(16, 2, 1), 256, 0, stream>>>(aggdd, 100, ddi_Wl, dx1h, bd,
                                                    1024, 100, 100, kc_of(100, 1), 0, 0.5f, 0, 100, 0);
        gemm_nt<<<dim3(16, 2, 1), 256, 0, stream>>>(dx0h, 100, wsumd, dx1h, nullptr,
                                                    1024, 100, 100, kc_of(100, 1), 1, 0.5f, 0, 100, 0);
        axpy_k<<<g1d(102400), 256, 0, stream>>>(dx1h, aggzpd, 0.5f, 102400);
        // --- layer-1 protein update ---
        gemm_nt<<<dim3(16, 16, 1), 256, 0, stream>>>(aggpp, 1000, ppi_Wl, px1h, bp,
                                                     1024, 1000, 1000, kc_of(1000, 1), 0, 0.5f, 0, 1000, 0);
        gemm_nt<<<dim3(16, 16, 1), 256, 0, stream>>>(px0h, 1000, wsump, px1h, nullptr,
                                                     1024, 1000, 1000, kc_of(1000, 1), 1, 0.5f, 0, 1000, 0);
        gemm_nt<<<dim3(16, 16, 1), 256, 0, stream>>>(aggdp, 100, dpi_Wl, px1h, nullptr,
                                                     1024, 1000, 100, kc_of(100, 1), 1, 0.5f, 0, 1000, 0);
        // --- layer 2, node 0 only ---
        zero_k<<<g1d((int)ZERO2_CNT), 256, 0, stream>>>(ws + ZERO2_BEG, (int)ZERO2_CNT);
        segmean_k<<<dim3(1, BH_), 256, 0, stream>>>(dx1h, ddi_edges, a2dd, b0, 256, 0, 128, 128, 100, 1);
        segmean_k<<<dim3(1, BH_), 256, 0, stream>>>(px1h, dpi_edges, a2pd, b0, 128, 64, 0, 64, 1000, 1);
        segmean_k<<<dim3(1, BH_), 256, 0, stream>>>(px1h, ppi_edges, a2pp, b0, 256, 0, 128, 128, 1000, 1);
        segmean_k<<<dim3(1, BH_), 256, 0, stream>>>(dx1h, dpi_edges, a2dp, b0, 128, 0, 64, 64, 100, 1);
        gemm_nt<<<dim3(1, 2, 1), 256, 0, stream>>>(a2dd, 100, ddi_Wl, cd2h, nullptr,
                                                   32, 100, 100, kc_of(100, 1), 2, 1.f, 0, 0, 0);
        gemm_nt<<<dim3(1, 2, 1), 256, 0, stream>>>(dx1h, 3200, wsumd, cd2h, nullptr,
                                                   32, 100, 100, kc_of(100, 1), 2, 1.f, 0, 0, 0);
        gemm_nt<<<dim3(1, 2, 4), 256, 0, stream>>>(a2pd, 1000, pdi_Wl, cd2h, nullptr,
                                                   32, 100, 1000, kc_of(1000, 4), 2, 1.f, 0, 0, 0);
        gemm_nt<<<dim3(1, 16, 2), 256, 0, stream>>>(a2pp, 1000, ppi_Wl, cp2h, nullptr,
                                                    32, 1000, 1000, kc_of(1000, 2), 2, 1.f, 0, 0, 0);
        gemm_nt<<<dim3(1, 16, 2), 256, 0, stream>>>(px1h, 32000, wsump, cp2h, nullptr,
                                                    32, 1000, 1000, kc_of(1000, 2), 2, 1.f, 0, 0, 0);
        gemm_nt<<<dim3(1, 16, 1), 256, 0, stream>>>(a2dp, 100, dpi_Wl, cp2h, nullptr,
                                                    32, 1000, 100, kc_of(100, 1), 2, 1.f, 0, 0, 0);
        epilogue_k<<<g1d(32 * 100), 256, 0, stream>>>(cd2h, bd, pair + (size_t)b0 * 1420,
                                                      32, 100, 0.5f, 0, 1420, 320);
        epilogue_k<<<g1d(32 * 1000), 256, 0, stream>>>(cp2h, bp, pair + (size_t)b0 * 1420,
                                                       32, 1000, 0.5f, 0, 1420, 420);
        // --- protein conv tower for this half (aliases the now-dead GNN buffers) ---
        conv1e_k<4><<<dim3(16, 1, BH_), 256, 0, stream>>>(protein_tokens, b0, 1000, protein_embed, 26,
                                                          pW1, pb1, y1ph, 40, 997);
        conv_k<8><<<dim3(16, 2, BH_), 256, 0, stream>>>(y1ph, pW2, pb2, y2ph, 40, 80, 997, 990, 0, 0, 0);
        conv_k<12><<<dim3(16, 3, BH_), 256, 0, stream>>>(y2ph, pW3, pb3, pair + (size_t)b0 * 1420,
                                                         80, 160, 990, 979, 1, 1420, 160);
    }

    // drug conv tower (full batch, tiny)
    conv1e_k<4><<<dim3(2, 1, 64), 256, 0, stream>>>(drug_tokens, 0, 100, drug_embed, 71,
                                                    dW1, db1, y1d, 40, 97);
    conv_k<6><<<dim3(2, 2, 64), 256, 0, stream>>>(y1d, dW2, db2, y2d, 40, 80, 97, 92, 0, 0, 0);
    conv_k<8><<<dim3(2, 3, 64), 256, 0, stream>>>(y2d, dW3, db3, pair, 80, 160, 92, 85, 1, 1420, 0);

    // FC head: split-K atomic GEMMs + leaky-relu epilogues
    gemm_nt<<<dim3(1, 16, 4), 256, 0, stream>>>(pair, 1420, fc1_W, cf1, nullptr,
                                                64, 1024, 1420, kc_of(1420, 4), 2, 1.f, 0, 0, 0);
    epilogue_k<<<g1d(64 * 1024), 256, 0, stream>>>(cf1, fc1_b, h1, 64, 1024, 1.f, 2, 1024, 0);
    gemm_nt<<<dim3(1, 16, 4), 256, 0, stream>>>(h1, 1024, fc2_W, cf2, nullptr,
                                                64, 1024, 1024, kc_of(1024, 4), 2, 1.f, 0, 0, 0);
    epilogue_k<<<g1d(64 * 1024), 256, 0, stream>>>(cf2, fc2_b, h2, 64, 1024, 1.f, 2, 1024, 0);
    gemm_nt<<<dim3(1, 8, 4), 256, 0, stream>>>(h2, 1024, fc3_W, cf3, nullptr,
                                               64, 512, 1024, kc_of(1024, 4), 2, 1.f, 0, 0, 0);
    epilogue_k<<<g1d(64 * 512), 256, 0, stream>>>(cf3, fc3_b, h3, 64, 512, 1.f, 2, 512, 0);
    out_k<<<dim3(1), 128, 0, stream>>>(h3, out_W, out_b, outp);
}

// Round 3
// 1057.047 us; speedup vs baseline: 3.1454x; 3.1454x over previous
//
#include <hip/hip_runtime.h>
#include <hip/hip_bf16.h>

// ---------------------------------------------------------------------------
// SSGraphDTI forward. Heavy compute in bf16 MFMA (16x16x32), FC head fp32.
// B=64, ND=NPR=32, LD=100, LP=1000, DIM=64, CONV=40
// ---------------------------------------------------------------------------

typedef __attribute__((ext_vector_type(8))) short short8;
typedef __attribute__((ext_vector_type(4))) float f32x4;
union FragU { uint32_t u[4]; uint4 q; short8 s; };

// ---------------- workspace layout (byte offsets) ----------------
static constexpr size_t O_PAIR = 0;          // 64*1420 f32 = 363,520
static constexpr size_t O_CF1  = 363520;     // 64*1024 f32
static constexpr size_t O_CF2  = 625664;
static constexpr size_t O_CF3  = 887808;     // 64*512 f32
static constexpr size_t O_H1   = 1018880;
static constexpr size_t O_H2   = 1281024;
static constexpr size_t O_H3   = 1543168;    // 64*512 f32
static constexpr size_t O_BD   = 1674240;    // 128 f32
static constexpr size_t O_BP   = 1674752;    // 1024 f32
static constexpr size_t Z1_END = 1678848;    // zero span [0, Z1_END)
static constexpr size_t O_WD   = 1678848;    // 128x384 bf16
static constexpr size_t O_WP   = 1777152;    // 1024x2176 bf16
static constexpr size_t O_PDIB = 6233600;    // 128x1024 bf16
static constexpr size_t O_WTP1 = 6495744;    // 64x512 bf16
static constexpr size_t O_WTP2 = 6561280;    // 128x320 bf16
static constexpr size_t O_WTP3 = 6643200;    // 192x1280 bf16
static constexpr size_t O_WTD1 = 7134720;    // 64x512 bf16
static constexpr size_t O_WTD2 = 7200256;    // 128x320 bf16
static constexpr size_t O_WTD3 = 7282176;    // 192x640 bf16
static constexpr size_t AR     = 7527936;    // aliased region base
// GNN phase (within AR):
static constexpr size_t O_XP   = AR + 0;          // 2048x2176 bf16 = 8,912,896
static constexpr size_t O_XD   = AR + 8912896;    // 2048x384 bf16
static constexpr size_t O_ZPD  = AR + 10485760;   // 2048x128 bf16
static constexpr size_t O_PX1  = AR + 11010048;   // 2048x1024 bf16
static constexpr size_t O_DX1  = AR + 15204352;   // 2048x128 bf16
static constexpr size_t O_XP2  = AR + 15728640;   // 64x2176 bf16
static constexpr size_t O_XD2  = AR + 16007168;   // 64x384 bf16
static constexpr size_t O_A2PD = AR + 16056320;   // 64x1024 bf16 -> 16,187,392
// conv phase aliases (GNN dead):
static constexpr size_t O_X0P  = AR + 0;          // 64x64x1000 bf16 = 8,192,000
static constexpr size_t O_Y1P  = AR + 8192000;    // 64x40x1000 bf16 = 5,120,000
static constexpr size_t O_Y2P  = AR + 0;          // 64x80x992 bf16 (x0p dead)
static constexpr size_t O_X0D  = AR + 13312000;   // 64x64x104 bf16
static constexpr size_t O_Y1D  = AR + 14163968;   // 64x40x104 bf16
static constexpr size_t O_Y2D  = AR + 14696448;   // 64x80x96 bf16 -> 15,679,488
static constexpr size_t NEED_BYTES = AR + 16187392;  // 23,715,328

// ---------------------------------------------------------------------------
__global__ void zero32_k(uint32_t* __restrict__ p, int n) {
    int i = blockIdx.x * 256 + threadIdx.x;
    if (i < n) p[i] = 0u;
}

__global__ void addsc_k(float* __restrict__ o, const float* __restrict__ a,
                        const float* __restrict__ b, float s, int n) {
    int i = blockIdx.x * 256 + threadIdx.x;
    if (i < n) o[i] = s * (a[i] + b[i]);
}

// weight block convert: dst[n*ld_dst+coloff+k] = bf16(src1+src2) or 0-pad
__global__ void wtcvt_k(unsigned short* __restrict__ dst, int ld_dst, int coloff, int Npad,
                        const float* __restrict__ s1, const float* __restrict__ s2,
                        int ld_src, int N, int Kreal, int Kblk) {
    int idx = blockIdx.x * 256 + threadIdx.x;
    if (idx >= Npad * Kblk) return;
    int n = idx / Kblk, k = idx % Kblk;
    float v = 0.f;
    if (n < N && k < Kreal) {
        v = s1[(size_t)n * ld_src + k];
        if (s2) v += s2[(size_t)n * ld_src + k];
    }
    __hip_bfloat16 h = __float2bfloat16(v);
    dst[(size_t)n * ld_dst + coloff + k] = *(unsigned short*)&h;
}

// identity block for Wd_cat cols [256:384)
__global__ void ident_k(unsigned short* __restrict__ Wd) {
    int idx = blockIdx.x * 256 + threadIdx.x;
    if (idx >= 128 * 128) return;
    int n = idx / 128, k = idx % 128;
    __hip_bfloat16 h = __float2bfloat16((n == k && n < 100) ? 1.f : 0.f);
    Wd[(size_t)n * 384 + 256 + k] = *(unsigned short*)&h;
}

// conv weights: dst[co][ci*KP+k] = W[co][ci][k] (zero-padded)
__global__ void wtconv_k(unsigned short* __restrict__ dst, const float* __restrict__ W,
                         int Co_pad, int Co, int Ci, int K, int KP) {
    int idx = blockIdx.x * 256 + threadIdx.x;
    if (idx >= Co_pad * Ci * KP) return;
    int co = idx / (Ci * KP);
    int ci = (idx / KP) % Ci;
    int k = idx % KP;
    float v = (co < Co && k < K) ? W[((size_t)co * Ci + ci) * K + k] : 0.f;
    __hip_bfloat16 h = __float2bfloat16(v);
    dst[idx] = *(unsigned short*)&h;
}

// copy layer-1 node-0 rows into layer-2 concat blocks
__global__ void copy_rows_k(const unsigned short* __restrict__ src, int lds,
                            unsigned short* __restrict__ dst, int ldo, int coloff, int n_el) {
    int b = blockIdx.x;
    for (int d = threadIdx.x; d < n_el; d += 256)
        dst[(size_t)b * ldo + coloff + d] = src[(size_t)b * 32 * lds + d];
}

// embedding lookup -> bf16 (B, 64, Lpad), zero pads
__global__ __launch_bounds__(256) void embed_k(const int* __restrict__ toks,
                                               const float* __restrict__ table,
                                               unsigned short* __restrict__ out,
                                               int L, int Lpad) {
    int b = blockIdx.x, c0 = blockIdx.y * 8;
    for (int t = threadIdx.x; t < Lpad; t += 256) {
        if (t < L) {
            int tk = toks[(size_t)b * L + t];
            #pragma unroll
            for (int c = 0; c < 8; ++c) {
                __hip_bfloat16 h = __float2bfloat16(table[(size_t)tk * 64 + c0 + c]);
                out[((size_t)b * 64 + c0 + c) * Lpad + t] = *(unsigned short*)&h;
            }
        } else {
            #pragma unroll
            for (int c = 0; c < 8; ++c)
                out[((size_t)b * 64 + c0 + c) * Lpad + t] = 0;
        }
    }
}

// bag-of-tokens node features via LDS histogram -> bf16 strided output
__global__ __launch_bounds__(256) void node_feat_k(const int* __restrict__ toks,
                                                   const float* __restrict__ table,
                                                   int V, int Lw,
                                                   unsigned short* __restrict__ out,
                                                   int ldo, int coloff) {
    const int b = blockIdx.y, n = blockIdx.x, tid = threadIdx.x;
    __shared__ int cnt[71];
    for (int v = tid; v < V; v += 256) cnt[v] = 0;
    __syncthreads();
    const int* t = toks + ((size_t)b * 32 + n) * Lw;
    for (int i = tid; i < Lw; i += 256) atomicAdd(&cnt[t[i]], 1);
    __syncthreads();
    float inv = 1.f / (float)Lw;
    unsigned short* o = out + ((size_t)b * 32 + n) * ldo + coloff;
    for (int d = tid; d < Lw; d += 256) {
        float a = 0.f;
        for (int v = 0; v < V; ++v) {
            int c = cnt[v];
            if (c) a += (float)c * table[(size_t)v * Lw + d];
        }
        __hip_bfloat16 h = __float2bfloat16(a * inv);
        o[d] = *(unsigned short*)&h;
    }
}

// segment-mean gather, bf16 in/out, fp32 accumulate
__global__ __launch_bounds__(256) void segmean_k(const unsigned short* __restrict__ x, int ldx,
                                                 const int* __restrict__ edges,
                                                 int E2, int srcrel, int dstrel, int E,
                                                 int D, int nout,
                                                 unsigned short* __restrict__ out,
                                                 int ldo, int coloff) {
    const int n = blockIdx.x, lb = blockIdx.y, tid = threadIdx.x;
    const int* eb = edges + (size_t)lb * E2;
    const unsigned short* xb = x + (size_t)lb * 32 * ldx;
    const int d0 = tid, d1 = tid + 256, d2 = tid + 512, d3 = tid + 768;
    float s0 = 0.f, s1 = 0.f, s2 = 0.f, s3 = 0.f;
    int cnt = 0;
    for (int e = 0; e < E; ++e) {
        if (eb[dstrel + e] == n) {
            ++cnt;
            const unsigned short* xr = xb + (size_t)eb[srcrel + e] * ldx;
            if (d0 < D) s0 += __bfloat162float(*(const __hip_bfloat16*)&xr[d0]);
            if (d1 < D) s1 += __bfloat162float(*(const __hip_bfloat16*)&xr[d1]);
            if (d2 < D) s2 += __bfloat162float(*(const __hip_bfloat16*)&xr[d2]);
            if (d3 < D) s3 += __bfloat162float(*(const __hip_bfloat16*)&xr[d3]);
        }
    }
    float inv = 1.f / (float)max(cnt, 1);
    unsigned short* o = out + ((size_t)lb * nout + n) * ldo + coloff;
    __hip_bfloat16 h;
    if (d0 < D) { h = __float2bfloat16(s0 * inv); o[d0] = *(unsigned short*)&h; }
    if (d1 < D) { h = __float2bfloat16(s1 * inv); o[d1] = *(unsigned short*)&h; }
    if (d2 < D) { h = __float2bfloat16(s2 * inv); o[d2] = *(unsigned short*)&h; }
    if (d3 < D) { h = __float2bfloat16(s3 * inv); o[d3] = *(unsigned short*)&h; }
}

// ---------------------------------------------------------------------------
// bf16 NT MFMA GEMM: C(M,N) = scale * A(M,K)@B(Npad,K)^T + bias
// block: 64 rows x 256 cols (4 waves, each a 64-col strip, 4x4 16x16 tiles)
// M, K multiples of 64. Output fp32 (outF) or bf16 (outH), cols n < Nw.
__global__ __launch_bounds__(256) void gemm_bf(const unsigned short* __restrict__ A, int lda,
                                               const unsigned short* __restrict__ Bm, int ldb,
                                               int Npad, int K,
                                               const float* __restrict__ bias, int Nb,
                                               float scale,
                                               float* __restrict__ outF,
                                               unsigned short* __restrict__ outH,
                                               int rs, int coloff, int Nw) {
    const int tid = threadIdx.x;
    const int m0 = blockIdx.x * 64, n0 = blockIdx.y * 256;
    const int lane = tid & 63, w = tid >> 6, c = lane & 15, q = lane >> 4;
    __shared__ __align__(16) unsigned short As[64 * 72];
    __shared__ __align__(16) unsigned short Bs[256 * 72];
    f32x4 acc[4][4];
    #pragma unroll
    for (int i = 0; i < 4; ++i)
        #pragma unroll
        for (int j = 0; j < 4; ++j) acc[i][j] = (f32x4){0.f, 0.f, 0.f, 0.f};

    const int row8 = tid >> 3, col8 = (tid & 7) * 8;
    for (int kk = 0; kk < K; kk += 64) {
        #pragma unroll
        for (int p = 0; p < 2; ++p) {
            int row = row8 + p * 32;
            *(uint4*)&As[row * 72 + col8] =
                *(const uint4*)&A[(size_t)(m0 + row) * lda + kk + col8];
        }
        #pragma unroll
        for (int p = 0; p < 8; ++p) {
            int row = row8 + p * 32;
            uint4 v = make_uint4(0u, 0u, 0u, 0u);
            if (n0 + row < Npad)
                v = *(const uint4*)&Bm[(size_t)(n0 + row) * ldb + kk + col8];
            *(uint4*)&Bs[row * 72 + col8] = v;
        }
        __syncthreads();
        #pragma unroll
        for (int ks = 0; ks < 2; ++ks) {
            int kc = ks * 32;
            FragU af[4];
            #pragma unroll
            for (int i = 0; i < 4; ++i)
                af[i].q = *(const uint4*)&As[(i * 16 + c) * 72 + kc + q * 8];
            #pragma unroll
            for (int j = 0; j < 4; ++j) {
                FragU bf;
                bf.q = *(const uint4*)&Bs[(w * 64 + j * 16 + c) * 72 + kc + q * 8];
                #pragma unroll
                for (int i = 0; i < 4; ++i)
                    acc[i][j] = __builtin_amdgcn_mfma_f32_16x16x32_bf16(af[i].s, bf.s,
                                                                        acc[i][j], 0, 0, 0);
            }
        }
        __syncthreads();
    }
    #pragma unroll
    for (int i = 0; i < 4; ++i) {
        #pragma unroll
        for (int r = 0; r < 4; ++r) {
            int m = m0 + i * 16 + q * 4 + r;
            #pragma unroll
            for (int j = 0; j < 4; ++j) {
                int n = n0 + w * 64 + j * 16 + c;
                if (n >= Nw) continue;
                float v = scale * acc[i][j][r];
                if (bias && n < Nb) v += bias[n];
                size_t o = (size_t)m * rs + coloff + n;
                if (outH) {
                    __hip_bfloat16 h = __float2bfloat16(v);
                    outH[o] = *(unsigned short*)&h;
                } else {
                    outF[o] = v;
                }
            }
        }
    }
}

// ---------------------------------------------------------------------------
// conv1d as implicit-GEMM bf16 MFMA. kk = ci*KP + k. Wt pre-transformed
// [Co_pad][Ci*KP] bf16 zero-padded. Block: 64 co x 256 t. Per kk64-chunk stages
// CIPC ci-rows x 272 t window; B-frags assembled with alignbit (2B shifts).
template <int KP>
__global__ __launch_bounds__(256) void conv_mfma(const unsigned short* __restrict__ xin,
                                                 int Ci, int Lp,
                                                 const unsigned short* __restrict__ Wt, int KK,
                                                 int nchunk,
                                                 const float* __restrict__ bias, int Co,
                                                 unsigned short* __restrict__ yout,
                                                 int Lout, int LoutPad,
                                                 float* __restrict__ pool, int pool_coloff) {
    constexpr int CIPC = 64 / KP;
    constexpr int LG = (KP == 8) ? 3 : 4;
    const int tid = threadIdx.x;
    const int b = blockIdx.z, co0 = blockIdx.y * 64, t0 = blockIdx.x * 256;
    const int lane = tid & 63, w = tid >> 6, c = lane & 15, q = lane >> 4;
    __shared__ __align__(16) unsigned short As[64 * 72];
    __shared__ __align__(16) unsigned short xraw[CIPC * 272];
    f32x4 acc[4][4];
    #pragma unroll
    for (int i = 0; i < 4; ++i)
        #pragma unroll
        for (int j = 0; j < 4; ++j) acc[i][j] = (f32x4){0.f, 0.f, 0.f, 0.f};

    const int row8 = tid >> 3, col8 = (tid & 7) * 8;
    for (int ch = 0; ch < nchunk; ++ch) {
        const int kkbase = ch * 64, ci0 = ch * CIPC;
        #pragma unroll
        for (int p = 0; p < 2; ++p) {
            int row = row8 + p * 32;
            *(uint4*)&As[row * 72 + col8] =
                *(const uint4*)&Wt[(size_t)(co0 + row) * KK + kkbase + col8];
        }
        for (int gi = tid; gi < CIPC * 34; gi += 256) {
            int ci = gi / 34, g8 = (gi % 34) * 8, gt = t0 + g8;
            const unsigned short* src = xin + ((size_t)b * Ci + ci0 + ci) * Lp + gt;
            if (gt + 8 <= Lp) {
                *(uint4*)&xraw[ci * 272 + g8] = *(const uint4*)src;
            } else {
                #pragma unroll
                for (int jj = 0; jj < 8; ++jj)
                    xraw[ci * 272 + g8 + jj] = (gt + jj < Lp) ? src[jj] : (unsigned short)0;
            }
        }
        __syncthreads();
        #pragma unroll
        for (int ks = 0; ks < 2; ++ks) {
            const int kc = ks * 32;
            FragU af[4];
            #pragma unroll
            for (int i = 0; i < 4; ++i)
                af[i].q = *(const uint4*)&As[(i * 16 + c) * 72 + kc + q * 8];
            const int koff = kc + q * 8;
            const int cioff = koff >> LG;
            const int k0 = koff & (KP - 1);
            const uint32_t* xr = (const uint32_t*)xraw + cioff * 136;
            #pragma unroll
            for (int j = 0; j < 4; ++j) {
                int tt = w * 64 + j * 16 + c;
                int eoff = tt + k0;
                int d0 = eoff >> 1;
                unsigned sh = (unsigned)(eoff & 1) * 16u;
                uint32_t u0 = xr[d0], u1 = xr[d0 + 1], u2 = xr[d0 + 2],
                         u3 = xr[d0 + 3], u4 = xr[d0 + 4];
                FragU bf;
                bf.u[0] = __builtin_amdgcn_alignbit(u1, u0, sh);
                bf.u[1] = __builtin_amdgcn_alignbit(u2, u1, sh);
                bf.u[2] = __builtin_amdgcn_alignbit(u3, u2, sh);
                bf.u[3] = __builtin_amdgcn_alignbit(u4, u3, sh);
                #pragma unroll
                for (int i = 0; i < 4; ++i)
                    acc[i][j] = __builtin_amdgcn_mfma_f32_16x16x32_bf16(af[i].s, bf.s,
                                                                        acc[i][j], 0, 0, 0);
            }
        }
        __syncthreads();
    }
    if (pool) {
        #pragma unroll
        for (int i = 0; i < 4; ++i) {
            #pragma unroll
            for (int r = 0; r < 4; ++r) {
                int co = co0 + i * 16 + q * 4 + r;
                float bv = (co < Co) ? bias[co] : 0.f;
                float v = 0.f;
                #pragma unroll
                for (int j = 0; j < 4; ++j) {
                    int t = t0 + w * 64 + j * 16 + c;
                    if (t < Lout) v = fmaxf(v, fmaxf(acc[i][j][r] + bv, 0.f));
                }
                v = fmaxf(v, __shfl_xor(v, 1));
                v = fmaxf(v, __shfl_xor(v, 2));
                v = fmaxf(v, __shfl_xor(v, 4));
                v = fmaxf(v, __shfl_xor(v, 8));
                if (c == 0 && co < Co)
                    atomicMax((int*)&pool[(size_t)b * 1420 + pool_coloff + co],
                              __float_as_int(v));
            }
        }
    } else {
        #pragma unroll
        for (int i = 0; i < 4; ++i) {
            #pragma unroll
            for (int r = 0; r < 4; ++r) {
                int co = co0 + i * 16 + q * 4 + r;
                if (co >= Co) continue;
                float bv = bias[co];
                #pragma unroll
                for (int j = 0; j < 4; ++j) {
                    int t = t0 + w * 64 + j * 16 + c;
                    if (t < Lout) {
                        __hip_bfloat16 h = __float2bfloat16(fmaxf(acc[i][j][r] + bv, 0.f));
                        yout[((size_t)b * Co + co) * LoutPad + t] = *(unsigned short*)&h;
                    } else if (t < LoutPad) {
                        yout[((size_t)b * Co + co) * LoutPad + t] = 0;
                    }
                }
            }
        }
    }
}

// ---------------------------------------------------------------------------
// fp32 NT-SGEMM (FC head), mode 2 = split-K atomic into C[m*N+n]
__global__ __launch_bounds__(256) void gemm_nt(const float* __restrict__ A, int lda,
                                               const float* __restrict__ Bm,
                                               float* __restrict__ Cout,
                                               int M, int N, int K, int KC) {
    const int m0 = blockIdx.x * 64, n0 = blockIdx.y * 64, s = blockIdx.z;
    const int tid = threadIdx.x, ty = tid >> 4, tx = tid & 15;
    __shared__ __align__(16) float As[16][68];
    __shared__ __align__(16) float Bs[16][68];
    float acc[4][4] = {};
    const int kbeg = s * KC, kend = min(K, kbeg + KC);
    for (int k0 = kbeg; k0 < kend; k0 += 16) {
        int colk = k0 + tx;
        bool kok = colk < kend;
        #pragma unroll
        for (int qq = 0; qq < 4; ++qq) {
            int mi = ty + qq * 16;
            As[tx][mi] = (kok && (m0 + mi) < M) ? A[(size_t)(m0 + mi) * lda + colk] : 0.f;
            Bs[tx][mi] = (kok && (n0 + mi) < N) ? Bm[(size_t)(n0 + mi) * K + colk] : 0.f;
        }
        __syncthreads();
        #pragma unroll
        for (int kk = 0; kk < 16; ++kk) {
            float4 a4 = *(const float4*)&As[kk][ty * 4];
            float4 b4 = *(const float4*)&Bs[kk][tx * 4];
            float av[4] = {a4.x, a4.y, a4.z, a4.w};
            float bv[4] = {b4.x, b4.y, b4.z, b4.w};
            #pragma unroll
            for (int i = 0; i < 4; ++i)
                #pragma unroll
                for (int j = 0; j < 4; ++j)
                    acc[i][j] = fmaf(av[i], bv[j], acc[i][j]);
        }
        __syncthreads();
    }
    #pragma unroll
    for (int i = 0; i < 4; ++i) {
        int m = m0 + ty * 4 + i;
        if (m >= M) continue;
        #pragma unroll
        for (int j = 0; j < 4; ++j) {
            int n = n0 + tx * 4 + j;
            if (n >= N) continue;
            atomicAdd(&Cout[(size_t)m * N + n], acc[i][j]);
        }
    }
}

__global__ void epilogue_k(const float* __restrict__ C, const float* __restrict__ bias,
                           float* __restrict__ out, int M, int N, int act) {
    int idx = blockIdx.x * 256 + threadIdx.x;
    if (idx >= M * N) return;
    int m = idx / N, n = idx % N;
    float v = C[idx] + bias[n];
    if (act == 2) v = v >= 0.f ? v : 0.01f * v;
    out[(size_t)m * N + n] = v;
}

__global__ void out_k(const float* __restrict__ h3, const float* __restrict__ W,
                      const float* __restrict__ bias, float* __restrict__ out) {
    int tid = threadIdx.x;
    if (tid >= 128) return;
    int b = tid >> 1, n = tid & 1;
    const float* hr = h3 + (size_t)b * 512;
    const float* wr = W + (size_t)n * 512;
    float a = 0.f;
    for (int k = 0; k < 512; ++k) a = fmaf(hr[k], wr[k], a);
    out[b * 2 + n] = a + bias[n];
}

// ---------------------------------------------------------------------------
static inline int kc_of(int K, int S) { return ((K + S * 16 - 1) / (S * 16)) * 16; }
static inline dim3 g1d(int n) { return dim3((n + 255) / 256); }

extern "C" void kernel_launch(void* const* d_in, const int* in_sizes, int n_in,
                              void* d_out, int out_size, void* d_ws, size_t ws_size,
                              hipStream_t stream) {
    const int* drug_tokens       = (const int*)d_in[0];
    const int* protein_tokens    = (const int*)d_in[1];
    const int* drug_node_tokens  = (const int*)d_in[2];
    const int* protein_node_toks = (const int*)d_in[3];
    const int* ddi_edges         = (const int*)d_in[4];
    const int* ppi_edges         = (const int*)d_in[5];
    const int* dpi_edges         = (const int*)d_in[6];
    const float* drug_embed      = (const float*)d_in[7];
    const float* protein_embed   = (const float*)d_in[8];
    const float* dW1 = (const float*)d_in[9];  const float* db1 = (const float*)d_in[10];
    const float* dW2 = (const float*)d_in[11]; const float* db2 = (const float*)d_in[12];
    const float* dW3 = (const float*)d_in[13]; const float* db3 = (const float*)d_in[14];
    const float* pW1 = (const float*)d_in[15]; const float* pb1 = (const float*)d_in[16];
    const float* pW2 = (const float*)d_in[17]; const float* pb2 = (const float*)d_in[18];
    const float* pW3 = (const float*)d_in[19]; const float* pb3 = (const float*)d_in[20];
    const float* drug_node_table = (const float*)d_in[21];
    const float* prot_node_table = (const float*)d_in[22];
    const float* ddi_Wl = (const float*)d_in[23]; const float* ddi_bl = (const float*)d_in[24];
    const float* ddi_Wr = (const float*)d_in[25];
    const float* ppi_Wl = (const float*)d_in[26]; const float* ppi_bl = (const float*)d_in[27];
    const float* ppi_Wr = (const float*)d_in[28];
    const float* dpi_Wl = (const float*)d_in[29]; const float* dpi_bl = (const float*)d_in[30];
    const float* dpi_Wr = (const float*)d_in[31];
    const float* pdi_Wl = (const float*)d_in[32]; const float* pdi_bl = (const float*)d_in[33];
    const float* pdi_Wr = (const float*)d_in[34];
    const float* fc1_W = (const float*)d_in[35]; const float* fc1_b = (const float*)d_in[36];
    const float* fc2_W = (const float*)d_in[37]; const float* fc2_b = (const float*)d_in[38];
    const float* fc3_W = (const float*)d_in[39]; const float* fc3_b = (const float*)d_in[40];
    const float* out_W = (const float*)d_in[41]; const float* out_b = (const float*)d_in[42];

    float* outp = (float*)d_out;
    if (ws_size < NEED_BYTES) {  // clean failure instead of corruption
        zero32_k<<<g1d(out_size), 256, 0, stream>>>((uint32_t*)outp, out_size);
        return;
    }
    char* wsb = (char*)d_ws;
    float* pair = (float*)(wsb + O_PAIR);
    float* cf1 = (float*)(wsb + O_CF1); float* cf2 = (float*)(wsb + O_CF2);
    float* cf3 = (float*)(wsb + O_CF3);
    float* h1 = (float*)(wsb + O_H1); float* h2 = (float*)(wsb + O_H2);
    float* h3 = (float*)(wsb + O_H3);
    float* bd = (float*)(wsb + O_BD); float* bp = (float*)(wsb + O_BP);
    unsigned short* Wd   = (unsigned short*)(wsb + O_WD);
    unsigned short* Wp   = (unsigned short*)(wsb + O_WP);
    unsigned short* pdiB = (unsigned short*)(wsb + O_PDIB);
    unsigned short* WtP1 = (unsigned short*)(wsb + O_WTP1);
    unsigned short* WtP2 = (unsigned short*)(wsb + O_WTP2);
    unsigned short* WtP3 = (unsigned short*)(wsb + O_WTP3);
    unsigned short* WtD1 = (unsigned short*)(wsb + O_WTD1);
    unsigned short* WtD2 = (unsigned short*)(wsb + O_WTD2);
    unsigned short* WtD3 = (unsigned short*)(wsb + O_WTD3);
    unsigned short* Xp  = (unsigned short*)(wsb + O_XP);
    unsigned short* Xd  = (unsigned short*)(wsb + O_XD);
    unsigned short* zpd = (unsigned short*)(wsb + O_ZPD);
    unsigned short* px1 = (unsigned short*)(wsb + O_PX1);
    unsigned short* dx1 = (unsigned short*)(wsb + O_DX1);
    unsigned short* Xp2 = (unsigned short*)(wsb + O_XP2);
    unsigned short* Xd2 = (unsigned short*)(wsb + O_XD2);
    unsigned short* a2pd = (unsigned short*)(wsb + O_A2PD);
    unsigned short* x0p = (unsigned short*)(wsb + O_X0P);
    unsigned short* y1p = (unsigned short*)(wsb + O_Y1P);
    unsigned short* y2p = (unsigned short*)(wsb + O_Y2P);
    unsigned short* x0d = (unsigned short*)(wsb + O_X0D);
    unsigned short* y1d = (unsigned short*)(wsb + O_Y1D);
    unsigned short* y2d = (unsigned short*)(wsb + O_Y2D);

    // 0) zero: fp32 accum region; Xp+Xd; Xp2+Xd2
    zero32_k<<<g1d(Z1_END / 4), 256, 0, stream>>>((uint32_t*)wsb, Z1_END / 4);
    zero32_k<<<g1d(10485760 / 4), 256, 0, stream>>>((uint32_t*)(wsb + O_XP), 10485760 / 4);
    zero32_k<<<g1d(327680 / 4), 256, 0, stream>>>((uint32_t*)(wsb + O_XP2), 327680 / 4);

    // 1) weight prep
    addsc_k<<<g1d(100), 256, 0, stream>>>(bd, ddi_bl, pdi_bl, 0.5f, 100);
    addsc_k<<<g1d(1000), 256, 0, stream>>>(bp, ppi_bl, dpi_bl, 0.5f, 1000);
    wtcvt_k<<<g1d(128 * 128), 256, 0, stream>>>(Wd, 384, 0, 128, ddi_Wl, nullptr, 100, 100, 100, 128);
    wtcvt_k<<<g1d(128 * 128), 256, 0, stream>>>(Wd, 384, 128, 128, ddi_Wr, pdi_Wr, 100, 100, 100, 128);
    ident_k<<<g1d(128 * 128), 256, 0, stream>>>(Wd);
    wtcvt_k<<<g1d(1024 * 1024), 256, 0, stream>>>(Wp, 2176, 0, 1024, ppi_Wl, nullptr, 1000, 1000, 1000, 1024);
    wtcvt_k<<<g1d(1024 * 1024), 256, 0, stream>>>(Wp, 2176, 1024, 1024, ppi_Wr, dpi_Wr, 1000, 1000, 1000, 1024);
    wtcvt_k<<<g1d(1024 * 128), 256, 0, stream>>>(Wp, 2176, 2048, 1024, dpi_Wl, nullptr, 100, 1000, 100, 128);
    wtcvt_k<<<g1d(128 * 1024), 256, 0, stream>>>(pdiB, 1024, 0, 128, pdi_Wl, nullptr, 1000, 100, 1000, 1024);
    wtconv_k<<<g1d(64 * 64 * 8), 256, 0, stream>>>(WtP1, pW1, 64, 40, 64, 4, 8);
    wtconv_k<<<g1d(128 * 40 * 8), 256, 0, stream>>>(WtP2, pW2, 128, 80, 40, 8, 8);
    wtconv_k<<<g1d(192 * 80 * 16), 256, 0, stream>>>(WtP3, pW3, 192, 160, 80, 12, 16);
    wtconv_k<<<g1d(64 * 64 * 8), 256, 0, stream>>>(WtD1, dW1, 64, 40, 64, 4, 8);
    wtconv_k<<<g1d(128 * 40 * 8), 256, 0, stream>>>(WtD2, dW2, 128, 80, 40, 6, 8);
    wtconv_k<<<g1d(192 * 80 * 8), 256, 0, stream>>>(WtD3, dW3, 192, 160, 80, 8, 8);

    // 2) node features into concat blocks: Xd[:,128:]=dx0, Xp[:,1024:]=px0
    node_feat_k<<<dim3(32, 64), 256, 0, stream>>>(drug_node_tokens, drug_node_table, 71, 100, Xd, 384, 128);
    node_feat_k<<<dim3(32, 64), 256, 0, stream>>>(protein_node_toks, prot_node_table, 26, 1000, Xp, 2176, 1024);

    // 3) layer-1 aggregations
    segmean_k<<<dim3(32, 64), 256, 0, stream>>>(Xd + 128, 384, ddi_edges, 256, 0, 128, 128, 128, 32, Xd, 384, 0);
    segmean_k<<<dim3(32, 64), 256, 0, stream>>>(Xp + 1024, 2176, ppi_edges, 256, 0, 128, 128, 1024, 32, Xp, 2176, 0);
    segmean_k<<<dim3(32, 64), 256, 0, stream>>>(Xd + 128, 384, dpi_edges, 128, 0, 64, 64, 128, 32, Xp, 2176, 2048);
    // pdi: transform px0 then aggregate
    gemm_bf<<<dim3(32, 1), 256, 0, stream>>>(Xp + 1024, 2176, pdiB, 1024, 128, 1024,
                                             nullptr, 0, 1.f, nullptr, zpd, 128, 0, 128);
    segmean_k<<<dim3(32, 64), 256, 0, stream>>>(zpd, 128, dpi_edges, 128, 64, 0, 64, 128, 32, Xd, 384, 256);

    // 4) layer-1 updates (single concat GEMM per side)
    gemm_bf<<<dim3(32, 1), 256, 0, stream>>>(Xd, 384, Wd, 384, 128, 384,
                                             bd, 100, 0.5f, nullptr, dx1, 128, 0, 128);
    gemm_bf<<<dim3(32, 4), 256, 0, stream>>>(Xp, 2176, Wp, 2176, 1024, 2176,
                                             bp, 1000, 0.5f, nullptr, px1, 1024, 0, 1024);

    // 5) layer-2 (node 0 only)
    segmean_k<<<dim3(1, 64), 256, 0, stream>>>(dx1, 128, ddi_edges, 256, 0, 128, 128, 128, 1, Xd2, 384, 0);
    segmean_k<<<dim3(1, 64), 256, 0, stream>>>(px1, 1024, ppi_edges, 256, 0, 128, 128, 1024, 1, Xp2, 2176, 0);
    segmean_k<<<dim3(1, 64), 256, 0, stream>>>(dx1, 128, dpi_edges, 128, 0, 64, 64, 128, 1, Xp2, 2176, 2048);
    segmean_k<<<dim3(1, 64), 256, 0, stream>>>(px1, 1024, dpi_edges, 128, 64, 0, 64, 1024, 1, a2pd, 1024, 0);
    copy_rows_k<<<dim3(64), 256, 0, stream>>>(dx1, 128, Xd2, 384, 128, 128);
    copy_rows_k<<<dim3(64), 256, 0, stream>>>(px1, 1024, Xp2, 2176, 1024, 1024);
    gemm_bf<<<dim3(1, 1), 256, 0, stream>>>(a2pd, 1024, pdiB, 1024, 128, 1024,
                                            nullptr, 0, 1.f, nullptr, Xd2, 384, 256, 128);
    gemm_bf<<<dim3(1, 1), 256, 0, stream>>>(Xd2, 384, Wd, 384, 128, 384,
                                            bd, 100, 0.5f, pair, nullptr, 1420, 320, 100);
    gemm_bf<<<dim3(1, 4), 256, 0, stream>>>(Xp2, 2176, Wp, 2176, 1024, 2176,
                                            bp, 1000, 0.5f, pair, nullptr, 1420, 420, 1000);

    // 6) conv towers (aliased region; GNN results already in pair)
    embed_k<<<dim3(64, 8), 256, 0, stream>>>(protein_tokens, protein_embed, x0p, 1000, 1000);
    conv_mfma<8><<<dim3(4, 1, 64), 256, 0, stream>>>(x0p, 64, 1000, WtP1, 512, 8,
                                                     pb1, 40, y1p, 997, 1000, nullptr, 0);
    conv_mfma<8><<<dim3(4, 2, 64), 256, 0, stream>>>(y1p, 40, 1000, WtP2, 320, 5,
                                                     pb2, 80, y2p, 990, 992, nullptr, 0);
    conv_mfma<16><<<dim3(4, 3, 64), 256, 0, stream>>>(y2p, 80, 992, WtP3, 1280, 20,
                                                      pb3, 160, nullptr, 979, 0, pair, 160);
    embed_k<<<dim3(64, 8), 256, 0, stream>>>(drug_tokens, drug_embed, x0d, 100, 104);
    conv_mfma<8><<<dim3(1, 1, 64), 256, 0, stream>>>(x0d, 64, 104, WtD1, 512, 8,
                                                     db1, 40, y1d, 97, 104, nullptr, 0);
    conv_mfma<8><<<dim3(1, 2, 64), 256, 0, stream>>>(y1d, 40, 104, WtD2, 320, 5,
                                                     db2, 80, y2d, 92, 96, nullptr, 0);
    conv_mfma<8><<<dim3(1, 3, 64), 256, 0, stream>>>(y2d, 80, 96, WtD3, 640, 10,
                                                     db3, 160, nullptr, 85, 0, pair, 0);

    // 7) FC head (fp32)
    gemm_nt<<<dim3(1, 16, 4), 256, 0, stream>>>(pair, 1420, fc1_W, cf1, 64, 1024, 1420, kc_of(1420, 4));
    epilogue_k<<<g1d(64 * 1024), 256, 0, stream>>>(cf1, fc1_b, h1, 64, 1024, 2);
    gemm_nt<<<dim3(1, 16, 4), 256, 0, stream>>>(h1, 1024, fc2_W, cf2, 64, 1024, 1024, kc_of(1024, 4));
    epilogue_k<<<g1d(64 * 1024), 256, 0, stream>>>(cf2, fc2_b, h2, 64, 1024, 2);
    gemm_nt<<<dim3(1, 8, 4), 256, 0, stream>>>(h2, 1024, fc3_W, cf3, 64, 512, 1024, kc_of(1024, 4));
    epilogue_k<<<g1d(64 * 512), 256, 0, stream>>>(cf3, fc3_b, h3, 64, 512, 2);
    out_k<<<dim3(1), 128, 0, stream>>>(h3, out_W, out_b, outp);
}

// Round 4
// 890.533 us; speedup vs baseline: 3.7335x; 1.1870x over previous
//
#include <hip/hip_runtime.h>
#include <hip/hip_bf16.h>

// ---------------------------------------------------------------------------
// SSGraphDTI forward. Heavy compute in bf16 MFMA (16x16x32), FC head fp32.
// B=64, ND=NPR=32, LD=100, LP=1000, DIM=64, CONV=40
// R4: skinny-M GEMMs get dedicated high-parallelism kernel (layer-2 was 4
// blocks / 129us); weight prep fused into one launch.
// ---------------------------------------------------------------------------

typedef __attribute__((ext_vector_type(8))) short short8;
typedef __attribute__((ext_vector_type(4))) float f32x4;
union FragU { uint32_t u[4]; uint4 q; short8 s; };

// ---------------- workspace layout (byte offsets) ----------------
static constexpr size_t O_PAIR = 0;          // 64*1420 f32 = 363,520
static constexpr size_t O_CF1  = 363520;     // 64*1024 f32
static constexpr size_t O_CF2  = 625664;
static constexpr size_t O_CF3  = 887808;     // 64*512 f32
static constexpr size_t O_H1   = 1018880;
static constexpr size_t O_H2   = 1281024;
static constexpr size_t O_H3   = 1543168;    // 64*512 f32
static constexpr size_t O_BD   = 1674240;    // 128 f32
static constexpr size_t O_BP   = 1674752;    // 1024 f32
static constexpr size_t O_T    = 1678848;    // 64x128 f32 (a2pd-transform temp)
static constexpr size_t Z1_END = 1711616;    // zero span [0, Z1_END)
static constexpr size_t O_WD   = 1711616;    // 128x384 bf16
static constexpr size_t O_WP   = 1809920;    // 1024x2176 bf16
static constexpr size_t O_PDIB = 6266368;    // 128x1024 bf16
static constexpr size_t O_WTP1 = 6528512;    // 64x512 bf16
static constexpr size_t O_WTP2 = 6594048;    // 128x320 bf16
static constexpr size_t O_WTP3 = 6675968;    // 192x1280 bf16
static constexpr size_t O_WTD1 = 7167488;    // 64x512 bf16
static constexpr size_t O_WTD2 = 7233024;    // 128x320 bf16
static constexpr size_t O_WTD3 = 7314944;    // 192x640 bf16
static constexpr size_t AR     = 7560704;    // aliased region base
// GNN phase (within AR):
static constexpr size_t O_XP   = AR + 0;          // 2048x2176 bf16 = 8,912,896
static constexpr size_t O_XD   = AR + 8912896;    // 2048x384 bf16
static constexpr size_t O_ZPD  = AR + 10485760;   // 2048x128 bf16
static constexpr size_t O_PX1  = AR + 11010048;   // 2048x1024 bf16
static constexpr size_t O_DX1  = AR + 15204352;   // 2048x128 bf16
static constexpr size_t O_XP2  = AR + 15728640;   // 64x2176 bf16
static constexpr size_t O_XD2  = AR + 16007168;   // 64x384 bf16
static constexpr size_t O_A2PD = AR + 16056320;   // 64x1024 bf16 -> 16,187,392
// conv phase aliases (GNN dead):
static constexpr size_t O_X0P  = AR + 0;          // 64x64x1000 bf16 = 8,192,000
static constexpr size_t O_Y1P  = AR + 8192000;    // 64x40x1000 bf16 = 5,120,000
static constexpr size_t O_Y2P  = AR + 0;          // 64x80x992 bf16 (x0p dead)
static constexpr size_t O_X0D  = AR + 13312000;   // 64x64x104 bf16
static constexpr size_t O_Y1D  = AR + 14163968;   // 64x40x104 bf16
static constexpr size_t O_Y2D  = AR + 14696448;   // 64x80x96 bf16 -> 15,679,488
static constexpr size_t NEED_BYTES = AR + 16187392;  // 23,748,096

// ---------------------------------------------------------------------------
__global__ void zero32_k(uint32_t* __restrict__ p, int n) {
    int i = blockIdx.x * 256 + threadIdx.x;
    if (i < n) p[i] = 0u;
}

// ---------------- fused weight prep ----------------
// range table (element counts, cumulative)
static constexpr long PC0 = 100;                 // bd
static constexpr long PC1 = PC0 + 1000;          // bp
static constexpr long PC2 = PC1 + 16384;         // Wd cols[0:128)
static constexpr long PC3 = PC2 + 16384;         // Wd cols[128:256)
static constexpr long PC4 = PC3 + 16384;         // Wd ident [256:384)
static constexpr long PC5 = PC4 + 1048576;       // Wp cols[0:1024)
static constexpr long PC6 = PC5 + 1048576;       // Wp cols[1024:2048)
static constexpr long PC7 = PC6 + 131072;        // Wp cols[2048:2176)
static constexpr long PC8 = PC7 + 131072;        // pdiB
static constexpr long PC9 = PC8 + 32768;         // WtP1
static constexpr long PC10 = PC9 + 40960;        // WtP2
static constexpr long PC11 = PC10 + 245760;      // WtP3
static constexpr long PC12 = PC11 + 32768;       // WtD1
static constexpr long PC13 = PC12 + 40960;       // WtD2
static constexpr long PC14 = PC13 + 122880;      // WtD3

__device__ inline void wt_block(unsigned short* dst, int ld_dst, int coloff,
                                const float* s1, const float* s2, int ld_src,
                                int N, int Kreal, int Kblk, long local) {
    int n = (int)(local / Kblk), k = (int)(local % Kblk);
    float v = 0.f;
    if (n < N && k < Kreal) {
        v = s1[(size_t)n * ld_src + k];
        if (s2) v += s2[(size_t)n * ld_src + k];
    }
    __hip_bfloat16 h = __float2bfloat16(v);
    dst[(size_t)n * ld_dst + coloff + k] = *(unsigned short*)&h;
}

__device__ inline void wtconv_block(unsigned short* dst, const float* W,
                                    int Co, int Ci, int K, int KP, long local) {
    int co = (int)(local / (Ci * KP));
    int rem = (int)(local % (Ci * KP));
    int ci = rem / KP, k = rem % KP;
    float v = (co < Co && k < K) ? W[((size_t)co * Ci + ci) * K + k] : 0.f;
    __hip_bfloat16 h = __float2bfloat16(v);
    dst[local] = *(unsigned short*)&h;
}

__global__ __launch_bounds__(256) void prep_k(
    float* bd, float* bp, unsigned short* Wd, unsigned short* Wp,
    unsigned short* pdiB,
    unsigned short* WtP1, unsigned short* WtP2, unsigned short* WtP3,
    unsigned short* WtD1, unsigned short* WtD2, unsigned short* WtD3,
    const float* ddi_Wl, const float* ddi_bl, const float* ddi_Wr,
    const float* ppi_Wl, const float* ppi_bl, const float* ppi_Wr,
    const float* dpi_Wl, const float* dpi_bl, const float* dpi_Wr,
    const float* pdi_Wl, const float* pdi_bl, const float* pdi_Wr,
    const float* dW1, const float* dW2, const float* dW3,
    const float* pW1, const float* pW2, const float* pW3) {
    long idx = (long)blockIdx.x * 256 + threadIdx.x;
    if (idx < PC0) { bd[idx] = 0.5f * (ddi_bl[idx] + pdi_bl[idx]); return; }
    if (idx < PC1) { long j = idx - PC0; bp[j] = 0.5f * (ppi_bl[j] + dpi_bl[j]); return; }
    if (idx < PC2) { wt_block(Wd, 384, 0, ddi_Wl, nullptr, 100, 100, 100, 128, idx - PC1); return; }
    if (idx < PC3) { wt_block(Wd, 384, 128, ddi_Wr, pdi_Wr, 100, 100, 100, 128, idx - PC2); return; }
    if (idx < PC4) {
        long l = idx - PC3; int n = (int)(l / 128), k = (int)(l % 128);
        __hip_bfloat16 h = __float2bfloat16((n == k && n < 100) ? 1.f : 0.f);
        Wd[(size_t)n * 384 + 256 + k] = *(unsigned short*)&h; return;
    }
    if (idx < PC5) { wt_block(Wp, 2176, 0, ppi_Wl, nullptr, 1000, 1000, 1000, 1024, idx - PC4); return; }
    if (idx < PC6) { wt_block(Wp, 2176, 1024, ppi_Wr, dpi_Wr, 1000, 1000, 1000, 1024, idx - PC5); return; }
    if (idx < PC7) { wt_block(Wp, 2176, 2048, dpi_Wl, nullptr, 100, 1000, 100, 128, idx - PC6); return; }
    if (idx < PC8) { wt_block(pdiB, 1024, 0, pdi_Wl, nullptr, 1000, 100, 1000, 1024, idx - PC7); return; }
    if (idx < PC9)  { wtconv_block(WtP1, pW1, 40, 64, 4, 8, idx - PC8); return; }
    if (idx < PC10) { wtconv_block(WtP2, pW2, 80, 40, 8, 8, idx - PC9); return; }
    if (idx < PC11) { wtconv_block(WtP3, pW3, 160, 80, 12, 16, idx - PC10); return; }
    if (idx < PC12) { wtconv_block(WtD1, dW1, 40, 64, 4, 8, idx - PC11); return; }
    if (idx < PC13) { wtconv_block(WtD2, dW2, 80, 40, 6, 8, idx - PC12); return; }
    if (idx < PC14) { wtconv_block(WtD3, dW3, 160, 80, 8, 8, idx - PC13); return; }
}

// pre-fill layer-2 bias into pair cols [320:1420) (skinny gemms atomicAdd on top)
__global__ void biasfill_k(float* __restrict__ pair, const float* __restrict__ bd,
                           const float* __restrict__ bp) {
    int idx = blockIdx.x * 256 + threadIdx.x;
    if (idx >= 64 * 1100) return;
    int b = idx / 1100, j = idx % 1100;
    if (j < 100) pair[(size_t)b * 1420 + 320 + j] = bd[j];
    else pair[(size_t)b * 1420 + 420 + (j - 100)] = bp[j - 100];
}

// fp32 temp -> bf16 into Xd2 cols [256:384)
__global__ void cvtT_k(const float* __restrict__ T, unsigned short* __restrict__ Xd2) {
    int idx = blockIdx.x * 256 + threadIdx.x;
    if (idx >= 64 * 128) return;
    int b = idx / 128, k = idx % 128;
    __hip_bfloat16 h = __float2bfloat16(T[idx]);
    Xd2[(size_t)b * 384 + 256 + k] = *(unsigned short*)&h;
}

// copy layer-1 node-0 rows into layer-2 concat blocks
__global__ void copy_rows_k(const unsigned short* __restrict__ src, int lds,
                            unsigned short* __restrict__ dst, int ldo, int coloff, int n_el) {
    int b = blockIdx.x;
    for (int d = threadIdx.x; d < n_el; d += 256)
        dst[(size_t)b * ldo + coloff + d] = src[(size_t)b * 32 * lds + d];
}

// embedding lookup -> bf16 (B, 64, Lpad), zero pads
__global__ __launch_bounds__(256) void embed_k(const int* __restrict__ toks,
                                               const float* __restrict__ table,
                                               unsigned short* __restrict__ out,
                                               int L, int Lpad) {
    int b = blockIdx.x, c0 = blockIdx.y * 8;
    for (int t = threadIdx.x; t < Lpad; t += 256) {
        if (t < L) {
            int tk = toks[(size_t)b * L + t];
            #pragma unroll
            for (int c = 0; c < 8; ++c) {
                __hip_bfloat16 h = __float2bfloat16(table[(size_t)tk * 64 + c0 + c]);
                out[((size_t)b * 64 + c0 + c) * Lpad + t] = *(unsigned short*)&h;
            }
        } else {
            #pragma unroll
            for (int c = 0; c < 8; ++c)
                out[((size_t)b * 64 + c0 + c) * Lpad + t] = 0;
        }
    }
}

// bag-of-tokens node features via LDS histogram -> bf16 strided output
__global__ __launch_bounds__(256) void node_feat_k(const int* __restrict__ toks,
                                                   const float* __restrict__ table,
                                                   int V, int Lw,
                                                   unsigned short* __restrict__ out,
                                                   int ldo, int coloff) {
    const int b = blockIdx.y, n = blockIdx.x, tid = threadIdx.x;
    __shared__ int cnt[71];
    for (int v = tid; v < V; v += 256) cnt[v] = 0;
    __syncthreads();
    const int* t = toks + ((size_t)b * 32 + n) * Lw;
    for (int i = tid; i < Lw; i += 256) atomicAdd(&cnt[t[i]], 1);
    __syncthreads();
    float inv = 1.f / (float)Lw;
    unsigned short* o = out + ((size_t)b * 32 + n) * ldo + coloff;
    for (int d = tid; d < Lw; d += 256) {
        float a = 0.f;
        for (int v = 0; v < V; ++v) {
            int c = cnt[v];
            if (c) a += (float)c * table[(size_t)v * Lw + d];
        }
        __hip_bfloat16 h = __float2bfloat16(a * inv);
        o[d] = *(unsigned short*)&h;
    }
}

// segment-mean gather, bf16 in/out, fp32 accumulate
__global__ __launch_bounds__(256) void segmean_k(const unsigned short* __restrict__ x, int ldx,
                                                 const int* __restrict__ edges,
                                                 int E2, int srcrel, int dstrel, int E,
                                                 int D, int nout,
                                                 unsigned short* __restrict__ out,
                                                 int ldo, int coloff) {
    const int n = blockIdx.x, lb = blockIdx.y, tid = threadIdx.x;
    const int* eb = edges + (size_t)lb * E2;
    const unsigned short* xb = x + (size_t)lb * 32 * ldx;
    const int d0 = tid, d1 = tid + 256, d2 = tid + 512, d3 = tid + 768;
    float s0 = 0.f, s1 = 0.f, s2 = 0.f, s3 = 0.f;
    int cnt = 0;
    for (int e = 0; e < E; ++e) {
        if (eb[dstrel + e] == n) {
            ++cnt;
            const unsigned short* xr = xb + (size_t)eb[srcrel + e] * ldx;
            if (d0 < D) s0 += __bfloat162float(*(const __hip_bfloat16*)&xr[d0]);
            if (d1 < D) s1 += __bfloat162float(*(const __hip_bfloat16*)&xr[d1]);
            if (d2 < D) s2 += __bfloat162float(*(const __hip_bfloat16*)&xr[d2]);
            if (d3 < D) s3 += __bfloat162float(*(const __hip_bfloat16*)&xr[d3]);
        }
    }
    float inv = 1.f / (float)max(cnt, 1);
    unsigned short* o = out + ((size_t)lb * nout + n) * ldo + coloff;
    __hip_bfloat16 h;
    if (d0 < D) { h = __float2bfloat16(s0 * inv); o[d0] = *(unsigned short*)&h; }
    if (d1 < D) { h = __float2bfloat16(s1 * inv); o[d1] = *(unsigned short*)&h; }
    if (d2 < D) { h = __float2bfloat16(s2 * inv); o[d2] = *(unsigned short*)&h; }
    if (d3 < D) { h = __float2bfloat16(s3 * inv); o[d3] = *(unsigned short*)&h; }
}

// ---------------------------------------------------------------------------
// bf16 NT MFMA GEMM: C(M,N) = scale * A(M,K)@B(Npad,K)^T + bias
// block: 64 rows x 256 cols (4 waves, each a 64-col strip, 4x4 16x16 tiles)
__global__ __launch_bounds__(256) void gemm_bf(const unsigned short* __restrict__ A, int lda,
                                               const unsigned short* __restrict__ Bm, int ldb,
                                               int Npad, int K,
                                               const float* __restrict__ bias, int Nb,
                                               float scale,
                                               float* __restrict__ outF,
                                               unsigned short* __restrict__ outH,
                                               int rs, int coloff, int Nw) {
    const int tid = threadIdx.x;
    const int m0 = blockIdx.x * 64, n0 = blockIdx.y * 256;
    const int lane = tid & 63, w = tid >> 6, c = lane & 15, q = lane >> 4;
    __shared__ __align__(16) unsigned short As[64 * 72];
    __shared__ __align__(16) unsigned short Bs[256 * 72];
    f32x4 acc[4][4];
    #pragma unroll
    for (int i = 0; i < 4; ++i)
        #pragma unroll
        for (int j = 0; j < 4; ++j) acc[i][j] = (f32x4){0.f, 0.f, 0.f, 0.f};

    const int row8 = tid >> 3, col8 = (tid & 7) * 8;
    for (int kk = 0; kk < K; kk += 64) {
        #pragma unroll
        for (int p = 0; p < 2; ++p) {
            int row = row8 + p * 32;
            *(uint4*)&As[row * 72 + col8] =
                *(const uint4*)&A[(size_t)(m0 + row) * lda + kk + col8];
        }
        #pragma unroll
        for (int p = 0; p < 8; ++p) {
            int row = row8 + p * 32;
            uint4 v = make_uint4(0u, 0u, 0u, 0u);
            if (n0 + row < Npad)
                v = *(const uint4*)&Bm[(size_t)(n0 + row) * ldb + kk + col8];
            *(uint4*)&Bs[row * 72 + col8] = v;
        }
        __syncthreads();
        #pragma unroll
        for (int ks = 0; ks < 2; ++ks) {
            int kc = ks * 32;
            FragU af[4];
            #pragma unroll
            for (int i = 0; i < 4; ++i)
                af[i].q = *(const uint4*)&As[(i * 16 + c) * 72 + kc + q * 8];
            #pragma unroll
            for (int j = 0; j < 4; ++j) {
                FragU bf;
                bf.q = *(const uint4*)&Bs[(w * 64 + j * 16 + c) * 72 + kc + q * 8];
                #pragma unroll
                for (int i = 0; i < 4; ++i)
                    acc[i][j] = __builtin_amdgcn_mfma_f32_16x16x32_bf16(af[i].s, bf.s,
                                                                        acc[i][j], 0, 0, 0);
            }
        }
        __syncthreads();
    }
    #pragma unroll
    for (int i = 0; i < 4; ++i) {
        #pragma unroll
        for (int r = 0; r < 4; ++r) {
            int m = m0 + i * 16 + q * 4 + r;
            #pragma unroll
            for (int j = 0; j < 4; ++j) {
                int n = n0 + w * 64 + j * 16 + c;
                if (n >= Nw) continue;
                float v = scale * acc[i][j][r];
                if (bias && n < Nb) v += bias[n];
                size_t o = (size_t)m * rs + coloff + n;
                if (outH) {
                    __hip_bfloat16 h = __float2bfloat16(v);
                    outH[o] = *(unsigned short*)&h;
                } else {
                    outF[o] = v;
                }
            }
        }
    }
}

// ---------------------------------------------------------------------------
// skinny-M (M==64) bf16 MFMA GEMM with split-K:
// out[m*rs+coloff+n] += scale * (A(64,K)@B(Npad,K)^T)[m,n]   (fp32 atomics)
// grid (Npad/64, KS). 4 waves per block, wave w owns output cols [w*16,(w+1)*16).
// No LDS: A (tiny) stays L2-hot, B rows are block-disjoint.
__global__ __launch_bounds__(256) void gemm_skinny(const unsigned short* __restrict__ A, int lda,
                                                   const unsigned short* __restrict__ Bm, int ldb,
                                                   int K, int KS, float scale,
                                                   float* __restrict__ out,
                                                   int rs, int coloff, int Nw) {
    const int tid = threadIdx.x;
    const int lane = tid & 63, w = tid >> 6, c = lane & 15, q = lane >> 4;
    const int n = blockIdx.x * 64 + w * 16 + c;      // B row == output col
    const int Ks = ((K / KS + 31) / 32) * 32;
    const int k0 = blockIdx.y * Ks;
    const int k1 = min(K, k0 + Ks);
    f32x4 acc[4];
    #pragma unroll
    for (int i = 0; i < 4; ++i) acc[i] = (f32x4){0.f, 0.f, 0.f, 0.f};
    for (int k = k0; k < k1; k += 32) {
        FragU bf;
        bf.q = *(const uint4*)&Bm[(size_t)n * ldb + k + q * 8];
        #pragma unroll
        for (int i = 0; i < 4; ++i) {
            FragU af;
            af.q = *(const uint4*)&A[(size_t)(i * 16 + c) * lda + k + q * 8];
            acc[i] = __builtin_amdgcn_mfma_f32_16x16x32_bf16(af.s, bf.s, acc[i], 0, 0, 0);
        }
    }
    if (n >= Nw) return;
    #pragma unroll
    for (int i = 0; i < 4; ++i)
        #pragma unroll
        for (int r = 0; r < 4; ++r) {
            int m = i * 16 + q * 4 + r;
            atomicAdd(&out[(size_t)m * rs + coloff + n], scale * acc[i][r]);
        }
}

// ---------------------------------------------------------------------------
// conv1d as implicit-GEMM bf16 MFMA. kk = ci*KP + k. Wt pre-transformed
// [Co_pad][Ci*KP] bf16 zero-padded. Block: 64 co x 256 t.
template <int KP>
__global__ __launch_bounds__(256) void conv_mfma(const unsigned short* __restrict__ xin,
                                                 int Ci, int Lp,
                                                 const unsigned short* __restrict__ Wt, int KK,
                                                 int nchunk,
                                                 const float* __restrict__ bias, int Co,
                                                 unsigned short* __restrict__ yout,
                                                 int Lout, int LoutPad,
                                                 float* __restrict__ pool, int pool_coloff) {
    constexpr int CIPC = 64 / KP;
    constexpr int LG = (KP == 8) ? 3 : 4;
    const int tid = threadIdx.x;
    const int b = blockIdx.z, co0 = blockIdx.y * 64, t0 = blockIdx.x * 256;
    const int lane = tid & 63, w = tid >> 6, c = lane & 15, q = lane >> 4;
    __shared__ __align__(16) unsigned short As[64 * 72];
    __shared__ __align__(16) unsigned short xraw[CIPC * 272];
    f32x4 acc[4][4];
    #pragma unroll
    for (int i = 0; i < 4; ++i)
        #pragma unroll
        for (int j = 0; j < 4; ++j) acc[i][j] = (f32x4){0.f, 0.f, 0.f, 0.f};

    const int row8 = tid >> 3, col8 = (tid & 7) * 8;
    for (int ch = 0; ch < nchunk; ++ch) {
        const int kkbase = ch * 64, ci0 = ch * CIPC;
        #pragma unroll
        for (int p = 0; p < 2; ++p) {
            int row = row8 + p * 32;
            *(uint4*)&As[row * 72 + col8] =
                *(const uint4*)&Wt[(size_t)(co0 + row) * KK + kkbase + col8];
        }
        for (int gi = tid; gi < CIPC * 34; gi += 256) {
            int ci = gi / 34, g8 = (gi % 34) * 8, gt = t0 + g8;
            const unsigned short* src = xin + ((size_t)b * Ci + ci0 + ci) * Lp + gt;
            if (gt + 8 <= Lp) {
                *(uint4*)&xraw[ci * 272 + g8] = *(const uint4*)src;
            } else {
                #pragma unroll
                for (int jj = 0; jj < 8; ++jj)
                    xraw[ci * 272 + g8 + jj] = (gt + jj < Lp) ? src[jj] : (unsigned short)0;
            }
        }
        __syncthreads();
        #pragma unroll
        for (int ks = 0; ks < 2; ++ks) {
            const int kc = ks * 32;
            FragU af[4];
            #pragma unroll
            for (int i = 0; i < 4; ++i)
                af[i].q = *(const uint4*)&As[(i * 16 + c) * 72 + kc + q * 8];
            const int koff = kc + q * 8;
            const int cioff = koff >> LG;
            const int k0 = koff & (KP - 1);
            const uint32_t* xr = (const uint32_t*)xraw + cioff * 136;
            #pragma unroll
            for (int j = 0; j < 4; ++j) {
                int tt = w * 64 + j * 16 + c;
                int eoff = tt + k0;
                int d0 = eoff >> 1;
                unsigned sh = (unsigned)(eoff & 1) * 16u;
                uint32_t u0 = xr[d0], u1 = xr[d0 + 1], u2 = xr[d0 + 2],
                         u3 = xr[d0 + 3], u4 = xr[d0 + 4];
                FragU bf;
                bf.u[0] = __builtin_amdgcn_alignbit(u1, u0, sh);
                bf.u[1] = __builtin_amdgcn_alignbit(u2, u1, sh);
                bf.u[2] = __builtin_amdgcn_alignbit(u3, u2, sh);
                bf.u[3] = __builtin_amdgcn_alignbit(u4, u3, sh);
                #pragma unroll
                for (int i = 0; i < 4; ++i)
                    acc[i][j] = __builtin_amdgcn_mfma_f32_16x16x32_bf16(af[i].s, bf.s,
                                                                        acc[i][j], 0, 0, 0);
            }
        }
        __syncthreads();
    }
    if (pool) {
        #pragma unroll
        for (int i = 0; i < 4; ++i) {
            #pragma unroll
            for (int r = 0; r < 4; ++r) {
                int co = co0 + i * 16 + q * 4 + r;
                float bv = (co < Co) ? bias[co] : 0.f;
                float v = 0.f;
                #pragma unroll
                for (int j = 0; j < 4; ++j) {
                    int t = t0 + w * 64 + j * 16 + c;
                    if (t < Lout) v = fmaxf(v, fmaxf(acc[i][j][r] + bv, 0.f));
                }
                v = fmaxf(v, __shfl_xor(v, 1));
                v = fmaxf(v, __shfl_xor(v, 2));
                v = fmaxf(v, __shfl_xor(v, 4));
                v = fmaxf(v, __shfl_xor(v, 8));
                if (c == 0 && co < Co)
                    atomicMax((int*)&pool[(size_t)b * 1420 + pool_coloff + co],
                              __float_as_int(v));
            }
        }
    } else {
        #pragma unroll
        for (int i = 0; i < 4; ++i) {
            #pragma unroll
            for (int r = 0; r < 4; ++r) {
                int co = co0 + i * 16 + q * 4 + r;
                if (co >= Co) continue;
                float bv = bias[co];
                #pragma unroll
                for (int j = 0; j < 4; ++j) {
                    int t = t0 + w * 64 + j * 16 + c;
                    if (t < Lout) {
                        __hip_bfloat16 h = __float2bfloat16(fmaxf(acc[i][j][r] + bv, 0.f));
                        yout[((size_t)b * Co + co) * LoutPad + t] = *(unsigned short*)&h;
                    } else if (t < LoutPad) {
                        yout[((size_t)b * Co + co) * LoutPad + t] = 0;
                    }
                }
            }
        }
    }
}

// ---------------------------------------------------------------------------
// fp32 NT-SGEMM (FC head), split-K atomic into C[m*N+n]
__global__ __launch_bounds__(256) void gemm_nt(const float* __restrict__ A, int lda,
                                               const float* __restrict__ Bm,
                                               float* __restrict__ Cout,
                                               int M, int N, int K, int KC) {
    const int m0 = blockIdx.x * 64, n0 = blockIdx.y * 64, s = blockIdx.z;
    const int tid = threadIdx.x, ty = tid >> 4, tx = tid & 15;
    __shared__ __align__(16) float As[16][68];
    __shared__ __align__(16) float Bs[16][68];
    float acc[4][4] = {};
    const int kbeg = s * KC, kend = min(K, kbeg + KC);
    for (int k0 = kbeg; k0 < kend; k0 += 16) {
        int colk = k0 + tx;
        bool kok = colk < kend;
        #pragma unroll
        for (int qq = 0; qq < 4; ++qq) {
            int mi = ty + qq * 16;
            As[tx][mi] = (kok && (m0 + mi) < M) ? A[(size_t)(m0 + mi) * lda + colk] : 0.f;
            Bs[tx][mi] = (kok && (n0 + mi) < N) ? Bm[(size_t)(n0 + mi) * K + colk] : 0.f;
        }
        __syncthreads();
        #pragma unroll
        for (int kk = 0; kk < 16; ++kk) {
            float4 a4 = *(const float4*)&As[kk][ty * 4];
            float4 b4 = *(const float4*)&Bs[kk][tx * 4];
            float av[4] = {a4.x, a4.y, a4.z, a4.w};
            float bv[4] = {b4.x, b4.y, b4.z, b4.w};
            #pragma unroll
            for (int i = 0; i < 4; ++i)
                #pragma unroll
                for (int j = 0; j < 4; ++j)
                    acc[i][j] = fmaf(av[i], bv[j], acc[i][j]);
        }
        __syncthreads();
    }
    #pragma unroll
    for (int i = 0; i < 4; ++i) {
        int m = m0 + ty * 4 + i;
        if (m >= M) continue;
        #pragma unroll
        for (int j = 0; j < 4; ++j) {
            int n = n0 + tx * 4 + j;
            if (n >= N) continue;
            atomicAdd(&Cout[(size_t)m * N + n], acc[i][j]);
        }
    }
}

__global__ void epilogue_k(const float* __restrict__ C, const float* __restrict__ bias,
                           float* __restrict__ out, int M, int N, int act) {
    int idx = blockIdx.x * 256 + threadIdx.x;
    if (idx >= M * N) return;
    int m = idx / N, n = idx % N;
    float v = C[idx] + bias[n];
    if (act == 2) v = v >= 0.f ? v : 0.01f * v;
    out[(size_t)m * N + n] = v;
}

__global__ void out_k(const float* __restrict__ h3, const float* __restrict__ W,
                      const float* __restrict__ bias, float* __restrict__ out) {
    int tid = threadIdx.x;
    if (tid >= 128) return;
    int b = tid >> 1, n = tid & 1;
    const float* hr = h3 + (size_t)b * 512;
    const float* wr = W + (size_t)n * 512;
    float a = 0.f;
    for (int k = 0; k < 512; ++k) a = fmaf(hr[k], wr[k], a);
    out[b * 2 + n] = a + bias[n];
}

// ---------------------------------------------------------------------------
static inline int kc_of(int K, int S) { return ((K + S * 16 - 1) / (S * 16)) * 16; }
static inline dim3 g1d(int n) { return dim3((n + 255) / 256); }

extern "C" void kernel_launch(void* const* d_in, const int* in_sizes, int n_in,
                              void* d_out, int out_size, void* d_ws, size_t ws_size,
                              hipStream_t stream) {
    const int* drug_tokens       = (const int*)d_in[0];
    const int* protein_tokens    = (const int*)d_in[1];
    const int* drug_node_tokens  = (const int*)d_in[2];
    const int* protein_node_toks = (const int*)d_in[3];
    const int* ddi_edges         = (const int*)d_in[4];
    const int* ppi_edges         = (const int*)d_in[5];
    const int* dpi_edges         = (const int*)d_in[6];
    const float* drug_embed      = (const float*)d_in[7];
    const float* protein_embed   = (const float*)d_in[8];
    const float* dW1 = (const float*)d_in[9];  const float* db1 = (const float*)d_in[10];
    const float* dW2 = (const float*)d_in[11]; const float* db2 = (const float*)d_in[12];
    const float* dW3 = (const float*)d_in[13]; const float* db3 = (const float*)d_in[14];
    const float* pW1 = (const float*)d_in[15]; const float* pb1 = (const float*)d_in[16];
    const float* pW2 = (const float*)d_in[17]; const float* pb2 = (const float*)d_in[18];
    const float* pW3 = (const float*)d_in[19]; const float* pb3 = (const float*)d_in[20];
    const float* drug_node_table = (const float*)d_in[21];
    const float* prot_node_table = (const float*)d_in[22];
    const float* ddi_Wl = (const float*)d_in[23]; const float* ddi_bl = (const float*)d_in[24];
    const float* ddi_Wr = (const float*)d_in[25];
    const float* ppi_Wl = (const float*)d_in[26]; const float* ppi_bl = (const float*)d_in[27];
    const float* ppi_Wr = (const float*)d_in[28];
    const float* dpi_Wl = (const float*)d_in[29]; const float* dpi_bl = (const float*)d_in[30];
    const float* dpi_Wr = (const float*)d_in[31];
    const float* pdi_Wl = (const float*)d_in[32]; const float* pdi_bl = (const float*)d_in[33];
    const float* pdi_Wr = (const float*)d_in[34];
    const float* fc1_W = (const float*)d_in[35]; const float* fc1_b = (const float*)d_in[36];
    const float* fc2_W = (const float*)d_in[37]; const float* fc2_b = (const float*)d_in[38];
    const float* fc3_W = (const float*)d_in[39]; const float* fc3_b = (const float*)d_in[40];
    const float* out_W = (const float*)d_in[41]; const float* out_b = (const float*)d_in[42];

    float* outp = (float*)d_out;
    if (ws_size < NEED_BYTES) {  // clean failure instead of corruption
        zero32_k<<<g1d(out_size), 256, 0, stream>>>((uint32_t*)outp, out_size);
        return;
    }
    char* wsb = (char*)d_ws;
    float* pair = (float*)(wsb + O_PAIR);
    float* cf1 = (float*)(wsb + O_CF1); float* cf2 = (float*)(wsb + O_CF2);
    float* cf3 = (float*)(wsb + O_CF3);
    float* h1 = (float*)(wsb + O_H1); float* h2 = (float*)(wsb + O_H2);
    float* h3 = (float*)(wsb + O_H3);
    float* bd = (float*)(wsb + O_BD); float* bp = (float*)(wsb + O_BP);
    float* T  = (float*)(wsb + O_T);
    unsigned short* Wd   = (unsigned short*)(wsb + O_WD);
    unsigned short* Wp   = (unsigned short*)(wsb + O_WP);
    unsigned short* pdiB = (unsigned short*)(wsb + O_PDIB);
    unsigned short* WtP1 = (unsigned short*)(wsb + O_WTP1);
    unsigned short* WtP2 = (unsigned short*)(wsb + O_WTP2);
    unsigned short* WtP3 = (unsigned short*)(wsb + O_WTP3);
    unsigned short* WtD1 = (unsigned short*)(wsb + O_WTD1);
    unsigned short* WtD2 = (unsigned short*)(wsb + O_WTD2);
    unsigned short* WtD3 = (unsigned short*)(wsb + O_WTD3);
    unsigned short* Xp  = (unsigned short*)(wsb + O_XP);
    unsigned short* Xd  = (unsigned short*)(wsb + O_XD);
    unsigned short* zpd = (unsigned short*)(wsb + O_ZPD);
    unsigned short* px1 = (unsigned short*)(wsb + O_PX1);
    unsigned short* dx1 = (unsigned short*)(wsb + O_DX1);
    unsigned short* Xp2 = (unsigned short*)(wsb + O_XP2);
    unsigned short* Xd2 = (unsigned short*)(wsb + O_XD2);
    unsigned short* a2pd = (unsigned short*)(wsb + O_A2PD);
    unsigned short* x0p = (unsigned short*)(wsb + O_X0P);
    unsigned short* y1p = (unsigned short*)(wsb + O_Y1P);
    unsigned short* y2p = (unsigned short*)(wsb + O_Y2P);
    unsigned short* x0d = (unsigned short*)(wsb + O_X0D);
    unsigned short* y1d = (unsigned short*)(wsb + O_Y1D);
    unsigned short* y2d = (unsigned short*)(wsb + O_Y2D);

    // 0) zero: fp32 accum region (pair..T); Xp+Xd; Xp2+Xd2
    zero32_k<<<g1d(Z1_END / 4), 256, 0, stream>>>((uint32_t*)wsb, Z1_END / 4);
    zero32_k<<<g1d(10485760 / 4), 256, 0, stream>>>((uint32_t*)(wsb + O_XP), 10485760 / 4);
    zero32_k<<<g1d(327680 / 4), 256, 0, stream>>>((uint32_t*)(wsb + O_XP2), 327680 / 4);

    // 1) fused weight prep (bd, bp, Wd, Wp, pdiB, conv weights) + layer-2 bias fill
    prep_k<<<g1d((int)PC14), 256, 0, stream>>>(bd, bp, Wd, Wp, pdiB,
                                               WtP1, WtP2, WtP3, WtD1, WtD2, WtD3,
                                               ddi_Wl, ddi_bl, ddi_Wr,
                                               ppi_Wl, ppi_bl, ppi_Wr,
                                               dpi_Wl, dpi_bl, dpi_Wr,
                                               pdi_Wl, pdi_bl, pdi_Wr,
                                               dW1, dW2, dW3, pW1, pW2, pW3);
    biasfill_k<<<g1d(64 * 1100), 256, 0, stream>>>(pair, bd, bp);

    // 2) node features into concat blocks: Xd[:,128:]=dx0, Xp[:,1024:]=px0
    node_feat_k<<<dim3(32, 64), 256, 0, stream>>>(drug_node_tokens, drug_node_table, 71, 100, Xd, 384, 128);
    node_feat_k<<<dim3(32, 64), 256, 0, stream>>>(protein_node_toks, prot_node_table, 26, 1000, Xp, 2176, 1024);

    // 3) layer-1 aggregations
    segmean_k<<<dim3(32, 64), 256, 0, stream>>>(Xd + 128, 384, ddi_edges, 256, 0, 128, 128, 128, 32, Xd, 384, 0);
    segmean_k<<<dim3(32, 64), 256, 0, stream>>>(Xp + 1024, 2176, ppi_edges, 256, 0, 128, 128, 1024, 32, Xp, 2176, 0);
    segmean_k<<<dim3(32, 64), 256, 0, stream>>>(Xd + 128, 384, dpi_edges, 128, 0, 64, 64, 128, 32, Xp, 2176, 2048);
    // pdi: transform px0 then aggregate
    gemm_bf<<<dim3(32, 1), 256, 0, stream>>>(Xp + 1024, 2176, pdiB, 1024, 128, 1024,
                                             nullptr, 0, 1.f, nullptr, zpd, 128, 0, 128);
    segmean_k<<<dim3(32, 64), 256, 0, stream>>>(zpd, 128, dpi_edges, 128, 64, 0, 64, 128, 32, Xd, 384, 256);

    // 4) layer-1 updates (single concat GEMM per side)
    gemm_bf<<<dim3(32, 1), 256, 0, stream>>>(Xd, 384, Wd, 384, 128, 384,
                                             bd, 100, 0.5f, nullptr, dx1, 128, 0, 128);
    gemm_bf<<<dim3(32, 4), 256, 0, stream>>>(Xp, 2176, Wp, 2176, 1024, 2176,
                                             bp, 1000, 0.5f, nullptr, px1, 1024, 0, 1024);

    // 5) layer-2 (node 0 only) — skinny split-K GEMMs, atomicAdd into pre-biased pair
    segmean_k<<<dim3(1, 64), 256, 0, stream>>>(dx1, 128, ddi_edges, 256, 0, 128, 128, 128, 1, Xd2, 384, 0);
    segmean_k<<<dim3(1, 64), 256, 0, stream>>>(px1, 1024, ppi_edges, 256, 0, 128, 128, 1024, 1, Xp2, 2176, 0);
    segmean_k<<<dim3(1, 64), 256, 0, stream>>>(dx1, 128, dpi_edges, 128, 0, 64, 64, 128, 1, Xp2, 2176, 2048);
    segmean_k<<<dim3(1, 64), 256, 0, stream>>>(px1, 1024, dpi_edges, 128, 64, 0, 64, 1024, 1, a2pd, 1024, 0);
    copy_rows_k<<<dim3(64), 256, 0, stream>>>(dx1, 128, Xd2, 384, 128, 128);
    copy_rows_k<<<dim3(64), 256, 0, stream>>>(px1, 1024, Xp2, 2176, 1024, 1024);
    gemm_skinny<<<dim3(2, 4), 256, 0, stream>>>(a2pd, 1024, pdiB, 1024, 1024, 4, 1.f,
                                                T, 128, 0, 128);
    cvtT_k<<<g1d(64 * 128), 256, 0, stream>>>(T, Xd2);
    gemm_skinny<<<dim3(2, 2), 256, 0, stream>>>(Xd2, 384, Wd, 384, 384, 2, 0.5f,
                                                pair, 1420, 320, 100);
    gemm_skinny<<<dim3(16, 8), 256, 0, stream>>>(Xp2, 2176, Wp, 2176, 2176, 8, 0.5f,
                                                 pair, 1420, 420, 1000);

    // 6) conv towers (aliased region; GNN results already in pair)
    embed_k<<<dim3(64, 8), 256, 0, stream>>>(protein_tokens, protein_embed, x0p, 1000, 1000);
    conv_mfma<8><<<dim3(4, 1, 64), 256, 0, stream>>>(x0p, 64, 1000, WtP1, 512, 8,
                                                     pb1, 40, y1p, 997, 1000, nullptr, 0);
    conv_mfma<8><<<dim3(4, 2, 64), 256, 0, stream>>>(y1p, 40, 1000, WtP2, 320, 5,
                                                     pb2, 80, y2p, 990, 992, nullptr, 0);
    conv_mfma<16><<<dim3(4, 3, 64), 256, 0, stream>>>(y2p, 80, 992, WtP3, 1280, 20,
                                                      pb3, 160, nullptr, 979, 0, pair, 160);
    embed_k<<<dim3(64, 8), 256, 0, stream>>>(drug_tokens, drug_embed, x0d, 100, 104);
    conv_mfma<8><<<dim3(1, 1, 64), 256, 0, stream>>>(x0d, 64, 104, WtD1, 512, 8,
                                                     db1, 40, y1d, 97, 104, nullptr, 0);
    conv_mfma<8><<<dim3(1, 2, 64), 256, 0, stream>>>(y1d, 40, 104, WtD2, 320, 5,
                                                     db2, 80, y2d, 92, 96, nullptr, 0);
    conv_mfma<8><<<dim3(1, 3, 64), 256, 0, stream>>>(y2d, 80, 96, WtD3, 640, 10,
                                                     db3, 160, nullptr, 85, 0, pair, 0);

    // 7) FC head (fp32)
    gemm_nt<<<dim3(1, 16, 4), 256, 0, stream>>>(pair, 1420, fc1_W, cf1, 64, 1024, 1420, kc_of(1420, 4));
    epilogue_k<<<g1d(64 * 1024), 256, 0, stream>>>(cf1, fc1_b, h1, 64, 1024, 2);
    gemm_nt<<<dim3(1, 16, 4), 256, 0, stream>>>(h1, 1024, fc2_W, cf2, 64, 1024, 1024, kc_of(1024, 4));
    epilogue_k<<<g1d(64 * 1024), 256, 0, stream>>>(cf2, fc2_b, h2, 64, 1024, 2);
    gemm_nt<<<dim3(1, 8, 4), 256, 0, stream>>>(h2, 1024, fc3_W, cf3, 64, 512, 1024, kc_of(1024, 4));
    epilogue_k<<<g1d(64 * 512), 256, 0, stream>>>(cf3, fc3_b, h3, 64, 512, 2);
    out_k<<<dim3(1), 128, 0, stream>>>(h3, out_W, out_b, outp);
}

// Round 5
// 572.383 us; speedup vs baseline: 5.8087x; 1.5558x over previous
//
#include <hip/hip_runtime.h>
#include <hip/hip_bf16.h>

// ---------------------------------------------------------------------------
// SSGraphDTI forward. bf16 MFMA for convs + GNN, fp32 FC head.
// R5: GNN is affine -> collapse 2 layers into 2-hop aggregation weight vectors
// (exact linear algebra) + skinny split-K MFMA GEMMs. Fix y2p/y1p overlap race.
// Fuse protein embed into conv1. FC split-K 8.
// ---------------------------------------------------------------------------

typedef __attribute__((ext_vector_type(8))) short short8;
typedef __attribute__((ext_vector_type(4))) float f32x4;
union FragU { uint32_t u[4]; uint4 q; short8 s; };

static __device__ inline unsigned short f2bf(float v) {
    __hip_bfloat16 h = __float2bfloat16(v);
    return *(unsigned short*)&h;
}
static __device__ inline float bf2f(unsigned short u) {
    return __bfloat162float(*(const __hip_bfloat16*)&u);
}

// ---------------- workspace layout (byte offsets) ----------------
static constexpr size_t O_PAIR = 0;          // 64*1420 f32
static constexpr size_t O_CF1  = 363520;     // 64*1024 f32
static constexpr size_t O_CF2  = 625664;
static constexpr size_t O_CF3  = 887808;     // 64*512 f32
static constexpr size_t Z1_END = 1018880;    // zero span 1 [0, Z1_END)
static constexpr size_t O_H1   = 1018880;
static constexpr size_t O_H2   = 1281024;
static constexpr size_t O_H3   = 1543168;
static constexpr size_t O_BD   = 1674240;    // 128 f32
static constexpr size_t O_BP   = 1674752;    // 1024 f32
static constexpr size_t O_WDS  = 1678848;    // 128x1248 bf16
static constexpr size_t O_WPS  = 1998336;    // 1024x2208 bf16
static constexpr size_t O_WTP1 = 6520320;    // 64x512 bf16
static constexpr size_t O_WTP2 = 6585856;    // 128x320 bf16
static constexpr size_t O_WTP3 = 6667776;    // 192x1280 bf16
static constexpr size_t O_WTD1 = 7159296;    // 64x512 bf16
static constexpr size_t O_WTD2 = 7224832;    // 128x320 bf16
static constexpr size_t O_WTD3 = 7306752;    // 192x640 bf16
static constexpr size_t AR     = 7552512;    // aliased region base
// GNN phase:
static constexpr size_t A_DX0 = AR + 0;        // 64*32*104 bf16 = 425,984
static constexpr size_t A_PX0 = AR + 425984;   // 64*32*1000 bf16 = 4,096,000
static constexpr size_t A_AD  = AR + 4521984;  // 192x1248 bf16 = 479,232
static constexpr size_t A_AP  = AR + 5001216;  // 192x2208 bf16 = 847,872
static constexpr size_t A_A2D = AR + 5849088;  // 64x1248 bf16 = 159,744
static constexpr size_t A_A2P = AR + 6008832;  // 64x2208 bf16 = 282,624
static constexpr size_t A_UD  = AR + 6291456;  // 192x112 f32 = 86,016
static constexpr size_t A_UP  = AR + 6377472;  // 192x1024 f32 = 786,432
static constexpr size_t A_RS  = AR + 7163904;  // 64x512 f32 = 131,072 -> 7,294,976
static constexpr size_t Z2_BEG = A_AD;         // zero span 2: Ad..Up
static constexpr size_t Z2_CNT = (A_RS - A_AD) / 4;   // words
// conv phase aliases (GNN dead):
static constexpr size_t A_Y2P = AR + 0;          // 64x80x992 bf16 = 10,158,080
static constexpr size_t A_Y1P = AR + 10158080;   // 64x40x1000 bf16 = 5,120,000 -> 15,278,080
static constexpr size_t A_X0D = AR + 0;          // 64x64x104 bf16 (after prot conv3)
static constexpr size_t A_Y1D = AR + 851968;     // 64x40x104 bf16
static constexpr size_t A_Y2D = AR + 1384448;    // 64x80x96 bf16 -> 2,367,488
static constexpr size_t NEED_BYTES = AR + 15278080;  // 22,830,592

// ---------------------------------------------------------------------------
__global__ void zero32_k(uint32_t* __restrict__ p, int n) {
    int i = blockIdx.x * 256 + threadIdx.x;
    if (i < n) p[i] = 0u;
}

// ---------------- fused weight prep ----------------
static constexpr long P0 = 100;                // bd
static constexpr long P1 = P0 + 1000;          // bp
static constexpr long P2 = P1 + 14336;         // WdS cols[0:112) = ddi_Wl
static constexpr long P3 = P2 + 14336;         // WdS cols[112:224) = ddi_Wr+pdi_Wr
static constexpr long P4 = P3 + 131072;        // WdS cols[224:1248) = pdi_Wl
static constexpr long P5 = P4 + 1048576;       // WpS cols[0:1024) = ppi_Wl
static constexpr long P6 = P5 + 1048576;       // WpS cols[1024:2048) = ppi_Wr+dpi_Wr
static constexpr long P7 = P6 + 163840;        // WpS cols[2048:2208) = dpi_Wl
static constexpr long P8 = P7 + 32768;         // WtP1
static constexpr long P9 = P8 + 40960;         // WtP2
static constexpr long P10 = P9 + 245760;       // WtP3
static constexpr long P11 = P10 + 32768;       // WtD1
static constexpr long P12 = P11 + 40960;       // WtD2
static constexpr long P13 = P12 + 122880;      // WtD3

__device__ inline void wt_block(unsigned short* dst, int ld_dst, int coloff,
                                const float* s1, const float* s2, int ld_src,
                                int N, int Kreal, int Kblk, long local) {
    int n = (int)(local / Kblk), k = (int)(local % Kblk);
    float v = 0.f;
    if (n < N && k < Kreal) {
        v = s1[(size_t)n * ld_src + k];
        if (s2) v += s2[(size_t)n * ld_src + k];
    }
    dst[(size_t)n * ld_dst + coloff + k] = f2bf(v);
}

__device__ inline void wtconv_block(unsigned short* dst, const float* W,
                                    int Co, int Ci, int K, int KP, long local) {
    int co = (int)(local / (Ci * KP));
    int rem = (int)(local % (Ci * KP));
    int ci = rem / KP, k = rem % KP;
    float v = (co < Co && k < K) ? W[((size_t)co * Ci + ci) * K + k] : 0.f;
    dst[local] = f2bf(v);
}

__global__ __launch_bounds__(256) void prep_k(
    float* bd, float* bp, unsigned short* WdS, unsigned short* WpS,
    unsigned short* WtP1, unsigned short* WtP2, unsigned short* WtP3,
    unsigned short* WtD1, unsigned short* WtD2, unsigned short* WtD3,
    const float* ddi_Wl, const float* ddi_bl, const float* ddi_Wr,
    const float* ppi_Wl, const float* ppi_bl, const float* ppi_Wr,
    const float* dpi_Wl, const float* dpi_bl, const float* dpi_Wr,
    const float* pdi_Wl, const float* pdi_bl, const float* pdi_Wr,
    const float* dW1, const float* dW2, const float* dW3,
    const float* pW1, const float* pW2, const float* pW3) {
    long idx = (long)blockIdx.x * 256 + threadIdx.x;
    if (idx < P0) { bd[idx] = 0.5f * (ddi_bl[idx] + pdi_bl[idx]); return; }
    if (idx < P1) { long j = idx - P0; bp[j] = 0.5f * (ppi_bl[j] + dpi_bl[j]); return; }
    if (idx < P2) { wt_block(WdS, 1248, 0, ddi_Wl, nullptr, 100, 100, 100, 112, idx - P1); return; }
    if (idx < P3) { wt_block(WdS, 1248, 112, ddi_Wr, pdi_Wr, 100, 100, 100, 112, idx - P2); return; }
    if (idx < P4) { wt_block(WdS, 1248, 224, pdi_Wl, nullptr, 1000, 100, 1000, 1024, idx - P3); return; }
    if (idx < P5) { wt_block(WpS, 2208, 0, ppi_Wl, nullptr, 1000, 1000, 1000, 1024, idx - P4); return; }
    if (idx < P6) { wt_block(WpS, 2208, 1024, ppi_Wr, dpi_Wr, 1000, 1000, 1000, 1024, idx - P5); return; }
    if (idx < P7) { wt_block(WpS, 2208, 2048, dpi_Wl, nullptr, 100, 1000, 100, 160, idx - P6); return; }
    if (idx < P8)  { wtconv_block(WtP1, pW1, 40, 64, 4, 8, idx - P7); return; }
    if (idx < P9)  { wtconv_block(WtP2, pW2, 80, 40, 8, 8, idx - P8); return; }
    if (idx < P10) { wtconv_block(WtP3, pW3, 160, 80, 12, 16, idx - P9); return; }
    if (idx < P11) { wtconv_block(WtD1, dW1, 40, 64, 4, 8, idx - P10); return; }
    if (idx < P12) { wtconv_block(WtD2, dW2, 80, 40, 6, 8, idx - P11); return; }
    if (idx < P13) { wtconv_block(WtD3, dW3, 160, 80, 8, 8, idx - P12); return; }
}

// pre-fill layer-2 bias into pair cols [320:1420) (stage-2 atomicAdds on top)
__global__ void biasfill_k(float* __restrict__ pair, const float* __restrict__ bd,
                           const float* __restrict__ bp) {
    int idx = blockIdx.x * 256 + threadIdx.x;
    if (idx >= 64 * 1100) return;
    int b = idx / 1100, j = idx % 1100;
    if (j < 100) pair[(size_t)b * 1420 + 320 + j] = bd[j];
    else pair[(size_t)b * 1420 + 420 + (j - 100)] = bp[j - 100];
}

// embedding lookup -> bf16 (B, 64, Lpad), zero pads (drug tower)
__global__ __launch_bounds__(256) void embed_k(const int* __restrict__ toks,
                                               const float* __restrict__ table,
                                               unsigned short* __restrict__ out,
                                               int L, int Lpad) {
    int b = blockIdx.x, c0 = blockIdx.y * 8;
    for (int t = threadIdx.x; t < Lpad; t += 256) {
        if (t < L) {
            int tk = toks[(size_t)b * L + t];
            #pragma unroll
            for (int c = 0; c < 8; ++c)
                out[((size_t)b * 64 + c0 + c) * Lpad + t] = f2bf(table[(size_t)tk * 64 + c0 + c]);
        } else {
            #pragma unroll
            for (int c = 0; c < 8; ++c)
                out[((size_t)b * 64 + c0 + c) * Lpad + t] = 0;
        }
    }
}

// bag-of-tokens node features via LDS histogram -> bf16
__global__ __launch_bounds__(256) void node_feat_k(const int* __restrict__ toks,
                                                   const float* __restrict__ table,
                                                   int V, int Lw,
                                                   unsigned short* __restrict__ out, int ldo) {
    const int b = blockIdx.y, n = blockIdx.x, tid = threadIdx.x;
    __shared__ int cnt[71];
    for (int v = tid; v < V; v += 256) cnt[v] = 0;
    __syncthreads();
    const int* t = toks + ((size_t)b * 32 + n) * Lw;
    for (int i = tid; i < Lw; i += 256) atomicAdd(&cnt[t[i]], 1);
    __syncthreads();
    float inv = 1.f / (float)Lw;
    unsigned short* o = out + ((size_t)b * 32 + n) * ldo;
    for (int d = tid; d < Lw; d += 256) {
        float a = 0.f;
        for (int v = 0; v < V; ++v) {
            int c = cnt[v];
            if (c) a += (float)c * table[(size_t)v * Lw + d];
        }
        o[d] = f2bf(a * inv);
    }
}

// ---------------------------------------------------------------------------
// per-batch 2-hop aggregation weights. M[0]=SD(ddi), M[1]=SP(ppi),
// M[2]=Tpd(prot->drug), M[3]=Tdp(drug->prot). RS per batch (512 f32):
// r1..r7 @ 0..192, s1..s7 @ 224..416, rho @ 448..451.
__global__ __launch_bounds__(256) void rs_k(const int* __restrict__ ddi,
                                            const int* __restrict__ ppi,
                                            const int* __restrict__ dpi,
                                            float* __restrict__ RS) {
    const int b = blockIdx.x, tid = threadIdx.x;
    __shared__ float M[4][32][32];
    __shared__ int cnt[4][32];
    __shared__ float inv[4][32];
    for (int i = tid; i < 4 * 32 * 32; i += 256) ((float*)M)[i] = 0.f;
    if (tid < 128) ((int*)cnt)[tid] = 0;
    __syncthreads();
    const int* ed = ddi + (size_t)b * 256;
    const int* ep = ppi + (size_t)b * 256;
    const int* ex = dpi + (size_t)b * 128;
    if (tid < 128) {
        atomicAdd(&cnt[0][ed[128 + tid]], 1);
        atomicAdd(&cnt[1][ep[128 + tid]], 1);
    } else if (tid < 192) {
        int e = tid - 128;
        atomicAdd(&cnt[2][ex[e]], 1);        // Tpd: drug dst = dpi[0]
        atomicAdd(&cnt[3][ex[64 + e]], 1);   // Tdp: prot dst = dpi[1]
    }
    __syncthreads();
    if (tid < 128) {
        int which = tid >> 5, j = tid & 31;
        inv[which][j] = 1.f / (float)max(cnt[which][j], 1);
    }
    __syncthreads();
    if (tid < 128) {
        int s = ed[tid], d = ed[128 + tid];
        atomicAdd(&M[0][d][s], inv[0][d]);
        int s2 = ep[tid], d2 = ep[128 + tid];
        atomicAdd(&M[1][d2][s2], inv[1][d2]);
    } else if (tid < 192) {
        int e = tid - 128;
        int dr = ex[e], pr = ex[64 + e];
        atomicAdd(&M[2][dr][pr], inv[2][dr]);  // Tpd[drug][prot]
        atomicAdd(&M[3][pr][dr], inv[3][pr]);  // Tdp[prot][drug]
    }
    __syncthreads();
    float* R = RS + (size_t)b * 512;
    if (tid < 32) {
        int j = tid;
        float r2 = M[0][0][j], s2v = M[2][0][j], s5 = M[1][0][j], r6 = M[3][0][j];
        float r1 = 0.f, s1 = 0.f, s3 = 0.f, r4 = 0.f, s4 = 0.f, r5 = 0.f, r7 = 0.f, s7 = 0.f;
        for (int k = 0; k < 32; ++k) {
            float a = M[0][0][k], bq = M[2][0][k], cq = M[1][0][k], dq = M[3][0][k];
            r1 += a * M[0][k][j];
            s1 += a * M[2][k][j];
            s3 += bq * M[1][k][j];
            r4 += bq * M[3][k][j];
            s4 += cq * M[1][k][j];
            r5 += cq * M[3][k][j];
            r7 += dq * M[0][k][j];
            s7 += dq * M[2][k][j];
        }
        R[0 + j] = r1;   R[32 + j] = r2;  R[64 + j] = (j == 0) ? 1.f : 0.f;
        R[96 + j] = r4;  R[128 + j] = r5; R[160 + j] = r6;  R[192 + j] = r7;
        R[224 + j] = s1; R[256 + j] = s2v; R[288 + j] = s3; R[320 + j] = s4;
        R[352 + j] = s5; R[384 + j] = (j == 0) ? 1.f : 0.f; R[416 + j] = s7;
    }
    __syncthreads();
    if (tid == 0) {
        float a = 0.f, bq = 0.f, cq = 0.f, dq = 0.f;
        for (int k = 0; k < 32; ++k) {
            a += M[0][0][k]; bq += M[2][0][k]; cq += M[1][0][k]; dq += M[3][0][k];
        }
        R[448] = a;   // rho_u1 = sum r2
        R[449] = bq;  // rho_u3 = sum s2
        R[450] = cq;  // rho_w1 = sum s5
        R[451] = dq;  // rho_w3 = sum r6
    }
}

// feature gather: blockIdx.x = vec i (0..6 drug r1..r7, 7..13 prot s1..s7),
// blockIdx.y = batch. Writes bf16 into Ad/Ap concat slots.
__global__ __launch_bounds__(256) void fgather_k(const unsigned short* __restrict__ dx0,
                                                 const unsigned short* __restrict__ px0,
                                                 const float* __restrict__ RS,
                                                 unsigned short* __restrict__ Ad,
                                                 unsigned short* __restrict__ Ap) {
    const int i = blockIdx.x, b = blockIdx.y, tid = threadIdx.x;
    __shared__ float wsh[32];
    if (tid < 32) wsh[tid] = RS[(size_t)b * 512 + i * 32 + tid];
    __syncthreads();
    size_t g0d = ((size_t)0 * 64 + b) * 1248, g1d_ = ((size_t)1 * 64 + b) * 1248,
           g2d = ((size_t)2 * 64 + b) * 1248;
    size_t g0p = ((size_t)0 * 64 + b) * 2208, g1p = ((size_t)1 * 64 + b) * 2208,
           g2p = ((size_t)2 * 64 + b) * 2208;
    if (i < 7) {  // drug vec, D=100
        int d = tid;
        if (d >= 100) return;
        float acc = 0.f;
        const unsigned short* x = dx0 + (size_t)b * 32 * 104 + d;
        for (int k = 0; k < 32; ++k) acc += wsh[k] * bf2f(x[(size_t)k * 104]);
        unsigned short h = f2bf(acc);
        switch (i) {
            case 0: Ad[g0d + d] = h; break;                              // Fd1
            case 1: Ad[g0d + 112 + d] = h; Ad[g1d_ + d] = h; break;      // Fd2
            case 2: Ad[g1d_ + 112 + d] = h; break;                       // Fd3
            case 3: Ap[g0p + 2048 + d] = h; break;                       // Fd4
            case 4: Ap[g1p + 2048 + d] = h; break;                       // Fd5
            case 5: Ap[g2p + 2048 + d] = h; Ad[g2d + 112 + d] = h; break;// Fd6
            case 6: Ad[g2d + d] = h; break;                              // Fd7
        }
    } else {      // protein vec, D=1000
        int j = i - 7;
        for (int d = tid; d < 1000; d += 256) {
            float acc = 0.f;
            const unsigned short* x = px0 + (size_t)b * 32 * 1000 + d;
            for (int k = 0; k < 32; ++k) acc += wsh[k] * bf2f(x[(size_t)k * 1000]);
            unsigned short h = f2bf(acc);
            switch (j) {
                case 0: Ad[g0d + 224 + d] = h; break;                          // Fp1
                case 1: Ad[g1d_ + 224 + d] = h; Ap[g0p + 1024 + d] = h; break; // Fp2
                case 2: Ap[g0p + d] = h; break;                                // Fp3
                case 3: Ap[g1p + d] = h; break;                                // Fp4
                case 4: Ap[g1p + 1024 + d] = h; Ap[g2p + d] = h; break;        // Fp5
                case 5: Ap[g2p + 1024 + d] = h; break;                         // Fp6
                case 6: Ad[g2d + 224 + d] = h; break;                          // Fp7
            }
        }
    }
}

// ---------------------------------------------------------------------------
// skinny bf16 MFMA GEMM with split-K and m-groups:
// out[(gz*64+m)*rs+coloff+n] += scale * (A[gz](64,K) @ B(.,K)^T)[m,n]
// grid (Nblk, KS, G). No LDS; A/B read from global (L2-hot).
__global__ __launch_bounds__(256) void gemm_sk3(const unsigned short* __restrict__ A, int lda,
                                                const unsigned short* __restrict__ Bm, int ldb,
                                                int K, int KS, float scale,
                                                float* __restrict__ out,
                                                int rs, int coloff, int Nw) {
    const int tid = threadIdx.x;
    const int lane = tid & 63, w = tid >> 6, c = lane & 15, q = lane >> 4;
    const int n = blockIdx.x * 64 + w * 16 + c;
    const int gz = blockIdx.z;
    const unsigned short* Ab = A + (size_t)gz * 64 * lda;
    const int Ks = ((K / KS + 31) / 32) * 32;
    const int k0 = blockIdx.y * Ks;
    const int k1 = min(K, k0 + Ks);
    f32x4 acc[4];
    #pragma unroll
    for (int i = 0; i < 4; ++i) acc[i] = (f32x4){0.f, 0.f, 0.f, 0.f};
    for (int k = k0; k < k1; k += 32) {
        FragU bf;
        bf.q = *(const uint4*)&Bm[(size_t)n * ldb + k + q * 8];
        #pragma unroll
        for (int i = 0; i < 4; ++i) {
            FragU af;
            af.q = *(const uint4*)&Ab[(size_t)(i * 16 + c) * lda + k + q * 8];
            acc[i] = __builtin_amdgcn_mfma_f32_16x16x32_bf16(af.s, bf.s, acc[i], 0, 0, 0);
        }
    }
    if (n >= Nw) return;
    #pragma unroll
    for (int i = 0; i < 4; ++i)
        #pragma unroll
        for (int r = 0; r < 4; ++r) {
            int m = gz * 64 + i * 16 + q * 4 + r;
            atomicAdd(&out[(size_t)m * rs + coloff + n], scale * acc[i][r]);
        }
}

// stage-1 epilogues: U + rho*bias -> bf16 A2 slots
__global__ void ep_ud_k(const float* __restrict__ Ud, const float* __restrict__ RS,
                        const float* __restrict__ bd,
                        unsigned short* __restrict__ A2d, unsigned short* __restrict__ A2p) {
    int idx = blockIdx.x * 256 + threadIdx.x;
    if (idx >= 192 * 112) return;
    int m = idx / 112, n = idx % 112;
    if (n >= 100) return;
    int g = m >> 6, b = m & 63;
    float rho = (g == 0) ? RS[(size_t)b * 512 + 448] : (g == 1) ? 1.f : RS[(size_t)b * 512 + 451];
    unsigned short h = f2bf(Ud[idx] + rho * bd[n]);
    if (g == 0) A2d[(size_t)b * 1248 + n] = h;            // u1
    else if (g == 1) A2d[(size_t)b * 1248 + 112 + n] = h; // u2
    else A2p[(size_t)b * 2208 + 2048 + n] = h;            // w3
}

__global__ void ep_up_k(const float* __restrict__ Up, const float* __restrict__ RS,
                        const float* __restrict__ bp,
                        unsigned short* __restrict__ A2d, unsigned short* __restrict__ A2p) {
    int idx = blockIdx.x * 256 + threadIdx.x;
    if (idx >= 192 * 1024) return;
    int m = idx / 1024, n = idx % 1024;
    if (n >= 1000) return;
    int g = m >> 6, b = m & 63;
    float rho = (g == 0) ? RS[(size_t)b * 512 + 449] : (g == 1) ? RS[(size_t)b * 512 + 450] : 1.f;
    unsigned short h = f2bf(Up[idx] + rho * bp[n]);
    if (g == 0) A2d[(size_t)b * 1248 + 224 + n] = h;      // u3
    else if (g == 1) A2p[(size_t)b * 2208 + n] = h;       // w1
    else A2p[(size_t)b * 2208 + 1024 + n] = h;            // w2
}

// ---------------------------------------------------------------------------
// conv1d as implicit-GEMM bf16 MFMA (as R3/R4, verified). kk = ci*KP + k.
template <int KP>
__global__ __launch_bounds__(256) void conv_mfma(const unsigned short* __restrict__ xin,
                                                 int Ci, int Lp,
                                                 const unsigned short* __restrict__ Wt, int KK,
                                                 int nchunk,
                                                 const float* __restrict__ bias, int Co,
                                                 unsigned short* __restrict__ yout,
                                                 int Lout, int LoutPad,
                                                 float* __restrict__ pool, int pool_coloff) {
    constexpr int CIPC = 64 / KP;
    constexpr int LG = (KP == 8) ? 3 : 4;
    const int tid = threadIdx.x;
    const int b = blockIdx.z, co0 = blockIdx.y * 64, t0 = blockIdx.x * 256;
    const int lane = tid & 63, w = tid >> 6, c = lane & 15, q = lane >> 4;
    __shared__ __align__(16) unsigned short As[64 * 72];
    __shared__ __align__(16) unsigned short xraw[CIPC * 272];
    f32x4 acc[4][4];
    #pragma unroll
    for (int i = 0; i < 4; ++i)
        #pragma unroll
        for (int j = 0; j < 4; ++j) acc[i][j] = (f32x4){0.f, 0.f, 0.f, 0.f};

    const int row8 = tid >> 3, col8 = (tid & 7) * 8;
    for (int ch = 0; ch < nchunk; ++ch) {
        const int kkbase = ch * 64, ci0 = ch * CIPC;
        #pragma unroll
        for (int p = 0; p < 2; ++p) {
            int row = row8 + p * 32;
            *(uint4*)&As[row * 72 + col8] =
                *(const uint4*)&Wt[(size_t)(co0 + row) * KK + kkbase + col8];
        }
        for (int gi = tid; gi < CIPC * 34; gi += 256) {
            int ci = gi / 34, g8 = (gi % 34) * 8, gt = t0 + g8;
            const unsigned short* src = xin + ((size_t)b * Ci + ci0 + ci) * Lp + gt;
            if (gt + 8 <= Lp) {
                *(uint4*)&xraw[ci * 272 + g8] = *(const uint4*)src;
            } else {
                #pragma unroll
                for (int jj = 0; jj < 8; ++jj)
                    xraw[ci * 272 + g8 + jj] = (gt + jj < Lp) ? src[jj] : (unsigned short)0;
            }
        }
        __syncthreads();
        #pragma unroll
        for (int ks = 0; ks < 2; ++ks) {
            const int kc = ks * 32;
            FragU af[4];
            #pragma unroll
            for (int i = 0; i < 4; ++i)
                af[i].q = *(const uint4*)&As[(i * 16 + c) * 72 + kc + q * 8];
            const int koff = kc + q * 8;
            const int cioff = koff >> LG;
            const int k0 = koff & (KP - 1);
            const uint32_t* xr = (const uint32_t*)xraw + cioff * 136;
            #pragma unroll
            for (int j = 0; j < 4; ++j) {
                int tt = w * 64 + j * 16 + c;
                int eoff = tt + k0;
                int d0 = eoff >> 1;
                unsigned sh = (unsigned)(eoff & 1) * 16u;
                uint32_t u0 = xr[d0], u1 = xr[d0 + 1], u2 = xr[d0 + 2],
                         u3 = xr[d0 + 3], u4 = xr[d0 + 4];
                FragU bf;
                bf.u[0] = __builtin_amdgcn_alignbit(u1, u0, sh);
                bf.u[1] = __builtin_amdgcn_alignbit(u2, u1, sh);
                bf.u[2] = __builtin_amdgcn_alignbit(u3, u2, sh);
                bf.u[3] = __builtin_amdgcn_alignbit(u4, u3, sh);
                #pragma unroll
                for (int i = 0; i < 4; ++i)
                    acc[i][j] = __builtin_amdgcn_mfma_f32_16x16x32_bf16(af[i].s, bf.s,
                                                                        acc[i][j], 0, 0, 0);
            }
        }
        __syncthreads();
    }
    if (pool) {
        #pragma unroll
        for (int i = 0; i < 4; ++i) {
            #pragma unroll
            for (int r = 0; r < 4; ++r) {
                int co = co0 + i * 16 + q * 4 + r;
                float bv = (co < Co) ? bias[co] : 0.f;
                float v = 0.f;
                #pragma unroll
                for (int j = 0; j < 4; ++j) {
                    int t = t0 + w * 64 + j * 16 + c;
                    if (t < Lout) v = fmaxf(v, fmaxf(acc[i][j][r] + bv, 0.f));
                }
                v = fmaxf(v, __shfl_xor(v, 1));
                v = fmaxf(v, __shfl_xor(v, 2));
                v = fmaxf(v, __shfl_xor(v, 4));
                v = fmaxf(v, __shfl_xor(v, 8));
                if (c == 0 && co < Co)
                    atomicMax((int*)&pool[(size_t)b * 1420 + pool_coloff + co],
                              __float_as_int(v));
            }
        }
    } else {
        #pragma unroll
        for (int i = 0; i < 4; ++i) {
            #pragma unroll
            for (int r = 0; r < 4; ++r) {
                int co = co0 + i * 16 + q * 4 + r;
                if (co >= Co) continue;
                float bv = bias[co];
                #pragma unroll
                for (int j = 0; j < 4; ++j) {
                    int t = t0 + w * 64 + j * 16 + c;
                    if (t < Lout) {
                        yout[((size_t)b * Co + co) * LoutPad + t] =
                            f2bf(fmaxf(acc[i][j][r] + bv, 0.f));
                    } else if (t < LoutPad) {
                        yout[((size_t)b * Co + co) * LoutPad + t] = 0;
                    }
                }
            }
        }
    }
}

// protein conv1 with fused embedding lookup (V<=32). KP=8, Ci=64.
__global__ __launch_bounds__(256) void conv1e_mfma(const int* __restrict__ toks,
                                                   const float* __restrict__ table, int V, int L,
                                                   const unsigned short* __restrict__ Wt, int KK,
                                                   const float* __restrict__ bias, int Co,
                                                   unsigned short* __restrict__ yout,
                                                   int Lout, int LoutPad) {
    const int tid = threadIdx.x;
    const int b = blockIdx.z, co0 = blockIdx.y * 64, t0 = blockIdx.x * 256;
    const int lane = tid & 63, w = tid >> 6, c = lane & 15, q = lane >> 4;
    __shared__ __align__(16) unsigned short As[64 * 72];
    __shared__ __align__(16) unsigned short xraw[8 * 272];
    __shared__ unsigned short tabT[64 * 32];
    __shared__ int tok_s[272];
    for (int idx = tid; idx < 64 * V; idx += 256) {
        int ci = idx / V, v = idx % V;
        tabT[ci * 32 + v] = f2bf(table[(size_t)v * 64 + ci]);
    }
    for (int t = tid; t < 272; t += 256) {
        int gt = t0 + t;
        tok_s[t] = (gt < L) ? toks[(size_t)b * L + gt] : 0;  // row 0 is zeros
    }
    __syncthreads();
    f32x4 acc[4][4];
    #pragma unroll
    for (int i = 0; i < 4; ++i)
        #pragma unroll
        for (int j = 0; j < 4; ++j) acc[i][j] = (f32x4){0.f, 0.f, 0.f, 0.f};
    const int row8 = tid >> 3, col8 = (tid & 7) * 8;
    for (int ch = 0; ch < 8; ++ch) {
        const int kkbase = ch * 64, ci0 = ch * 8;
        #pragma unroll
        for (int p = 0; p < 2; ++p) {
            int row = row8 + p * 32;
            *(uint4*)&As[row * 72 + col8] =
                *(const uint4*)&Wt[(size_t)(co0 + row) * KK + kkbase + col8];
        }
        for (int gi = tid; gi < 8 * 272; gi += 256) {
            int ci = gi / 272, t = gi % 272;
            xraw[gi] = tabT[(ci0 + ci) * 32 + tok_s[t]];
        }
        __syncthreads();
        #pragma unroll
        for (int ks = 0; ks < 2; ++ks) {
            const int kc = ks * 32;
            FragU af[4];
            #pragma unroll
            for (int i = 0; i < 4; ++i)
                af[i].q = *(const uint4*)&As[(i * 16 + c) * 72 + kc + q * 8];
            const int koff = kc + q * 8;
            const int cioff = koff >> 3;
            const int k0 = koff & 7;
            const uint32_t* xr = (const uint32_t*)xraw + cioff * 136;
            #pragma unroll
            for (int j = 0; j < 4; ++j) {
                int tt = w * 64 + j * 16 + c;
                int eoff = tt + k0;
                int d0 = eoff >> 1;
                unsigned sh = (unsigned)(eoff & 1) * 16u;
                uint32_t u0 = xr[d0], u1 = xr[d0 + 1], u2 = xr[d0 + 2],
                         u3 = xr[d0 + 3], u4 = xr[d0 + 4];
                FragU bf;
                bf.u[0] = __builtin_amdgcn_alignbit(u1, u0, sh);
                bf.u[1] = __builtin_amdgcn_alignbit(u2, u1, sh);
                bf.u[2] = __builtin_amdgcn_alignbit(u3, u2, sh);
                bf.u[3] = __builtin_amdgcn_alignbit(u4, u3, sh);
                #pragma unroll
                for (int i = 0; i < 4; ++i)
                    acc[i][j] = __builtin_amdgcn_mfma_f32_16x16x32_bf16(af[i].s, bf.s,
                                                                        acc[i][j], 0, 0, 0);
            }
        }
        __syncthreads();
    }
    #pragma unroll
    for (int i = 0; i < 4; ++i) {
        #pragma unroll
        for (int r = 0; r < 4; ++r) {
            int co = co0 + i * 16 + q * 4 + r;
            if (co >= Co) continue;
            float bv = bias[co];
            #pragma unroll
            for (int j = 0; j < 4; ++j) {
                int t = t0 + w * 64 + j * 16 + c;
                if (t < Lout) {
                    yout[((size_t)b * Co + co) * LoutPad + t] =
                        f2bf(fmaxf(acc[i][j][r] + bv, 0.f));
                } else if (t < LoutPad) {
                    yout[((size_t)b * Co + co) * LoutPad + t] = 0;
                }
            }
        }
    }
}

// ---------------------------------------------------------------------------
// fp32 NT-SGEMM (FC head), split-K atomic into C[m*N+n]
__global__ __launch_bounds__(256) void gemm_nt(const float* __restrict__ A, int lda,
                                               const float* __restrict__ Bm,
                                               float* __restrict__ Cout,
                                               int M, int N, int K, int KC) {
    const int m0 = blockIdx.x * 64, n0 = blockIdx.y * 64, s = blockIdx.z;
    const int tid = threadIdx.x, ty = tid >> 4, tx = tid & 15;
    __shared__ __align__(16) float As[16][68];
    __shared__ __align__(16) float Bs[16][68];
    float acc[4][4] = {};
    const int kbeg = s * KC, kend = min(K, kbeg + KC);
    for (int k0 = kbeg; k0 < kend; k0 += 16) {
        int colk = k0 + tx;
        bool kok = colk < kend;
        #pragma unroll
        for (int qq = 0; qq < 4; ++qq) {
            int mi = ty + qq * 16;
            As[tx][mi] = (kok && (m0 + mi) < M) ? A[(size_t)(m0 + mi) * lda + colk] : 0.f;
            Bs[tx][mi] = (kok && (n0 + mi) < N) ? Bm[(size_t)(n0 + mi) * K + colk] : 0.f;
        }
        __syncthreads();
        #pragma unroll
        for (int kk = 0; kk < 16; ++kk) {
            float4 a4 = *(const float4*)&As[kk][ty * 4];
            float4 b4 = *(const float4*)&Bs[kk][tx * 4];
            float av[4] = {a4.x, a4.y, a4.z, a4.w};
            float bv[4] = {b4.x, b4.y, b4.z, b4.w};
            #pragma unroll
            for (int i = 0; i < 4; ++i)
                #pragma unroll
                for (int j = 0; j < 4; ++j)
                    acc[i][j] = fmaf(av[i], bv[j], acc[i][j]);
        }
        __syncthreads();
    }
    #pragma unroll
    for (int i = 0; i < 4; ++i) {
        int m = m0 + ty * 4 + i;
        if (m >= M) continue;
        #pragma unroll
        for (int j = 0; j < 4; ++j) {
            int n = n0 + tx * 4 + j;
            if (n >= N) continue;
            atomicAdd(&Cout[(size_t)m * N + n], acc[i][j]);
        }
    }
}

__global__ void epilogue_k(const float* __restrict__ C, const float* __restrict__ bias,
                           float* __restrict__ out, int M, int N, int act) {
    int idx = blockIdx.x * 256 + threadIdx.x;
    if (idx >= M * N) return;
    int m = idx / N, n = idx % N;
    float v = C[idx] + bias[n];
    if (act == 2) v = v >= 0.f ? v : 0.01f * v;
    out[(size_t)m * N + n] = v;
}

__global__ void out_k(const float* __restrict__ h3, const float* __restrict__ W,
                      const float* __restrict__ bias, float* __restrict__ out) {
    int tid = threadIdx.x;
    if (tid >= 128) return;
    int b = tid >> 1, n = tid & 1;
    const float* hr = h3 + (size_t)b * 512;
    const float* wr = W + (size_t)n * 512;
    float a = 0.f;
    for (int k = 0; k < 512; ++k) a = fmaf(hr[k], wr[k], a);
    out[b * 2 + n] = a + bias[n];
}

// ---------------------------------------------------------------------------
static inline int kc_of(int K, int S) { return ((K + S * 16 - 1) / (S * 16)) * 16; }
static inline dim3 g1d(int n) { return dim3((n + 255) / 256); }

extern "C" void kernel_launch(void* const* d_in, const int* in_sizes, int n_in,
                              void* d_out, int out_size, void* d_ws, size_t ws_size,
                              hipStream_t stream) {
    const int* drug_tokens       = (const int*)d_in[0];
    const int* protein_tokens    = (const int*)d_in[1];
    const int* drug_node_tokens  = (const int*)d_in[2];
    const int* protein_node_toks = (const int*)d_in[3];
    const int* ddi_edges         = (const int*)d_in[4];
    const int* ppi_edges         = (const int*)d_in[5];
    const int* dpi_edges         = (const int*)d_in[6];
    const float* drug_embed      = (const float*)d_in[7];
    const float* protein_embed   = (const float*)d_in[8];
    const float* dW1 = (const float*)d_in[9];  const float* db1 = (const float*)d_in[10];
    const float* dW2 = (const float*)d_in[11]; const float* db2 = (const float*)d_in[12];
    const float* dW3 = (const float*)d_in[13]; const float* db3 = (const float*)d_in[14];
    const float* pW1 = (const float*)d_in[15]; const float* pb1 = (const float*)d_in[16];
    const float* pW2 = (const float*)d_in[17]; const float* pb2 = (const float*)d_in[18];
    const float* pW3 = (const float*)d_in[19]; const float* pb3 = (const float*)d_in[20];
    const float* drug_node_table = (const float*)d_in[21];
    const float* prot_node_table = (const float*)d_in[22];
    const float* ddi_Wl = (const float*)d_in[23]; const float* ddi_bl = (const float*)d_in[24];
    const float* ddi_Wr = (const float*)d_in[25];
    const float* ppi_Wl = (const float*)d_in[26]; const float* ppi_bl = (const float*)d_in[27];
    const float* ppi_Wr = (const float*)d_in[28];
    const float* dpi_Wl = (const float*)d_in[29]; const float* dpi_bl = (const float*)d_in[30];
    const float* dpi_Wr = (const float*)d_in[31];
    const float* pdi_Wl = (const float*)d_in[32]; const float* pdi_bl = (const float*)d_in[33];
    const float* pdi_Wr = (const float*)d_in[34];
    const float* fc1_W = (const float*)d_in[35]; const float* fc1_b = (const float*)d_in[36];
    const float* fc2_W = (const float*)d_in[37]; const float* fc2_b = (const float*)d_in[38];
    const float* fc3_W = (const float*)d_in[39]; const float* fc3_b = (const float*)d_in[40];
    const float* out_W = (const float*)d_in[41]; const float* out_b = (const float*)d_in[42];

    float* outp = (float*)d_out;
    if (ws_size < NEED_BYTES) {
        zero32_k<<<g1d(out_size), 256, 0, stream>>>((uint32_t*)outp, out_size);
        return;
    }
    char* wsb = (char*)d_ws;
    float* pair = (float*)(wsb + O_PAIR);
    float* cf1 = (float*)(wsb + O_CF1); float* cf2 = (float*)(wsb + O_CF2);
    float* cf3 = (float*)(wsb + O_CF3);
    float* h1 = (float*)(wsb + O_H1); float* h2 = (float*)(wsb + O_H2);
    float* h3 = (float*)(wsb + O_H3);
    float* bd = (float*)(wsb + O_BD); float* bp = (float*)(wsb + O_BP);
    unsigned short* WdS  = (unsigned short*)(wsb + O_WDS);
    unsigned short* WpS  = (unsigned short*)(wsb + O_WPS);
    unsigned short* WtP1 = (unsigned short*)(wsb + O_WTP1);
    unsigned short* WtP2 = (unsigned short*)(wsb + O_WTP2);
    unsigned short* WtP3 = (unsigned short*)(wsb + O_WTP3);
    unsigned short* WtD1 = (unsigned short*)(wsb + O_WTD1);
    unsigned short* WtD2 = (unsigned short*)(wsb + O_WTD2);
    unsigned short* WtD3 = (unsigned short*)(wsb + O_WTD3);
    unsigned short* dx0 = (unsigned short*)(wsb + A_DX0);
    unsigned short* px0 = (unsigned short*)(wsb + A_PX0);
    unsigned short* Ad  = (unsigned short*)(wsb + A_AD);
    unsigned short* Ap  = (unsigned short*)(wsb + A_AP);
    unsigned short* A2d = (unsigned short*)(wsb + A_A2D);
    unsigned short* A2p = (unsigned short*)(wsb + A_A2P);
    float* Ud = (float*)(wsb + A_UD);
    float* Up = (float*)(wsb + A_UP);
    float* RS = (float*)(wsb + A_RS);
    unsigned short* y2p = (unsigned short*)(wsb + A_Y2P);
    unsigned short* y1p = (unsigned short*)(wsb + A_Y1P);
    unsigned short* x0d = (unsigned short*)(wsb + A_X0D);
    unsigned short* y1d = (unsigned short*)(wsb + A_Y1D);
    unsigned short* y2d = (unsigned short*)(wsb + A_Y2D);

    // 0) zeros: pair..cf3 (atomic targets); Ad..Up (concat pads + split-K accum)
    zero32_k<<<g1d(Z1_END / 4), 256, 0, stream>>>((uint32_t*)wsb, Z1_END / 4);
    zero32_k<<<g1d((int)Z2_CNT), 256, 0, stream>>>((uint32_t*)(wsb + Z2_BEG), (int)Z2_CNT);

    // 1) weight prep + layer-2 bias pre-fill
    prep_k<<<g1d((int)P13), 256, 0, stream>>>(bd, bp, WdS, WpS,
                                              WtP1, WtP2, WtP3, WtD1, WtD2, WtD3,
                                              ddi_Wl, ddi_bl, ddi_Wr,
                                              ppi_Wl, ppi_bl, ppi_Wr,
                                              dpi_Wl, dpi_bl, dpi_Wr,
                                              pdi_Wl, pdi_bl, pdi_Wr,
                                              dW1, dW2, dW3, pW1, pW2, pW3);
    biasfill_k<<<g1d(64 * 1100), 256, 0, stream>>>(pair, bd, bp);

    // 2) node features
    node_feat_k<<<dim3(32, 64), 256, 0, stream>>>(drug_node_tokens, drug_node_table, 71, 100, dx0, 104);
    node_feat_k<<<dim3(32, 64), 256, 0, stream>>>(protein_node_toks, prot_node_table, 26, 1000, px0, 1000);

    // 3) 2-hop aggregation weights + feature gathers into concat A matrices
    rs_k<<<dim3(64), 256, 0, stream>>>(ddi_edges, ppi_edges, dpi_edges, RS);
    fgather_k<<<dim3(14, 64), 256, 0, stream>>>(dx0, px0, RS, Ad, Ap);

    // 4) GNN stage 1: U = 0.5 * A @ Wcat^T (split-K atomic into zeroed U)
    gemm_sk3<<<dim3(2, 8, 3), 256, 0, stream>>>(Ad, 1248, WdS, 1248, 1248, 8, 0.5f,
                                                Ud, 112, 0, 100);
    gemm_sk3<<<dim3(16, 4, 3), 256, 0, stream>>>(Ap, 2208, WpS, 2208, 2208, 4, 0.5f,
                                                 Up, 1024, 0, 1000);
    ep_ud_k<<<g1d(192 * 112), 256, 0, stream>>>(Ud, RS, bd, A2d, A2p);
    ep_up_k<<<g1d(192 * 1024), 256, 0, stream>>>(Up, RS, bp, A2d, A2p);

    // 5) GNN stage 2 -> pair[:,320:1420) (atomicAdd onto pre-filled bias)
    gemm_sk3<<<dim3(2, 8, 1), 256, 0, stream>>>(A2d, 1248, WdS, 1248, 1248, 8, 0.5f,
                                                pair, 1420, 320, 100);
    gemm_sk3<<<dim3(16, 8, 1), 256, 0, stream>>>(A2p, 2208, WpS, 2208, 2208, 8, 0.5f,
                                                 pair, 1420, 420, 1000);

    // 6) protein conv tower (y2p region aliases dead GNN buffers)
    conv1e_mfma<<<dim3(4, 1, 64), 256, 0, stream>>>(protein_tokens, protein_embed, 26, 1000,
                                                    WtP1, 512, pb1, 40, y1p, 997, 1000);
    conv_mfma<8><<<dim3(4, 2, 64), 256, 0, stream>>>(y1p, 40, 1000, WtP2, 320, 5,
                                                     pb2, 80, y2p, 990, 992, nullptr, 0);
    conv_mfma<16><<<dim3(4, 3, 64), 256, 0, stream>>>(y2p, 80, 992, WtP3, 1280, 20,
                                                      pb3, 160, nullptr, 979, 0, pair, 160);

    // 7) drug conv tower (x0d region aliases dead y2p)
    embed_k<<<dim3(64, 8), 256, 0, stream>>>(drug_tokens, drug_embed, x0d, 100, 104);
    conv_mfma<8><<<dim3(1, 1, 64), 256, 0, stream>>>(x0d, 64, 104, WtD1, 512, 8,
                                                     db1, 40, y1d, 97, 104, nullptr, 0);
    conv_mfma<8><<<dim3(1, 2, 64), 256, 0, stream>>>(y1d, 40, 104, WtD2, 320, 5,
                                                     db2, 80, y2d, 92, 96, nullptr, 0);
    conv_mfma<8><<<dim3(1, 3, 64), 256, 0, stream>>>(y2d, 80, 96, WtD3, 640, 10,
                                                     db3, 160, nullptr, 85, 0, pair, 0);

    // 8) FC head (fp32, split-K 8)
    gemm_nt<<<dim3(1, 16, 8), 256, 0, stream>>>(pair, 1420, fc1_W, cf1, 64, 1024, 1420, kc_of(1420, 8));
    epilogue_k<<<g1d(64 * 1024), 256, 0, stream>>>(cf1, fc1_b, h1, 64, 1024, 2);
    gemm_nt<<<dim3(1, 16, 8), 256, 0, stream>>>(h1, 1024, fc2_W, cf2, 64, 1024, 1024, kc_of(1024, 8));
    epilogue_k<<<g1d(64 * 1024), 256, 0, stream>>>(cf2, fc2_b, h2, 64, 1024, 2);
    gemm_nt<<<dim3(1, 8, 8), 256, 0, stream>>>(h2, 1024, fc3_W, cf3, 64, 512, 1024, kc_of(1024, 8));
    epilogue_k<<<g1d(64 * 512), 256, 0, stream>>>(cf3, fc3_b, h3, 64, 512, 2);
    out_k<<<dim3(1), 128, 0, stream>>>(h3, out_W, out_b, outp);
}

// Round 6
// 517.074 us; speedup vs baseline: 6.4301x; 1.1070x over previous
//
#include <hip/hip_runtime.h>
#include <hip/hip_bf16.h>

// ---------------------------------------------------------------------------
// SSGraphDTI forward. bf16 MFMA convs + GNN (collapsed affine form), fp32 FC.
// R6: gnn_front_k fuses rs/node_feat/fgather via F = ((w*cnt)/L)@table;
// dual-dispatch conv kernels overlap drug & protein towers; FC split-K 16;
// merged zero/ep/prep launches.
// ---------------------------------------------------------------------------

typedef __attribute__((ext_vector_type(8))) short short8;
typedef __attribute__((ext_vector_type(4))) float f32x4;
union FragU { uint32_t u[4]; uint4 q; short8 s; };

static __device__ inline unsigned short f2bf(float v) {
    __hip_bfloat16 h = __float2bfloat16(v);
    return *(unsigned short*)&h;
}

// ---------------- workspace layout (byte offsets) ----------------
static constexpr size_t O_PAIR = 0;          // 64*1420 f32
static constexpr size_t O_CF1  = 363520;     // 64*1024 f32
static constexpr size_t O_CF2  = 625664;
static constexpr size_t O_CF3  = 887808;     // 64*512 f32
static constexpr size_t Z1_END = 1018880;    // zero span 1 [0, Z1_END)
static constexpr size_t O_H1   = 1018880;
static constexpr size_t O_H2   = 1281024;
static constexpr size_t O_H3   = 1543168;
static constexpr size_t O_BD   = 1674240;    // 128 f32
static constexpr size_t O_BP   = 1674752;    // 1024 f32
static constexpr size_t O_WDS  = 1678848;    // 128x1248 bf16
static constexpr size_t O_WPS  = 1998336;    // 1024x2208 bf16
static constexpr size_t O_WTP1 = 6520320;    // 64x512 bf16
static constexpr size_t O_WTP2 = 6585856;    // 128x320 bf16
static constexpr size_t O_WTP3 = 6667776;    // 192x1280 bf16
static constexpr size_t O_WTD1 = 7159296;    // 64x512 bf16
static constexpr size_t O_WTD2 = 7224832;    // 128x320 bf16
static constexpr size_t O_WTD3 = 7306752;    // 192x640 bf16
static constexpr size_t AR     = 7552512;    // aliased region base
// GNN phase:
static constexpr size_t A_AD  = AR + 0;        // 192x1248 bf16 = 479,232
static constexpr size_t A_AP  = AR + 479232;   // 192x2208 bf16 = 847,872
static constexpr size_t A_A2D = AR + 1327104;  // 64x1248 bf16
static constexpr size_t A_A2P = AR + 1486848;  // 64x2208 bf16
static constexpr size_t A_UD  = AR + 1769472;  // 192x112 f32
static constexpr size_t A_UP  = AR + 1855488;  // 192x1024 f32 -> 2,641,920
static constexpr size_t A_RHO = AR + 2641920;  // 64x4 f32
static constexpr size_t Z2_CNT = 2641920 / 4;  // words (Ad..Up)
// conv phase aliases (GNN dead by then):
static constexpr size_t A_Y2P = AR + 0;          // 64x80x992 bf16 = 10,158,080
static constexpr size_t A_Y1P = AR + 10158080;   // 64x40x1000 bf16 = 5,120,000
static constexpr size_t A_Y1D = AR + 15278080;   // 64x40x104 bf16 = 532,480
static constexpr size_t A_Y2D = AR + 10158080;   // 64x80x96 bf16 (aliases dead y1p)
static constexpr size_t NEED_BYTES = AR + 15810560;  // 23,363,072

// ---------------------------------------------------------------------------
__global__ void zero32_k(uint32_t* __restrict__ p, int n) {
    int i = blockIdx.x * 256 + threadIdx.x;
    if (i < n) p[i] = 0u;
}

__global__ void zero2_k(uint32_t* __restrict__ p1, int n1,
                        uint32_t* __restrict__ p2, int n2) {
    int i = blockIdx.x * 256 + threadIdx.x;
    if (i < n1) p1[i] = 0u;
    else if (i - n1 < n2) p2[i - n1] = 0u;
}

// ---------------- fused weight prep (+ layer-2 bias fill) ----------------
static constexpr long P0 = 100;                // bd
static constexpr long P1 = P0 + 1000;          // bp
static constexpr long P2 = P1 + 14336;         // WdS cols[0:112) = ddi_Wl
static constexpr long P3 = P2 + 14336;         // WdS cols[112:224) = ddi_Wr+pdi_Wr
static constexpr long P4 = P3 + 131072;        // WdS cols[224:1248) = pdi_Wl
static constexpr long P5 = P4 + 1048576;       // WpS cols[0:1024) = ppi_Wl
static constexpr long P6 = P5 + 1048576;       // WpS cols[1024:2048) = ppi_Wr+dpi_Wr
static constexpr long P7 = P6 + 163840;        // WpS cols[2048:2208) = dpi_Wl
static constexpr long P8 = P7 + 131072;        // (reserved, matches old pdiB slot) -> unused writes skipped
static constexpr long P9 = P8 + 32768;         // WtP1
static constexpr long P10 = P9 + 40960;        // WtP2
static constexpr long P11 = P10 + 245760;      // WtP3
static constexpr long P12 = P11 + 32768;       // WtD1
static constexpr long P13 = P12 + 40960;       // WtD2
static constexpr long P14 = P13 + 122880;      // WtD3
static constexpr long P15 = P14 + 70400;       // biasfill (64*1100)

__device__ inline void wt_block(unsigned short* dst, int ld_dst, int coloff,
                                const float* s1, const float* s2, int ld_src,
                                int N, int Kreal, int Kblk, long local) {
    int n = (int)(local / Kblk), k = (int)(local % Kblk);
    float v = 0.f;
    if (n < N && k < Kreal) {
        v = s1[(size_t)n * ld_src + k];
        if (s2) v += s2[(size_t)n * ld_src + k];
    }
    dst[(size_t)n * ld_dst + coloff + k] = f2bf(v);
}

__device__ inline void wtconv_block(unsigned short* dst, const float* W,
                                    int Co, int Ci, int K, int KP, long local) {
    int co = (int)(local / (Ci * KP));
    int rem = (int)(local % (Ci * KP));
    int ci = rem / KP, k = rem % KP;
    float v = (co < Co && k < K) ? W[((size_t)co * Ci + ci) * K + k] : 0.f;
    dst[local] = f2bf(v);
}

__global__ __launch_bounds__(256) void prep_k(
    float* bd, float* bp, unsigned short* WdS, unsigned short* WpS,
    unsigned short* WtP1, unsigned short* WtP2, unsigned short* WtP3,
    unsigned short* WtD1, unsigned short* WtD2, unsigned short* WtD3,
    float* pair,
    const float* ddi_Wl, const float* ddi_bl, const float* ddi_Wr,
    const float* ppi_Wl, const float* ppi_bl, const float* ppi_Wr,
    const float* dpi_Wl, const float* dpi_bl, const float* dpi_Wr,
    const float* pdi_Wl, const float* pdi_bl, const float* pdi_Wr,
    const float* dW1, const float* dW2, const float* dW3,
    const float* pW1, const float* pW2, const float* pW3) {
    long idx = (long)blockIdx.x * 256 + threadIdx.x;
    if (idx < P0) { bd[idx] = 0.5f * (ddi_bl[idx] + pdi_bl[idx]); return; }
    if (idx < P1) { long j = idx - P0; bp[j] = 0.5f * (ppi_bl[j] + dpi_bl[j]); return; }
    if (idx < P2) { wt_block(WdS, 1248, 0, ddi_Wl, nullptr, 100, 100, 100, 112, idx - P1); return; }
    if (idx < P3) { wt_block(WdS, 1248, 112, ddi_Wr, pdi_Wr, 100, 100, 100, 112, idx - P2); return; }
    if (idx < P4) { wt_block(WdS, 1248, 224, pdi_Wl, nullptr, 1000, 100, 1000, 1024, idx - P3); return; }
    if (idx < P5) { wt_block(WpS, 2208, 0, ppi_Wl, nullptr, 1000, 1000, 1000, 1024, idx - P4); return; }
    if (idx < P6) { wt_block(WpS, 2208, 1024, ppi_Wr, dpi_Wr, 1000, 1000, 1000, 1024, idx - P5); return; }
    if (idx < P7) { wt_block(WpS, 2208, 2048, dpi_Wl, nullptr, 100, 1000, 100, 160, idx - P6); return; }
    if (idx < P8)  { return; }  // reserved
    if (idx < P9)  { wtconv_block(WtP1, pW1, 40, 64, 4, 8, idx - P8); return; }
    if (idx < P10) { wtconv_block(WtP2, pW2, 80, 40, 8, 8, idx - P9); return; }
    if (idx < P11) { wtconv_block(WtP3, pW3, 160, 80, 12, 16, idx - P10); return; }
    if (idx < P12) { wtconv_block(WtD1, dW1, 40, 64, 4, 8, idx - P11); return; }
    if (idx < P13) { wtconv_block(WtD2, dW2, 80, 40, 6, 8, idx - P12); return; }
    if (idx < P14) { wtconv_block(WtD3, dW3, 160, 80, 8, 8, idx - P13); return; }
    if (idx < P15) {
        long l = idx - P14;
        int b = (int)(l / 1100), j = (int)(l % 1100);
        if (j < 100) pair[(size_t)b * 1420 + 320 + j] = bd[j];
        else pair[(size_t)b * 1420 + 420 + (j - 100)] = bp[j - 100];
        return;
    }
}

// ---------------------------------------------------------------------------
// GNN front-end, one block per (role, batch). role 0: drug-side (r-vectors,
// drug histogram, Fd1..Fd7); role 1: protein-side (s-vectors, Fp1..Fp7).
// F[i] = ((w_i . cnt)/L) @ table, written straight into Ad/Ap concat slots.
__global__ __launch_bounds__(256) void gnn_front_k(const int* __restrict__ ddi,
                                                   const int* __restrict__ ppi,
                                                   const int* __restrict__ dpi,
                                                   const int* __restrict__ dtoks,
                                                   const int* __restrict__ ptoks,
                                                   const float* __restrict__ dtable,
                                                   const float* __restrict__ ptable,
                                                   float* __restrict__ RHO,
                                                   unsigned short* __restrict__ Ad,
                                                   unsigned short* __restrict__ Ap) {
    const int role = blockIdx.x, b = blockIdx.y, tid = threadIdx.x;
    __shared__ float M[4][32][32];
    __shared__ int cnt4[4][32];
    __shared__ float inv4[4][32];
    __shared__ float W7[7][32];
    __shared__ int cnt[32][72];
    __shared__ float WC[7][72];
    // --- adjacency mean-matrices (same as verified rs_k) ---
    for (int i = tid; i < 4 * 32 * 32; i += 256) ((float*)M)[i] = 0.f;
    if (tid < 128) ((int*)cnt4)[tid] = 0;
    __syncthreads();
    const int* ed = ddi + (size_t)b * 256;
    const int* ep = ppi + (size_t)b * 256;
    const int* ex = dpi + (size_t)b * 128;
    if (tid < 128) {
        atomicAdd(&cnt4[0][ed[128 + tid]], 1);
        atomicAdd(&cnt4[1][ep[128 + tid]], 1);
    } else if (tid < 192) {
        int e = tid - 128;
        atomicAdd(&cnt4[2][ex[e]], 1);
        atomicAdd(&cnt4[3][ex[64 + e]], 1);
    }
    __syncthreads();
    if (tid < 128) {
        int which = tid >> 5, j = tid & 31;
        inv4[which][j] = 1.f / (float)max(cnt4[which][j], 1);
    }
    __syncthreads();
    if (tid < 128) {
        int s = ed[tid], d = ed[128 + tid];
        atomicAdd(&M[0][d][s], inv4[0][d]);
        int s2 = ep[tid], d2 = ep[128 + tid];
        atomicAdd(&M[1][d2][s2], inv4[1][d2]);
    } else if (tid < 192) {
        int e = tid - 128;
        int dr = ex[e], pr = ex[64 + e];
        atomicAdd(&M[2][dr][pr], inv4[2][dr]);
        atomicAdd(&M[3][pr][dr], inv4[3][pr]);
    }
    __syncthreads();
    // --- weight vectors ---
    if (tid < 32) {
        int j = tid;
        if (role == 0) {
            float r1 = 0.f, r4 = 0.f, r5 = 0.f, r7 = 0.f;
            for (int k = 0; k < 32; ++k) {
                r1 += M[0][0][k] * M[0][k][j];
                r4 += M[2][0][k] * M[3][k][j];
                r5 += M[1][0][k] * M[3][k][j];
                r7 += M[3][0][k] * M[0][k][j];
            }
            W7[0][j] = r1; W7[1][j] = M[0][0][j]; W7[2][j] = (j == 0) ? 1.f : 0.f;
            W7[3][j] = r4; W7[4][j] = r5; W7[5][j] = M[3][0][j]; W7[6][j] = r7;
        } else {
            float s1 = 0.f, s3 = 0.f, s4 = 0.f, s7 = 0.f;
            for (int k = 0; k < 32; ++k) {
                s1 += M[0][0][k] * M[2][k][j];
                s3 += M[2][0][k] * M[1][k][j];
                s4 += M[1][0][k] * M[1][k][j];
                s7 += M[3][0][k] * M[2][k][j];
            }
            W7[0][j] = s1; W7[1][j] = M[2][0][j]; W7[2][j] = s3;
            W7[3][j] = s4; W7[4][j] = M[1][0][j];
            W7[5][j] = (j == 0) ? 1.f : 0.f; W7[6][j] = s7;
        }
    }
    if (role == 0 && tid == 0) {
        float a = 0.f, bq = 0.f, cq = 0.f, dq = 0.f;
        for (int k = 0; k < 32; ++k) {
            a += M[0][0][k]; bq += M[2][0][k]; cq += M[1][0][k]; dq += M[3][0][k];
        }
        RHO[b * 4 + 0] = a; RHO[b * 4 + 1] = bq; RHO[b * 4 + 2] = cq; RHO[b * 4 + 3] = dq;
    }
    // --- token histogram ---
    const int V = role ? 26 : 71;
    const int L = role ? 1000 : 100;
    for (int i = tid; i < 32 * 72; i += 256) ((int*)cnt)[i] = 0;
    __syncthreads();
    const int* tk = (role ? ptoks : dtoks) + (size_t)b * 32 * L;
    for (int i = tid; i < 32 * L; i += 256) atomicAdd(&cnt[i / L][tk[i]], 1);
    __syncthreads();
    // --- WC = (w . cnt) / L ---
    float invL = 1.f / (float)L;
    for (int o = tid; o < 7 * V; o += 256) {
        int i = o / V, v = o % V;
        float a = 0.f;
        for (int k = 0; k < 32; ++k) a += W7[i][k] * (float)cnt[k][v];
        WC[i][v] = a * invL;
    }
    __syncthreads();
    // --- F = WC @ table -> bf16 slots ---
    size_t g0d = (size_t)b * 1248, g1d_ = (size_t)(64 + b) * 1248, g2d = (size_t)(128 + b) * 1248;
    size_t g0p = (size_t)b * 2208, g1p = (size_t)(64 + b) * 2208, g2p = (size_t)(128 + b) * 2208;
    if (role == 0) {
        int d = tid;
        if (d >= 100) return;
        float acc[7] = {};
        for (int v = 0; v < 71; ++v) {
            float tv = dtable[(size_t)v * 100 + d];
            #pragma unroll
            for (int i = 0; i < 7; ++i) acc[i] += WC[i][v] * tv;
        }
        unsigned short h;
        h = f2bf(acc[0]); Ad[g0d + d] = h;                                   // r1
        h = f2bf(acc[1]); Ad[g0d + 112 + d] = h; Ad[g1d_ + d] = h;           // r2
        h = f2bf(acc[2]); Ad[g1d_ + 112 + d] = h;                            // r3
        h = f2bf(acc[3]); Ap[g0p + 2048 + d] = h;                            // r4
        h = f2bf(acc[4]); Ap[g1p + 2048 + d] = h;                            // r5
        h = f2bf(acc[5]); Ap[g2p + 2048 + d] = h; Ad[g2d + 112 + d] = h;     // r6
        h = f2bf(acc[6]); Ad[g2d + d] = h;                                   // r7
    } else {
        for (int d = tid; d < 1000; d += 256) {
            float acc[7] = {};
            for (int v = 0; v < 26; ++v) {
                float tv = ptable[(size_t)v * 1000 + d];
                #pragma unroll
                for (int i = 0; i < 7; ++i) acc[i] += WC[i][v] * tv;
            }
            unsigned short h;
            h = f2bf(acc[0]); Ad[g0d + 224 + d] = h;                          // s1
            h = f2bf(acc[1]); Ad[g1d_ + 224 + d] = h; Ap[g0p + 1024 + d] = h; // s2
            h = f2bf(acc[2]); Ap[g0p + d] = h;                                // s3
            h = f2bf(acc[3]); Ap[g1p + d] = h;                                // s4
            h = f2bf(acc[4]); Ap[g1p + 1024 + d] = h; Ap[g2p + d] = h;        // s5
            h = f2bf(acc[5]); Ap[g2p + 1024 + d] = h;                         // s6
            h = f2bf(acc[6]); Ad[g2d + 224 + d] = h;                          // s7
        }
    }
}

// ---------------------------------------------------------------------------
// skinny bf16 MFMA GEMM, split-K + m-groups; atomicAdd fp32 outputs.
__global__ __launch_bounds__(256) void gemm_sk3(const unsigned short* __restrict__ A, int lda,
                                                const unsigned short* __restrict__ Bm, int ldb,
                                                int K, int KS, float scale,
                                                float* __restrict__ out,
                                                int rs, int coloff, int Nw) {
    const int tid = threadIdx.x;
    const int lane = tid & 63, w = tid >> 6, c = lane & 15, q = lane >> 4;
    const int n = blockIdx.x * 64 + w * 16 + c;
    const int gz = blockIdx.z;
    const unsigned short* Ab = A + (size_t)gz * 64 * lda;
    const int Ks = ((K / KS + 31) / 32) * 32;
    const int k0 = blockIdx.y * Ks;
    const int k1 = min(K, k0 + Ks);
    f32x4 acc[4];
    #pragma unroll
    for (int i = 0; i < 4; ++i) acc[i] = (f32x4){0.f, 0.f, 0.f, 0.f};
    for (int k = k0; k < k1; k += 32) {
        FragU bf;
        bf.q = *(const uint4*)&Bm[(size_t)n * ldb + k + q * 8];
        #pragma unroll
        for (int i = 0; i < 4; ++i) {
            FragU af;
            af.q = *(const uint4*)&Ab[(size_t)(i * 16 + c) * lda + k + q * 8];
            acc[i] = __builtin_amdgcn_mfma_f32_16x16x32_bf16(af.s, bf.s, acc[i], 0, 0, 0);
        }
    }
    if (n >= Nw) return;
    #pragma unroll
    for (int i = 0; i < 4; ++i)
        #pragma unroll
        for (int r = 0; r < 4; ++r) {
            int m = gz * 64 + i * 16 + q * 4 + r;
            atomicAdd(&out[(size_t)m * rs + coloff + n], scale * acc[i][r]);
        }
}

// merged stage-1 epilogue: Ud/Up + rho*bias -> bf16 A2 slots
__global__ void ep_k(const float* __restrict__ Ud, const float* __restrict__ Up,
                     const float* __restrict__ RHO,
                     const float* __restrict__ bd, const float* __restrict__ bp,
                     unsigned short* __restrict__ A2d, unsigned short* __restrict__ A2p) {
    int idx = blockIdx.x * 256 + threadIdx.x;
    if (idx < 192 * 112) {
        int m = idx / 112, n = idx % 112;
        if (n >= 100) return;
        int g = m >> 6, b = m & 63;
        float rho = (g == 0) ? RHO[b * 4 + 0] : (g == 1) ? 1.f : RHO[b * 4 + 3];
        unsigned short h = f2bf(Ud[idx] + rho * bd[n]);
        if (g == 0) A2d[(size_t)b * 1248 + n] = h;
        else if (g == 1) A2d[(size_t)b * 1248 + 112 + n] = h;
        else A2p[(size_t)b * 2208 + 2048 + n] = h;
    } else {
        int l = idx - 192 * 112;
        if (l >= 192 * 1024) return;
        int m = l / 1024, n = l % 1024;
        if (n >= 1000) return;
        int g = m >> 6, b = m & 63;
        float rho = (g == 0) ? RHO[b * 4 + 1] : (g == 1) ? RHO[b * 4 + 2] : 1.f;
        unsigned short h = f2bf(Up[l] + rho * bp[n]);
        if (g == 0) A2d[(size_t)b * 1248 + 224 + n] = h;
        else if (g == 1) A2p[(size_t)b * 2208 + n] = h;
        else A2p[(size_t)b * 2208 + 1024 + n] = h;
    }
}

// ---------------------------------------------------------------------------
// conv1d implicit-GEMM bf16 MFMA body (shared buffers passed in).
template <int KP>
__device__ __forceinline__ void conv_body(const unsigned short* __restrict__ xin,
                                          int Ci, int Lp,
                                          const unsigned short* __restrict__ Wt, int KK,
                                          int nchunk,
                                          const float* __restrict__ bias, int Co,
                                          unsigned short* __restrict__ yout,
                                          int Lout, int LoutPad,
                                          float* __restrict__ pool, int pool_coloff,
                                          int b, int co0, int t0,
                                          unsigned short* As, unsigned short* xraw) {
    constexpr int CIPC = 64 / KP;
    constexpr int LG = (KP == 8) ? 3 : 4;
    const int tid = threadIdx.x;
    const int lane = tid & 63, w = tid >> 6, c = lane & 15, q = lane >> 4;
    f32x4 acc[4][4];
    #pragma unroll
    for (int i = 0; i < 4; ++i)
        #pragma unroll
        for (int j = 0; j < 4; ++j) acc[i][j] = (f32x4){0.f, 0.f, 0.f, 0.f};
    const int row8 = tid >> 3, col8 = (tid & 7) * 8;
    for (int ch = 0; ch < nchunk; ++ch) {
        const int kkbase = ch * 64, ci0 = ch * CIPC;
        #pragma unroll
        for (int p = 0; p < 2; ++p) {
            int row = row8 + p * 32;
            *(uint4*)&As[row * 72 + col8] =
                *(const uint4*)&Wt[(size_t)(co0 + row) * KK + kkbase + col8];
        }
        for (int gi = tid; gi < CIPC * 34; gi += 256) {
            int ci = gi / 34, g8 = (gi % 34) * 8, gt = t0 + g8;
            const unsigned short* src = xin + ((size_t)b * Ci + ci0 + ci) * Lp + gt;
            if (gt + 8 <= Lp) {
                *(uint4*)&xraw[ci * 272 + g8] = *(const uint4*)src;
            } else {
                #pragma unroll
                for (int jj = 0; jj < 8; ++jj)
                    xraw[ci * 272 + g8 + jj] = (gt + jj < Lp) ? src[jj] : (unsigned short)0;
            }
        }
        __syncthreads();
        #pragma unroll
        for (int ks = 0; ks < 2; ++ks) {
            const int kc = ks * 32;
            FragU af[4];
            #pragma unroll
            for (int i = 0; i < 4; ++i)
                af[i].q = *(const uint4*)&As[(i * 16 + c) * 72 + kc + q * 8];
            const int koff = kc + q * 8;
            const int cioff = koff >> LG;
            const int k0 = koff & (KP - 1);
            const uint32_t* xr = (const uint32_t*)xraw + cioff * 136;
            #pragma unroll
            for (int j = 0; j < 4; ++j) {
                int tt = w * 64 + j * 16 + c;
                int eoff = tt + k0;
                int d0 = eoff >> 1;
                unsigned sh = (unsigned)(eoff & 1) * 16u;
                uint32_t u0 = xr[d0], u1 = xr[d0 + 1], u2 = xr[d0 + 2],
                         u3 = xr[d0 + 3], u4 = xr[d0 + 4];
                FragU bf;
                bf.u[0] = __builtin_amdgcn_alignbit(u1, u0, sh);
                bf.u[1] = __builtin_amdgcn_alignbit(u2, u1, sh);
                bf.u[2] = __builtin_amdgcn_alignbit(u3, u2, sh);
                bf.u[3] = __builtin_amdgcn_alignbit(u4, u3, sh);
                #pragma unroll
                for (int i = 0; i < 4; ++i)
                    acc[i][j] = __builtin_amdgcn_mfma_f32_16x16x32_bf16(af[i].s, bf.s,
                                                                        acc[i][j], 0, 0, 0);
            }
        }
        __syncthreads();
    }
    if (pool) {
        #pragma unroll
        for (int i = 0; i < 4; ++i) {
            #pragma unroll
            for (int r = 0; r < 4; ++r) {
                int co = co0 + i * 16 + q * 4 + r;
                float bv = (co < Co) ? bias[co] : 0.f;
                float v = 0.f;
                #pragma unroll
                for (int j = 0; j < 4; ++j) {
                    int t = t0 + w * 64 + j * 16 + c;
                    if (t < Lout) v = fmaxf(v, fmaxf(acc[i][j][r] + bv, 0.f));
                }
                v = fmaxf(v, __shfl_xor(v, 1));
                v = fmaxf(v, __shfl_xor(v, 2));
                v = fmaxf(v, __shfl_xor(v, 4));
                v = fmaxf(v, __shfl_xor(v, 8));
                if (c == 0 && co < Co)
                    atomicMax((int*)&pool[(size_t)b * 1420 + pool_coloff + co],
                              __float_as_int(v));
            }
        }
    } else {
        #pragma unroll
        for (int i = 0; i < 4; ++i) {
            #pragma unroll
            for (int r = 0; r < 4; ++r) {
                int co = co0 + i * 16 + q * 4 + r;
                if (co >= Co) continue;
                float bv = bias[co];
                #pragma unroll
                for (int j = 0; j < 4; ++j) {
                    int t = t0 + w * 64 + j * 16 + c;
                    if (t < Lout) {
                        yout[((size_t)b * Co + co) * LoutPad + t] =
                            f2bf(fmaxf(acc[i][j][r] + bv, 0.f));
                    } else if (t < LoutPad) {
                        yout[((size_t)b * Co + co) * LoutPad + t] = 0;
                    }
                }
            }
        }
    }
}

template <int KP>
__global__ __launch_bounds__(256) void conv_mfma(const unsigned short* __restrict__ xin,
                                                 int Ci, int Lp,
                                                 const unsigned short* __restrict__ Wt, int KK,
                                                 int nchunk,
                                                 const float* __restrict__ bias, int Co,
                                                 unsigned short* __restrict__ yout,
                                                 int Lout, int LoutPad,
                                                 float* __restrict__ pool, int pool_coloff) {
    __shared__ __align__(16) unsigned short As[64 * 72];
    __shared__ __align__(16) unsigned short xraw[(64 / KP) * 272];
    conv_body<KP>(xin, Ci, Lp, Wt, KK, nchunk, bias, Co, yout, Lout, LoutPad,
                  pool, pool_coloff, blockIdx.z, blockIdx.y * 64, blockIdx.x * 256,
                  As, xraw);
}

// conv1 with fused embedding lookup (runtime V <= 71). KP=8, Ci=64.
__device__ __forceinline__ void conv1e_body(const int* __restrict__ toks,
                                            const float* __restrict__ table, int V, int L,
                                            const unsigned short* __restrict__ Wt, int KK,
                                            const float* __restrict__ bias, int Co,
                                            unsigned short* __restrict__ yout,
                                            int Lout, int LoutPad,
                                            int b, int co0, int t0,
                                            unsigned short* As, unsigned short* xraw,
                                            unsigned short* tabT, int* tok_s) {
    const int tid = threadIdx.x;
    const int lane = tid & 63, w = tid >> 6, c = lane & 15, q = lane >> 4;
    for (int idx = tid; idx < 64 * V; idx += 256) {
        int ci = idx / V, v = idx % V;
        tabT[ci * 72 + v] = f2bf(table[(size_t)v * 64 + ci]);
    }
    for (int t = tid; t < 272; t += 256) {
        int gt = t0 + t;
        tok_s[t] = (gt < L) ? toks[(size_t)b * L + gt] : 0;  // row 0 is zeros
    }
    __syncthreads();
    f32x4 acc[4][4];
    #pragma unroll
    for (int i = 0; i < 4; ++i)
        #pragma unroll
        for (int j = 0; j < 4; ++j) acc[i][j] = (f32x4){0.f, 0.f, 0.f, 0.f};
    const int row8 = tid >> 3, col8 = (tid & 7) * 8;
    for (int ch = 0; ch < 8; ++ch) {
        const int kkbase = ch * 64, ci0 = ch * 8;
        #pragma unroll
        for (int p = 0; p < 2; ++p) {
            int row = row8 + p * 32;
            *(uint4*)&As[row * 72 + col8] =
                *(const uint4*)&Wt[(size_t)(co0 + row) * KK + kkbase + col8];
        }
        for (int gi = tid; gi < 8 * 272; gi += 256) {
            int ci = gi / 272, t = gi % 272;
            xraw[gi] = tabT[(ci0 + ci) * 72 + tok_s[t]];
        }
        __syncthreads();
        #pragma unroll
        for (int ks = 0; ks < 2; ++ks) {
            const int kc = ks * 32;
            FragU af[4];
            #pragma unroll
            for (int i = 0; i < 4; ++i)
                af[i].q = *(const uint4*)&As[(i * 16 + c) * 72 + kc + q * 8];
            const int koff = kc + q * 8;
            const int cioff = koff >> 3;
            const int k0 = koff & 7;
            const uint32_t* xr = (const uint32_t*)xraw + cioff * 136;
            #pragma unroll
            for (int j = 0; j < 4; ++j) {
                int tt = w * 64 + j * 16 + c;
                int eoff = tt + k0;
                int d0 = eoff >> 1;
                unsigned sh = (unsigned)(eoff & 1) * 16u;
                uint32_t u0 = xr[d0], u1 = xr[d0 + 1], u2 = xr[d0 + 2],
                         u3 = xr[d0 + 3], u4 = xr[d0 + 4];
                FragU bf;
                bf.u[0] = __builtin_amdgcn_alignbit(u1, u0, sh);
                bf.u[1] = __builtin_amdgcn_alignbit(u2, u1, sh);
                bf.u[2] = __builtin_amdgcn_alignbit(u3, u2, sh);
                bf.u[3] = __builtin_amdgcn_alignbit(u4, u3, sh);
                #pragma unroll
                for (int i = 0; i < 4; ++i)
                    acc[i][j] = __builtin_amdgcn_mfma_f32_16x16x32_bf16(af[i].s, bf.s,
                                                                        acc[i][j], 0, 0, 0);
            }
        }
        __syncthreads();
    }
    #pragma unroll
    for (int i = 0; i < 4; ++i) {
        #pragma unroll
        for (int r = 0; r < 4; ++r) {
            int co = co0 + i * 16 + q * 4 + r;
            if (co >= Co) continue;
            float bv = bias[co];
            #pragma unroll
            for (int j = 0; j < 4; ++j) {
                int t = t0 + w * 64 + j * 16 + c;
                if (t < Lout) {
                    yout[((size_t)b * Co + co) * LoutPad + t] =
                        f2bf(fmaxf(acc[i][j][r] + bv, 0.f));
                } else if (t < LoutPad) {
                    yout[((size_t)b * Co + co) * LoutPad + t] = 0;
                }
            }
        }
    }
}

// dual conv1: z<64 protein conv1e, z>=64 drug conv1e. grid (4,1,128)
__global__ __launch_bounds__(256) void conv1_dual(
    const int* __restrict__ ptoks, const float* __restrict__ ptable,
    const unsigned short* __restrict__ WtP1, const float* __restrict__ pb1,
    unsigned short* __restrict__ y1p,
    const int* __restrict__ dtoks, const float* __restrict__ dtable,
    const unsigned short* __restrict__ WtD1, const float* __restrict__ db1,
    unsigned short* __restrict__ y1d) {
    __shared__ __align__(16) unsigned short As[64 * 72];
    __shared__ __align__(16) unsigned short xraw[8 * 272];
    __shared__ unsigned short tabT[64 * 72];
    __shared__ int tok_s[272];
    int z = blockIdx.z;
    if (z < 64) {
        conv1e_body(ptoks, ptable, 26, 1000, WtP1, 512, pb1, 40, y1p, 997, 1000,
                    z, blockIdx.y * 64, blockIdx.x * 256, As, xraw, tabT, tok_s);
    } else {
        if (blockIdx.x > 0) return;
        conv1e_body(dtoks, dtable, 71, 100, WtD1, 512, db1, 40, y1d, 97, 104,
                    z - 64, blockIdx.y * 64, 0, As, xraw, tabT, tok_s);
    }
}

// dual conv3: z<64 protein conv3 (KP=16, pool), z>=64 drug conv2 (KP=8).
// grid (4,3,128)
__global__ __launch_bounds__(256) void conv3_dual(
    const unsigned short* __restrict__ y2p, const unsigned short* __restrict__ WtP3,
    const float* __restrict__ pb3, float* __restrict__ pair,
    const unsigned short* __restrict__ y1d, const unsigned short* __restrict__ WtD2,
    const float* __restrict__ db2, unsigned short* __restrict__ y2d) {
    __shared__ __align__(16) unsigned short As[64 * 72];
    __shared__ __align__(16) unsigned short xraw[8 * 272];
    int z = blockIdx.z;
    if (z < 64) {
        conv_body<16>(y2p, 80, 992, WtP3, 1280, 20, pb3, 160, nullptr, 979, 0,
                      pair, 160, z, blockIdx.y * 64, blockIdx.x * 256, As, xraw);
    } else {
        if (blockIdx.x > 0 || blockIdx.y > 1) return;
        conv_body<8>(y1d, 40, 104, WtD2, 320, 5, db2, 80, y2d, 92, 96,
                     nullptr, 0, z - 64, blockIdx.y * 64, 0, As, xraw);
    }
}

// ---------------------------------------------------------------------------
// fp32 NT-SGEMM (FC head), split-K atomic into C[m*N+n]
__global__ __launch_bounds__(256) void gemm_nt(const float* __restrict__ A, int lda,
                                               const float* __restrict__ Bm,
                                               float* __restrict__ Cout,
                                               int M, int N, int K, int KC) {
    const int m0 = blockIdx.x * 64, n0 = blockIdx.y * 64, s = blockIdx.z;
    const int tid = threadIdx.x, ty = tid >> 4, tx = tid & 15;
    __shared__ __align__(16) float As[16][68];
    __shared__ __align__(16) float Bs[16][68];
    float acc[4][4] = {};
    const int kbeg = s * KC, kend = min(K, kbeg + KC);
    for (int k0 = kbeg; k0 < kend; k0 += 16) {
        int colk = k0 + tx;
        bool kok = colk < kend;
        #pragma unroll
        for (int qq = 0; qq < 4; ++qq) {
            int mi = ty + qq * 16;
            As[tx][mi] = (kok && (m0 + mi) < M) ? A[(size_t)(m0 + mi) * lda + colk] : 0.f;
            Bs[tx][mi] = (kok && (n0 + mi) < N) ? Bm[(size_t)(n0 + mi) * K + colk] : 0.f;
        }
        __syncthreads();
        #pragma unroll
        for (int kk = 0; kk < 16; ++kk) {
            float4 a4 = *(const float4*)&As[kk][ty * 4];
            float4 b4 = *(const float4*)&Bs[kk][tx * 4];
            float av[4] = {a4.x, a4.y, a4.z, a4.w};
            float bv[4] = {b4.x, b4.y, b4.z, b4.w};
            #pragma unroll
            for (int i = 0; i < 4; ++i)
                #pragma unroll
                for (int j = 0; j < 4; ++j)
                    acc[i][j] = fmaf(av[i], bv[j], acc[i][j]);
        }
        __syncthreads();
    }
    #pragma unroll
    for (int i = 0; i < 4; ++i) {
        int m = m0 + ty * 4 + i;
        if (m >= M) continue;
        #pragma unroll
        for (int j = 0; j < 4; ++j) {
            int n = n0 + tx * 4 + j;
            if (n >= N) continue;
            atomicAdd(&Cout[(size_t)m * N + n], acc[i][j]);
        }
    }
}

__global__ void epilogue_k(const float* __restrict__ C, const float* __restrict__ bias,
                           float* __restrict__ out, int M, int N, int act) {
    int idx = blockIdx.x * 256 + threadIdx.x;
    if (idx >= M * N) return;
    int m = idx / N, n = idx % N;
    float v = C[idx] + bias[n];
    if (act == 2) v = v >= 0.f ? v : 0.01f * v;
    out[(size_t)m * N + n] = v;
}

__global__ void out_k(const float* __restrict__ h3, const float* __restrict__ W,
                      const float* __restrict__ bias, float* __restrict__ out) {
    int tid = threadIdx.x;
    if (tid >= 128) return;
    int b = tid >> 1, n = tid & 1;
    const float* hr = h3 + (size_t)b * 512;
    const float* wr = W + (size_t)n * 512;
    float a = 0.f;
    for (int k = 0; k < 512; ++k) a = fmaf(hr[k], wr[k], a);
    out[b * 2 + n] = a + bias[n];
}

// ---------------------------------------------------------------------------
static inline int kc_of(int K, int S) { return ((K + S * 16 - 1) / (S * 16)) * 16; }
static inline dim3 g1d(int n) { return dim3((n + 255) / 256); }

extern "C" void kernel_launch(void* const* d_in, const int* in_sizes, int n_in,
                              void* d_out, int out_size, void* d_ws, size_t ws_size,
                              hipStream_t stream) {
    const int* drug_tokens       = (const int*)d_in[0];
    const int* protein_tokens    = (const int*)d_in[1];
    const int* drug_node_tokens  = (const int*)d_in[2];
    const int* protein_node_toks = (const int*)d_in[3];
    const int* ddi_edges         = (const int*)d_in[4];
    const int* ppi_edges         = (const int*)d_in[5];
    const int* dpi_edges         = (const int*)d_in[6];
    const float* drug_embed      = (const float*)d_in[7];
    const float* protein_embed   = (const float*)d_in[8];
    const float* dW1 = (const float*)d_in[9];  const float* db1 = (const float*)d_in[10];
    const float* dW2 = (const float*)d_in[11]; const float* db2 = (const float*)d_in[12];
    const float* dW3 = (const float*)d_in[13]; const float* db3 = (const float*)d_in[14];
    const float* pW1 = (const float*)d_in[15]; const float* pb1 = (const float*)d_in[16];
    const float* pW2 = (const float*)d_in[17]; const float* pb2 = (const float*)d_in[18];
    const float* pW3 = (const float*)d_in[19]; const float* pb3 = (const float*)d_in[20];
    const float* drug_node_table = (const float*)d_in[21];
    const float* prot_node_table = (const float*)d_in[22];
    const float* ddi_Wl = (const float*)d_in[23]; const float* ddi_bl = (const float*)d_in[24];
    const float* ddi_Wr = (const float*)d_in[25];
    const float* ppi_Wl = (const float*)d_in[26]; const float* ppi_bl = (const float*)d_in[27];
    const float* ppi_Wr = (const float*)d_in[28];
    const float* dpi_Wl = (const float*)d_in[29]; const float* dpi_bl = (const float*)d_in[30];
    const float* dpi_Wr = (const float*)d_in[31];
    const float* pdi_Wl = (const float*)d_in[32]; const float* pdi_bl = (const float*)d_in[33];
    const float* pdi_Wr = (const float*)d_in[34];
    const float* fc1_W = (const float*)d_in[35]; const float* fc1_b = (const float*)d_in[36];
    const float* fc2_W = (const float*)d_in[37]; const float* fc2_b = (const float*)d_in[38];
    const float* fc3_W = (const float*)d_in[39]; const float* fc3_b = (const float*)d_in[40];
    const float* out_W = (const float*)d_in[41]; const float* out_b = (const float*)d_in[42];

    float* outp = (float*)d_out;
    if (ws_size < NEED_BYTES) {
        zero32_k<<<g1d(out_size), 256, 0, stream>>>((uint32_t*)outp, out_size);
        return;
    }
    char* wsb = (char*)d_ws;
    float* pair = (float*)(wsb + O_PAIR);
    float* cf1 = (float*)(wsb + O_CF1); float* cf2 = (float*)(wsb + O_CF2);
    float* cf3 = (float*)(wsb + O_CF3);
    float* h1 = (float*)(wsb + O_H1); float* h2 = (float*)(wsb + O_H2);
    float* h3 = (float*)(wsb + O_H3);
    float* bd = (float*)(wsb + O_BD); float* bp = (float*)(wsb + O_BP);
    unsigned short* WdS  = (unsigned short*)(wsb + O_WDS);
    unsigned short* WpS  = (unsigned short*)(wsb + O_WPS);
    unsigned short* WtP1 = (unsigned short*)(wsb + O_WTP1);
    unsigned short* WtP2 = (unsigned short*)(wsb + O_WTP2);
    unsigned short* WtP3 = (unsigned short*)(wsb + O_WTP3);
    unsigned short* WtD1 = (unsigned short*)(wsb + O_WTD1);
    unsigned short* WtD2 = (unsigned short*)(wsb + O_WTD2);
    unsigned short* WtD3 = (unsigned short*)(wsb + O_WTD3);
    unsigned short* Ad  = (unsigned short*)(wsb + A_AD);
    unsigned short* Ap  = (unsigned short*)(wsb + A_AP);
    unsigned short* A2d = (unsigned short*)(wsb + A_A2D);
    unsigned short* A2p = (unsigned short*)(wsb + A_A2P);
    float* Ud  = (float*)(wsb + A_UD);
    float* Up  = (float*)(wsb + A_UP);
    float* RHO = (float*)(wsb + A_RHO);
    unsigned short* y2p = (unsigned short*)(wsb + A_Y2P);
    unsigned short* y1p = (unsigned short*)(wsb + A_Y1P);
    unsigned short* y1d = (unsigned short*)(wsb + A_Y1D);
    unsigned short* y2d = (unsigned short*)(wsb + A_Y2D);

    // 0) zero fp32 atomic targets + GNN concat/accum region (one launch)
    zero2_k<<<g1d((int)(Z1_END / 4 + Z2_CNT)), 256, 0, stream>>>(
        (uint32_t*)wsb, (int)(Z1_END / 4), (uint32_t*)(wsb + A_AD), (int)Z2_CNT);

    // 1) weight prep + layer-2 bias pre-fill (single launch)
    prep_k<<<g1d((int)P15), 256, 0, stream>>>(bd, bp, WdS, WpS,
                                              WtP1, WtP2, WtP3, WtD1, WtD2, WtD3, pair,
                                              ddi_Wl, ddi_bl, ddi_Wr,
                                              ppi_Wl, ppi_bl, ppi_Wr,
                                              dpi_Wl, dpi_bl, dpi_Wr,
                                              pdi_Wl, pdi_bl, pdi_Wr,
                                              dW1, dW2, dW3, pW1, pW2, pW3);

    // 2) GNN front-end: edges -> 2-hop weights -> histograms -> F into Ad/Ap
    gnn_front_k<<<dim3(2, 64), 256, 0, stream>>>(ddi_edges, ppi_edges, dpi_edges,
                                                 drug_node_tokens, protein_node_toks,
                                                 drug_node_table, prot_node_table,
                                                 RHO, Ad, Ap);

    // 3) GNN stage 1: U = 0.5 * A @ Wcat^T
    gemm_sk3<<<dim3(2, 8, 3), 256, 0, stream>>>(Ad, 1248, WdS, 1248, 1248, 8, 0.5f,
                                                Ud, 112, 0, 100);
    gemm_sk3<<<dim3(16, 8, 3), 256, 0, stream>>>(Ap, 2208, WpS, 2208, 2208, 8, 0.5f,
                                                 Up, 1024, 0, 1000);
    ep_k<<<g1d(192 * 112 + 192 * 1024), 256, 0, stream>>>(Ud, Up, RHO, bd, bp, A2d, A2p);

    // 4) GNN stage 2 -> pair[:,320:1420) (atomicAdd onto pre-filled bias)
    gemm_sk3<<<dim3(2, 8, 1), 256, 0, stream>>>(A2d, 1248, WdS, 1248, 1248, 8, 0.5f,
                                                pair, 1420, 320, 100);
    gemm_sk3<<<dim3(16, 8, 1), 256, 0, stream>>>(A2p, 2208, WpS, 2208, 2208, 8, 0.5f,
                                                 pair, 1420, 420, 1000);

    // 5) conv towers (GNN buffers dead; drug overlapped with protein)
    conv1_dual<<<dim3(4, 1, 128), 256, 0, stream>>>(protein_tokens, protein_embed,
                                                    WtP1, pb1, y1p,
                                                    drug_tokens, drug_embed,
                                                    WtD1, db1, y1d);
    conv_mfma<8><<<dim3(4, 2, 64), 256, 0, stream>>>(y1p, 40, 1000, WtP2, 320, 5,
                                                     pb2, 80, y2p, 990, 992, nullptr, 0);
    conv3_dual<<<dim3(4, 3, 128), 256, 0, stream>>>(y2p, WtP3, pb3, pair,
                                                    y1d, WtD2, db2, y2d);
    conv_mfma<8><<<dim3(1, 3, 64), 256, 0, stream>>>(y2d, 80, 96, WtD3, 640, 10,
                                                     db3, 160, nullptr, 85, 0, pair, 0);

    // 6) FC head (fp32, split-K 16 for occupancy)
    gemm_nt<<<dim3(1, 16, 16), 256, 0, stream>>>(pair, 1420, fc1_W, cf1, 64, 1024, 1420, kc_of(1420, 16));
    epilogue_k<<<g1d(64 * 1024), 256, 0, stream>>>(cf1, fc1_b, h1, 64, 1024, 2);
    gemm_nt<<<dim3(1, 16, 16), 256, 0, stream>>>(h1, 1024, fc2_W, cf2, 64, 1024, 1024, kc_of(1024, 16));
    epilogue_k<<<g1d(64 * 1024), 256, 0, stream>>>(cf2, fc2_b, h2, 64, 1024, 2);
    gemm_nt<<<dim3(1, 8, 16), 256, 0, stream>>>(h2, 1024, fc3_W, cf3, 64, 512, 1024, kc_of(1024, 16));
    epilogue_k<<<g1d(64 * 512), 256, 0, stream>>>(cf3, fc3_b, h3, 64, 512, 2);
    out_k<<<dim3(1), 128, 0, stream>>>(h3, out_W, out_b, outp);
}